// Round 1
// baseline (3613.874 us; speedup 1.0000x reference)
//
#include <hip/hip_runtime.h>
#include <hip/hip_bf16.h>

#define N_ 2
#define C_ 192
#define CB_ 64
#define HW_ 100
#define PIX_ (HW_*HW_)

static __device__ __forceinline__ float bn_scale(float g) {
    return g * rsqrtf(1.0f + 1e-5f);
}

// ---------------- conv1x1 + BN (192->192) ----------------
__global__ __launch_bounds__(256) void conv1x1_bn_k(
    const float* __restrict__ x, const float* __restrict__ w,
    const float* __restrict__ g, const float* __restrict__ b,
    float* __restrict__ out)
{
    int idx = blockIdx.x * 256 + threadIdx.x;           // (n, co, p)
    if (idx >= N_ * C_ * PIX_) return;
    int p  = idx % PIX_;
    int co = (idx / PIX_) % C_;
    int n  = idx / (PIX_ * C_);
    const float* xn = x + n * C_ * PIX_ + p;
    const float* wr = w + co * C_;
    float acc = 0.f;
    #pragma unroll 4
    for (int ci = 0; ci < C_; ++ci) acc += xn[ci * PIX_] * wr[ci];
    out[idx] = acc * bn_scale(g[co]) + b[co];
}

// ---------------- gather patches into U (flat order n,cb,r,c,i,j) ----------------
__global__ __launch_bounds__(256) void gather_u_k(
    const float* __restrict__ x1, float* __restrict__ U,
    int cidx, int nw, int sh, int kh, int total)
{
    int f = blockIdx.x * 256 + threadIdx.x;
    if (f >= total) return;
    int t = f;
    int j = t % nw; t /= nw;
    int i = t % nw; t /= nw;
    int c = t % kh; t /= kh;
    int r = t % kh; t /= kh;
    int cb = t % CB_;
    int n  = t / CB_;
    int hh = i * sh + r;
    int ww = j * sh + c;
    U[f] = x1[((n * C_ + cidx * CB_ + cb) * HW_ + hh) * HW_ + ww];
}

// ---------------- q/k/v 1x1 convs ----------------
__global__ __launch_bounds__(256) void qkv_k(
    const float* __restrict__ U,
    const float* __restrict__ qw, const float* __restrict__ kw,
    const float* __restrict__ vw,
    float* __restrict__ Q, float* __restrict__ K, float* __restrict__ V,
    int L, int total)
{
    int idx = blockIdx.x * 256 + threadIdx.x;           // (b, co, p)
    if (idx >= total) return;
    int p  = idx % L;
    int co = (idx / L) % CB_;
    int b  = idx / (L * CB_);
    const float* ub = U + b * CB_ * L + p;
    const float* qr = qw + co * CB_;
    const float* kr = kw + co * CB_;
    const float* vr = vw + co * CB_;
    float aq = 0.f, ak = 0.f, av = 0.f;
    #pragma unroll 4
    for (int ci = 0; ci < CB_; ++ci) {
        float u = ub[ci * L];
        aq += u * qr[ci];
        ak += u * kr[ci];
        av += u * vr[ci];
    }
    Q[idx] = aq; K[idx] = ak; V[idx] = av;
}

// ---------------- attention: one wave per (b, h, l) row ----------------
__global__ __launch_bounds__(256) void attn_k(
    const float* __restrict__ Q, const float* __restrict__ K,
    const float* __restrict__ V, float* __restrict__ O,
    int L, int rows)
{
    extern __shared__ float smem[];
    int gtid = blockIdx.x * 256 + threadIdx.x;
    int wave = gtid >> 6;
    int lane = threadIdx.x & 63;
    int wslot = threadIdx.x >> 6;
    float* sc = smem + wslot * L;
    if (wave >= rows) return;
    int l = wave % L;
    int h = (wave / L) & 3;
    int b = wave / (L * 4);
    const float* qb = Q + (b * CB_ + h * 16) * L;
    const float* kb = K + (b * CB_ + h * 16) * L;
    const float* vb = V + (b * CB_ + h * 16) * L;
    float q[16];
    #pragma unroll
    for (int d = 0; d < 16; ++d) q[d] = qb[d * L + l];
    float mx = -1e30f;
    for (int m = lane; m < L; m += 64) {
        float s = 0.f;
        #pragma unroll
        for (int d = 0; d < 16; ++d) s += q[d] * kb[d * L + m];
        s *= 0.25f;
        sc[m] = s;
        mx = fmaxf(mx, s);
    }
    #pragma unroll
    for (int o = 32; o > 0; o >>= 1) mx = fmaxf(mx, __shfl_xor(mx, o, 64));
    float sum = 0.f;
    for (int m = lane; m < L; m += 64) {
        float e = __expf(sc[m] - mx);
        sc[m] = e;
        sum += e;
    }
    #pragma unroll
    for (int o = 32; o > 0; o >>= 1) sum += __shfl_xor(sum, o, 64);
    float inv = 1.0f / sum;
    float acc[16];
    #pragma unroll
    for (int d = 0; d < 16; ++d) acc[d] = 0.f;
    for (int m = lane; m < L; m += 64) {
        float pm = sc[m];
        #pragma unroll
        for (int d = 0; d < 16; ++d) acc[d] += pm * vb[d * L + m];
    }
    #pragma unroll
    for (int d = 0; d < 16; ++d) {
        float a = acc[d];
        #pragma unroll
        for (int o = 32; o > 0; o >>= 1) a += __shfl_xor(a, o, 64);
        if (lane == 0) O[(b * CB_ + h * 16 + d) * L + l] = a * inv;
    }
}

// ---------------- proj 1x1 + residual(U) -> A ----------------
__global__ __launch_bounds__(256) void proj_res_k(
    const float* __restrict__ O, const float* __restrict__ U,
    const float* __restrict__ pw, float* __restrict__ A,
    int L, int total)
{
    int idx = blockIdx.x * 256 + threadIdx.x;
    if (idx >= total) return;
    int p  = idx % L;
    int co = (idx / L) % CB_;
    int b  = idx / (L * CB_);
    const float* ob = O + b * CB_ * L + p;
    const float* pr = pw + co * CB_;
    float acc = 0.f;
    #pragma unroll 4
    for (int ci = 0; ci < CB_; ++ci) acc += ob[ci * L] * pr[ci];
    A[idx] = acc + U[idx];
}

// ---------------- 3x3 pos conv + BN, accumulate into A ----------------
__global__ __launch_bounds__(256) void posconv_k(
    const float* __restrict__ U, const float* __restrict__ w,
    const float* __restrict__ g, const float* __restrict__ bb,
    float* __restrict__ A, int kh, int total)
{
    int idx = blockIdx.x * 256 + threadIdx.x;           // (b, co, y, x)
    if (idx >= total) return;
    int x  = idx % kh;
    int y  = (idx / kh) % kh;
    int co = (idx / (kh * kh)) % CB_;
    int b  = idx / (kh * kh * CB_);
    const float* ub = U + b * CB_ * kh * kh;
    float acc = 0.f;
    for (int ci = 0; ci < CB_; ++ci) {
        const float* up = ub + ci * kh * kh;
        const float* wp = w + (co * CB_ + ci) * 9;
        #pragma unroll
        for (int dy = 0; dy < 3; ++dy) {
            int yy = y + dy - 1;
            if (yy < 0 || yy >= kh) continue;
            #pragma unroll
            for (int dx = 0; dx < 3; ++dx) {
                int xx = x + dx - 1;
                if (xx < 0 || xx >= kh) continue;
                acc += up[yy * kh + xx] * wp[dy * 3 + dx];
            }
        }
    }
    A[idx] += acc * bn_scale(g[co]) + bb[co];
}

// ---------------- fold (gather-style overlap-add with count div) ----------------
__global__ __launch_bounds__(256) void fold_k(
    const float* __restrict__ A, float* __restrict__ cat,
    int cidx, int nw, int sh, int kh)
{
    int idx = blockIdx.x * 256 + threadIdx.x;           // (n, cb, h, w)
    if (idx >= N_ * CB_ * PIX_) return;
    int w  = idx % HW_;
    int h  = (idx / HW_) % HW_;
    int cb = (idx / PIX_) % CB_;
    int n  = idx / (PIX_ * CB_);
    int numh = h - kh + 1;
    int ilo = numh > 0 ? (numh + sh - 1) / sh : 0;
    int ihi = min(nw - 1, h / sh);
    int numw = w - kh + 1;
    int jlo = numw > 0 ? (numw + sh - 1) / sh : 0;
    int jhi = min(nw - 1, w / sh);
    float sum = 0.f;
    for (int i = ilo; i <= ihi; ++i) {
        int r = h - i * sh;
        for (int j = jlo; j <= jhi; ++j) {
            int c = w - j * sh;
            int f = ((((n * CB_ + cb) * kh + r) * kh + c) * nw + i) * nw + j;
            sum += A[f];
        }
    }
    float cnt = (float)((ihi - ilo + 1) * (jhi - jlo + 1));
    cat[((n * C_ + cidx * CB_ + cb) * HW_ + h) * HW_ + w] = sum / cnt;
}

// ---------------- 3x3 conv 192->192 + BN (+ optional residual) ----------------
template<bool RES>
__global__ __launch_bounds__(256) void conv3x3_bn_k(
    const float* __restrict__ in, const float* __restrict__ w,
    const float* __restrict__ g, const float* __restrict__ bb,
    const float* __restrict__ res, float* __restrict__ out)
{
    __shared__ float tile[18][18];
    int tx = threadIdx.x & 15, ty = threadIdx.x >> 4;
    int tX = (blockIdx.x % 7) * 16, tY = (blockIdx.x / 7) * 16;
    int cog = blockIdx.y;                                // 4 co per group
    int n   = blockIdx.z;
    int x0 = tX + tx, y0 = tY + ty;
    bool act = (x0 < HW_ && y0 < HW_);
    float acc[4] = {0.f, 0.f, 0.f, 0.f};
    for (int ci = 0; ci < C_; ++ci) {
        const float* ip = in + (n * C_ + ci) * PIX_;
        for (int t = threadIdx.x; t < 18 * 18; t += 256) {
            int lx = t % 18, ly = t / 18;
            int gx = tX + lx - 1, gy = tY + ly - 1;
            tile[ly][lx] = (gx >= 0 && gx < HW_ && gy >= 0 && gy < HW_)
                               ? ip[gy * HW_ + gx] : 0.f;
        }
        __syncthreads();
        if (act) {
            float v[9];
            #pragma unroll
            for (int dy = 0; dy < 3; ++dy)
                #pragma unroll
                for (int dx = 0; dx < 3; ++dx)
                    v[dy * 3 + dx] = tile[ty + dy][tx + dx];
            #pragma unroll
            for (int k = 0; k < 4; ++k) {
                const float* wp = w + ((cog * 4 + k) * C_ + ci) * 9;
                float a = acc[k];
                #pragma unroll
                for (int q = 0; q < 9; ++q) a += v[q] * wp[q];
                acc[k] = a;
            }
        }
        __syncthreads();
    }
    if (act) {
        #pragma unroll
        for (int k = 0; k < 4; ++k) {
            int co = cog * 4 + k;
            float v = acc[k] * bn_scale(g[co]) + bb[co];
            if (RES) v += res[((n * C_ + co) * HW_ + y0) * HW_ + x0];
            out[((n * C_ + co) * HW_ + y0) * HW_ + x0] = v;
        }
    }
}

extern "C" void kernel_launch(void* const* d_in, const int* in_sizes, int n_in,
                              void* d_out, int out_size, void* d_ws, size_t ws_size,
                              hipStream_t stream) {
    const float* x       = (const float*)d_in[0];
    const float* conv1_w = (const float*)d_in[1];
    const float* bn1_g   = (const float*)d_in[2];
    const float* bn1_b   = (const float*)d_in[3];
    const float* conv2_w = (const float*)d_in[4];
    const float* bn2_g   = (const float*)d_in[5];
    const float* bn2_b   = (const float*)d_in[6];
    const float* conv3_w = (const float*)d_in[7];
    const float* bn3_g   = (const float*)d_in[8];
    const float* bn3_b   = (const float*)d_in[9];
    const float* pos_w   = (const float*)d_in[10];
    const float* bnp_g   = (const float*)d_in[11];
    const float* bnp_b   = (const float*)d_in[12];
    const float* q_w     = (const float*)d_in[13];
    const float* k_w     = (const float*)d_in[14];
    const float* v_w     = (const float*)d_in[15];
    const float* proj_w  = (const float*)d_in[16];

    float* ws  = (float*)d_ws;
    const int TENS = N_ * C_ * PIX_;          // 3,840,000
    const int UCAP = 288 * CB_ * 144;         // 2,654,208 (largest chunk)
    float* x1  = ws;
    float* cat = ws + TENS;
    float* h2  = ws + 2 * TENS;
    float* U   = ws + 3 * TENS;
    float* Qb  = U  + UCAP;
    float* Kb  = Qb + UCAP;
    float* Vb  = Kb + UCAP;
    float* Ob  = Vb + UCAP;
    float* Ab  = Ob + UCAP;

    conv1x1_bn_k<<<(TENS + 255) / 256, 256, 0, stream>>>(x, conv1_w, bn1_g, bn1_b, x1);

    const int NWs[3] = {4, 8, 12};
    const int SHs[3] = {25, 12, 8};
    const int KHs[3] = {25, 16, 12};
    const int BPs[3] = {32, 128, 288};

    for (int cidx = 0; cidx < 3; ++cidx) {
        int nw = NWs[cidx], sh = SHs[cidx], kh = KHs[cidx], Bp = BPs[cidx];
        int L = kh * kh;
        int totalU = Bp * CB_ * L;
        gather_u_k<<<(totalU + 255) / 256, 256, 0, stream>>>(x1, U, cidx, nw, sh, kh, totalU);
        qkv_k<<<(totalU + 255) / 256, 256, 0, stream>>>(U, q_w, k_w, v_w, Qb, Kb, Vb, L, totalU);
        int rows = Bp * 4 * L;
        attn_k<<<(rows + 3) / 4, 256, 4 * L * sizeof(float), stream>>>(Qb, Kb, Vb, Ob, L, rows);
        proj_res_k<<<(totalU + 255) / 256, 256, 0, stream>>>(Ob, U, proj_w, Ab, L, totalU);
        posconv_k<<<(totalU + 255) / 256, 256, 0, stream>>>(U, pos_w, bnp_g, bnp_b, Ab, kh, totalU);
        fold_k<<<(N_ * CB_ * PIX_ + 255) / 256, 256, 0, stream>>>(Ab, cat, cidx, nw, sh, kh);
    }

    conv3x3_bn_k<true ><<<dim3(49, 48, 2), 256, 0, stream>>>(cat, conv2_w, bn2_g, bn2_b, x1, h2);
    conv3x3_bn_k<false><<<dim3(49, 48, 2), 256, 0, stream>>>(h2, conv3_w, bn3_g, bn3_b, nullptr, (float*)d_out);
}

// Round 2
// 2524.150 us; speedup vs baseline: 1.4317x; 1.4317x over previous
//
#include <hip/hip_runtime.h>
#include <hip/hip_bf16.h>

#define N_ 2
#define C_ 192
#define CB_ 64
#define HW_ 100
#define PIX_ (HW_*HW_)
#define PADW_ 102
#define PADPIX_ (PADW_*PADW_)
#define KTOT_ 1728
#define KSTEP_ 32

typedef __attribute__((ext_vector_type(8))) short bf16x8;
typedef __attribute__((ext_vector_type(4))) float f32x4;

static __device__ __forceinline__ float bn_scale(float g) {
    return g * rsqrtf(1.0f + 1e-5f);
}

static __device__ __forceinline__ unsigned short f2bf(float v) {
    __hip_bfloat16 h = __float2bfloat16(v);
    return *(unsigned short*)&h;
}

// ---------------- conv1x1 + BN (192->192) ----------------
__global__ __launch_bounds__(256) void conv1x1_bn_k(
    const float* __restrict__ x, const float* __restrict__ w,
    const float* __restrict__ g, const float* __restrict__ b,
    float* __restrict__ out)
{
    int idx = blockIdx.x * 256 + threadIdx.x;           // (n, co, p)
    if (idx >= N_ * C_ * PIX_) return;
    int p  = idx % PIX_;
    int co = (idx / PIX_) % C_;
    int n  = idx / (PIX_ * C_);
    const float* xn = x + n * C_ * PIX_ + p;
    const float* wr = w + co * C_;
    float acc = 0.f;
    #pragma unroll 4
    for (int ci = 0; ci < C_; ++ci) acc += xn[ci * PIX_] * wr[ci];
    out[idx] = acc * bn_scale(g[co]) + b[co];
}

// ---------------- gather patches into U (flat order n,cb,r,c,i,j) ----------------
__global__ __launch_bounds__(256) void gather_u_k(
    const float* __restrict__ x1, float* __restrict__ U,
    int cidx, int nw, int sh, int kh, int total)
{
    int f = blockIdx.x * 256 + threadIdx.x;
    if (f >= total) return;
    int t = f;
    int j = t % nw; t /= nw;
    int i = t % nw; t /= nw;
    int c = t % kh; t /= kh;
    int r = t % kh; t /= kh;
    int cb = t % CB_;
    int n  = t / CB_;
    int hh = i * sh + r;
    int ww = j * sh + c;
    U[f] = x1[((n * C_ + cidx * CB_ + cb) * HW_ + hh) * HW_ + ww];
}

// ---------------- q/k/v 1x1 convs ----------------
__global__ __launch_bounds__(256) void qkv_k(
    const float* __restrict__ U,
    const float* __restrict__ qw, const float* __restrict__ kw,
    const float* __restrict__ vw,
    float* __restrict__ Q, float* __restrict__ K, float* __restrict__ V,
    int L, int total)
{
    int idx = blockIdx.x * 256 + threadIdx.x;           // (b, co, p)
    if (idx >= total) return;
    int p  = idx % L;
    int co = (idx / L) % CB_;
    int b  = idx / (L * CB_);
    const float* ub = U + b * CB_ * L + p;
    const float* qr = qw + co * CB_;
    const float* kr = kw + co * CB_;
    const float* vr = vw + co * CB_;
    float aq = 0.f, ak = 0.f, av = 0.f;
    #pragma unroll 4
    for (int ci = 0; ci < CB_; ++ci) {
        float u = ub[ci * L];
        aq += u * qr[ci];
        ak += u * kr[ci];
        av += u * vr[ci];
    }
    Q[idx] = aq; K[idx] = ak; V[idx] = av;
}

// ---------------- attention: one wave per (b, h, l) row ----------------
__global__ __launch_bounds__(256) void attn_k(
    const float* __restrict__ Q, const float* __restrict__ K,
    const float* __restrict__ V, float* __restrict__ O,
    int L, int rows)
{
    extern __shared__ float smem[];
    int gtid = blockIdx.x * 256 + threadIdx.x;
    int wave = gtid >> 6;
    int lane = threadIdx.x & 63;
    int wslot = threadIdx.x >> 6;
    float* sc = smem + wslot * L;
    if (wave >= rows) return;
    int l = wave % L;
    int h = (wave / L) & 3;
    int b = wave / (L * 4);
    const float* qb = Q + (b * CB_ + h * 16) * L;
    const float* kb = K + (b * CB_ + h * 16) * L;
    const float* vb = V + (b * CB_ + h * 16) * L;
    float q[16];
    #pragma unroll
    for (int d = 0; d < 16; ++d) q[d] = qb[d * L + l];
    float mx = -1e30f;
    for (int m = lane; m < L; m += 64) {
        float s = 0.f;
        #pragma unroll
        for (int d = 0; d < 16; ++d) s += q[d] * kb[d * L + m];
        s *= 0.25f;
        sc[m] = s;
        mx = fmaxf(mx, s);
    }
    #pragma unroll
    for (int o = 32; o > 0; o >>= 1) mx = fmaxf(mx, __shfl_xor(mx, o, 64));
    float sum = 0.f;
    for (int m = lane; m < L; m += 64) {
        float e = __expf(sc[m] - mx);
        sc[m] = e;
        sum += e;
    }
    #pragma unroll
    for (int o = 32; o > 0; o >>= 1) sum += __shfl_xor(sum, o, 64);
    float inv = 1.0f / sum;
    float acc[16];
    #pragma unroll
    for (int d = 0; d < 16; ++d) acc[d] = 0.f;
    for (int m = lane; m < L; m += 64) {
        float pm = sc[m];
        #pragma unroll
        for (int d = 0; d < 16; ++d) acc[d] += pm * vb[d * L + m];
    }
    #pragma unroll
    for (int d = 0; d < 16; ++d) {
        float a = acc[d];
        #pragma unroll
        for (int o = 32; o > 0; o >>= 1) a += __shfl_xor(a, o, 64);
        if (lane == 0) O[(b * CB_ + h * 16 + d) * L + l] = a * inv;
    }
}

// ---------------- proj 1x1 + residual(U) -> A ----------------
__global__ __launch_bounds__(256) void proj_res_k(
    const float* __restrict__ O, const float* __restrict__ U,
    const float* __restrict__ pw, float* __restrict__ A,
    int L, int total)
{
    int idx = blockIdx.x * 256 + threadIdx.x;
    if (idx >= total) return;
    int p  = idx % L;
    int co = (idx / L) % CB_;
    int b  = idx / (L * CB_);
    const float* ob = O + b * CB_ * L + p;
    const float* pr = pw + co * CB_;
    float acc = 0.f;
    #pragma unroll 4
    for (int ci = 0; ci < CB_; ++ci) acc += ob[ci * L] * pr[ci];
    A[idx] = acc + U[idx];
}

// ---------------- 3x3 pos conv + BN, accumulate into A ----------------
__global__ __launch_bounds__(256) void posconv_k(
    const float* __restrict__ U, const float* __restrict__ w,
    const float* __restrict__ g, const float* __restrict__ bb,
    float* __restrict__ A, int kh, int total)
{
    int idx = blockIdx.x * 256 + threadIdx.x;           // (b, co, y, x)
    if (idx >= total) return;
    int x  = idx % kh;
    int y  = (idx / kh) % kh;
    int co = (idx / (kh * kh)) % CB_;
    int b  = idx / (kh * kh * CB_);
    const float* ub = U + b * CB_ * kh * kh;
    float acc = 0.f;
    for (int ci = 0; ci < CB_; ++ci) {
        const float* up = ub + ci * kh * kh;
        const float* wp = w + (co * CB_ + ci) * 9;
        #pragma unroll
        for (int dy = 0; dy < 3; ++dy) {
            int yy = y + dy - 1;
            if (yy < 0 || yy >= kh) continue;
            #pragma unroll
            for (int dx = 0; dx < 3; ++dx) {
                int xx = x + dx - 1;
                if (xx < 0 || xx >= kh) continue;
                acc += up[yy * kh + xx] * wp[dy * 3 + dx];
            }
        }
    }
    A[idx] += acc * bn_scale(g[co]) + bb[co];
}

// ---------------- fold (gather-style overlap-add with count div) ----------------
__global__ __launch_bounds__(256) void fold_k(
    const float* __restrict__ A, float* __restrict__ cat,
    int cidx, int nw, int sh, int kh)
{
    int idx = blockIdx.x * 256 + threadIdx.x;           // (n, cb, h, w)
    if (idx >= N_ * CB_ * PIX_) return;
    int w  = idx % HW_;
    int h  = (idx / HW_) % HW_;
    int cb = (idx / PIX_) % CB_;
    int n  = idx / (PIX_ * CB_);
    int numh = h - kh + 1;
    int ilo = numh > 0 ? (numh + sh - 1) / sh : 0;
    int ihi = min(nw - 1, h / sh);
    int numw = w - kh + 1;
    int jlo = numw > 0 ? (numw + sh - 1) / sh : 0;
    int jhi = min(nw - 1, w / sh);
    float sum = 0.f;
    for (int i = ilo; i <= ihi; ++i) {
        int r = h - i * sh;
        for (int j = jlo; j <= jhi; ++j) {
            int c = w - j * sh;
            int f = ((((n * CB_ + cb) * kh + r) * kh + c) * nw + i) * nw + j;
            sum += A[f];
        }
    }
    float cnt = (float)((ihi - ilo + 1) * (jhi - jlo + 1));
    cat[((n * C_ + cidx * CB_ + cb) * HW_ + h) * HW_ + w] = sum / cnt;
}

// ---------------- prep: pad fp32 image -> bf16 [N][C][102][102] ----------------
__global__ __launch_bounds__(256) void pad_bf16_k(
    const float* __restrict__ in, unsigned short* __restrict__ out)
{
    int idx = blockIdx.x * 256 + threadIdx.x;
    if (idx >= N_ * C_ * PADPIX_) return;
    int xx = idx % PADW_;
    int yy = (idx / PADW_) % PADW_;
    int c  = (idx / PADPIX_) % C_;
    int n  = idx / (PADPIX_ * C_);
    float v = 0.f;
    if (xx >= 1 && xx <= HW_ && yy >= 1 && yy <= HW_)
        v = in[((n * C_ + c) * HW_ + (yy - 1)) * HW_ + (xx - 1)];
    out[idx] = f2bf(v);
}

// ---------------- prep: weights fp32 -> bf16 flat [co][k] ----------------
__global__ __launch_bounds__(256) void wcvt_k(
    const float* __restrict__ in, unsigned short* __restrict__ out)
{
    int idx = blockIdx.x * 256 + threadIdx.x;
    if (idx >= C_ * KTOT_) return;
    out[idx] = f2bf(in[idx]);
}

// ---------------- prep: address tables ----------------
__global__ __launch_bounds__(256) void tables_k(int* __restrict__ koff, int* __restrict__ poff)
{
    int i = blockIdx.x * 256 + threadIdx.x;
    if (i < KTOT_) {
        int ci = i / 9, off = i % 9;
        koff[i] = ci * PADPIX_ + (off / 3) * PADW_ + (off % 3);
    }
    if (i < 10048) {
        poff[i] = (i < PIX_) ? (i / HW_) * PADW_ + (i % HW_) : 0;
    }
}

// ---------------- 3x3 conv as implicit GEMM, bf16 MFMA ----------------
// D[co][p] = sum_k W[co][k] * X[k][p],  k=(ci,dy,dx), X from padded bf16 image.
// Tile: 64 co x 64 pix, 4 waves (each wave: 16 co x 64 pix), K-step 32.
template<bool RES>
__global__ __launch_bounds__(256) void conv3x3_mfma_k(
    const unsigned short* __restrict__ Xp,   // [N][C][102][102] bf16
    const unsigned short* __restrict__ Wb,   // [192][1728] bf16
    const int* __restrict__ koff,            // [1728]
    const int* __restrict__ poff,            // [10048]
    const float* __restrict__ g, const float* __restrict__ bb,
    const float* __restrict__ res, float* __restrict__ out)
{
    __shared__ unsigned short lds[64][40];   // [p][k] padded to 40 (80B rows)
    int tid  = threadIdx.x;
    int lane = tid & 63;
    int w    = tid >> 6;
    int p0   = blockIdx.x * 64;
    int co0  = blockIdx.y * 64;
    int n    = blockIdx.z;
    const unsigned short* Xn = Xp + (size_t)n * C_ * PADPIX_;

    // staging role: thread handles row p = tid/4, k-slot sk = (tid&3)*8
    int sp = tid >> 2;
    int sk = (tid & 3) * 8;
    int po = poff[p0 + sp];

    // A: direct-from-global weight row for this wave/lane
    const unsigned short* arow =
        Wb + (size_t)(co0 + w * 16 + (lane & 15)) * KTOT_ + ((lane >> 4) * 8);

    f32x4 acc[4];
    #pragma unroll
    for (int f = 0; f < 4; ++f) acc[f] = (f32x4){0.f, 0.f, 0.f, 0.f};

    for (int k0 = 0; k0 < KTOT_; k0 += KSTEP_) {
        // gather 8 image elems for (sp, sk..sk+7)
        const int4* kp = (const int4*)(koff + k0 + sk);
        int4 ka = kp[0], kc = kp[1];
        int kk[8] = {ka.x, ka.y, ka.z, ka.w, kc.x, kc.y, kc.z, kc.w};
        bf16x8 bv;
        #pragma unroll
        for (int j = 0; j < 8; ++j) bv[j] = (short)Xn[kk[j] + po];
        __syncthreads();                      // prev MFMA-phase reads done
        *(bf16x8*)(&lds[sp][sk]) = bv;
        __syncthreads();                      // tile visible
        bf16x8 a = *(const bf16x8*)(arow + k0);
        #pragma unroll
        for (int f = 0; f < 4; ++f) {
            bf16x8 b = *(const bf16x8*)(&lds[f * 16 + (lane & 15)][(lane >> 4) * 8]);
            acc[f] = __builtin_amdgcn_mfma_f32_16x16x32_bf16(a, b, acc[f], 0, 0, 0);
        }
    }

    // epilogue: D col(p)=lane&15, row(co)=(lane>>4)*4+r
    #pragma unroll
    for (int f = 0; f < 4; ++f) {
        int p = p0 + f * 16 + (lane & 15);
        if (p < PIX_) {
            #pragma unroll
            for (int r = 0; r < 4; ++r) {
                int co = co0 + w * 16 + (lane >> 4) * 4 + r;
                float v = acc[f][r] * bn_scale(g[co]) + bb[co];
                if (RES) v += res[(size_t)(n * C_ + co) * PIX_ + p];
                out[(size_t)(n * C_ + co) * PIX_ + p] = v;
            }
        }
    }
}

extern "C" void kernel_launch(void* const* d_in, const int* in_sizes, int n_in,
                              void* d_out, int out_size, void* d_ws, size_t ws_size,
                              hipStream_t stream) {
    const float* x       = (const float*)d_in[0];
    const float* conv1_w = (const float*)d_in[1];
    const float* bn1_g   = (const float*)d_in[2];
    const float* bn1_b   = (const float*)d_in[3];
    const float* conv2_w = (const float*)d_in[4];
    const float* bn2_g   = (const float*)d_in[5];
    const float* bn2_b   = (const float*)d_in[6];
    const float* conv3_w = (const float*)d_in[7];
    const float* bn3_g   = (const float*)d_in[8];
    const float* bn3_b   = (const float*)d_in[9];
    const float* pos_w   = (const float*)d_in[10];
    const float* bnp_g   = (const float*)d_in[11];
    const float* bnp_b   = (const float*)d_in[12];
    const float* q_w     = (const float*)d_in[13];
    const float* k_w     = (const float*)d_in[14];
    const float* v_w     = (const float*)d_in[15];
    const float* proj_w  = (const float*)d_in[16];

    float* ws  = (float*)d_ws;
    const int TENS = N_ * C_ * PIX_;          // 3,840,000
    const int UCAP = 288 * CB_ * 144;         // 2,654,208 (largest chunk)
    float* x1  = ws;
    float* cat = ws + TENS;
    float* h2  = ws + 2 * TENS;
    float* U   = ws + 3 * TENS;
    float* Qb  = U  + UCAP;
    float* Kb  = Qb + UCAP;
    float* Vb  = Kb + UCAP;
    float* Ob  = Vb + UCAP;
    float* Ab  = Ob + UCAP;

    conv1x1_bn_k<<<(TENS + 255) / 256, 256, 0, stream>>>(x, conv1_w, bn1_g, bn1_b, x1);

    const int NWs[3] = {4, 8, 12};
    const int SHs[3] = {25, 12, 8};
    const int KHs[3] = {25, 16, 12};
    const int BPs[3] = {32, 128, 288};

    for (int cidx = 0; cidx < 3; ++cidx) {
        int nw = NWs[cidx], sh = SHs[cidx], kh = KHs[cidx], Bp = BPs[cidx];
        int L = kh * kh;
        int totalU = Bp * CB_ * L;
        gather_u_k<<<(totalU + 255) / 256, 256, 0, stream>>>(x1, U, cidx, nw, sh, kh, totalU);
        qkv_k<<<(totalU + 255) / 256, 256, 0, stream>>>(U, q_w, k_w, v_w, Qb, Kb, Vb, L, totalU);
        int rows = Bp * 4 * L;
        attn_k<<<(rows + 3) / 4, 256, 4 * L * sizeof(float), stream>>>(Qb, Kb, Vb, Ob, L, rows);
        proj_res_k<<<(totalU + 255) / 256, 256, 0, stream>>>(Ob, U, proj_w, Ab, L, totalU);
        posconv_k<<<(totalU + 255) / 256, 256, 0, stream>>>(U, pos_w, bnp_g, bnp_b, Ab, kh, totalU);
        fold_k<<<(N_ * CB_ * PIX_ + 255) / 256, 256, 0, stream>>>(Ab, cat, cidx, nw, sh, kh);
    }

    // ---- MFMA path for the two 3x3 convs (buffers alias dead U region) ----
    unsigned short* Xb   = (unsigned short*)U;    // 3,995,136 bf16 (~8MB) <= UCAP floats
    unsigned short* w2b  = (unsigned short*)Qb;   // 331,776 bf16
    unsigned short* w3b  = (unsigned short*)Kb;   // 331,776 bf16
    int*            koff = (int*)Vb;              // 1728
    int*            poff = (int*)Ob;              // 10048

    tables_k<<<(10048 + 255) / 256, 256, 0, stream>>>(koff, poff);
    wcvt_k<<<(C_ * KTOT_ + 255) / 256, 256, 0, stream>>>(conv2_w, w2b);
    wcvt_k<<<(C_ * KTOT_ + 255) / 256, 256, 0, stream>>>(conv3_w, w3b);

    const int PADTOT = N_ * C_ * PADPIX_;
    pad_bf16_k<<<(PADTOT + 255) / 256, 256, 0, stream>>>(cat, Xb);
    conv3x3_mfma_k<true><<<dim3(157, 3, 2), 256, 0, stream>>>(
        Xb, w2b, koff, poff, bn2_g, bn2_b, x1, h2);
    pad_bf16_k<<<(PADTOT + 255) / 256, 256, 0, stream>>>(h2, Xb);
    conv3x3_mfma_k<false><<<dim3(157, 3, 2), 256, 0, stream>>>(
        Xb, w3b, koff, poff, bn3_g, bn3_b, nullptr, (float*)d_out);
}

// Round 4
// 1470.371 us; speedup vs baseline: 2.4578x; 1.7167x over previous
//
#include <hip/hip_runtime.h>
#include <hip/hip_bf16.h>

#define N_ 2
#define C_ 192
#define CB_ 64
#define HW_ 100
#define PIX_ (HW_*HW_)
#define PADW_ 102
#define PADPIX_ (PADW_*PADW_)
#define KTOT_ 1728
#define KPOS_ 576
#define KSTEP_ 32

typedef __attribute__((ext_vector_type(8))) short bf16x8;
typedef __attribute__((ext_vector_type(4))) float f32x4;

static __device__ __forceinline__ float bn_scale(float g) {
    return g * rsqrtf(1.0f + 1e-5f);
}

static __device__ __forceinline__ unsigned short f2bf(float v) {
    __hip_bfloat16 h = __float2bfloat16(v);
    return *(unsigned short*)&h;
}

// ---------------- conv1x1 + BN (192->192) ----------------
__global__ __launch_bounds__(256) void conv1x1_bn_k(
    const float* __restrict__ x, const float* __restrict__ w,
    const float* __restrict__ g, const float* __restrict__ b,
    float* __restrict__ out)
{
    int idx = blockIdx.x * 256 + threadIdx.x;           // (n, co, p)
    if (idx >= N_ * C_ * PIX_) return;
    int p  = idx % PIX_;
    int co = (idx / PIX_) % C_;
    int n  = idx / (PIX_ * C_);
    const float* xn = x + n * C_ * PIX_ + p;
    const float* wr = w + co * C_;
    float acc = 0.f;
    #pragma unroll 4
    for (int ci = 0; ci < C_; ++ci) acc += xn[ci * PIX_] * wr[ci];
    out[idx] = acc * bn_scale(g[co]) + b[co];
}

// ---------------- gather patches into U (flat order n,cb,r,c,i,j) ----------------
__global__ __launch_bounds__(256) void gather_u_k(
    const float* __restrict__ x1, float* __restrict__ U,
    int cidx, int nw, int sh, int kh, int total)
{
    int f = blockIdx.x * 256 + threadIdx.x;
    if (f >= total) return;
    int t = f;
    int j = t % nw; t /= nw;
    int i = t % nw; t /= nw;
    int c = t % kh; t /= kh;
    int r = t % kh; t /= kh;
    int cb = t % CB_;
    int n  = t / CB_;
    int hh = i * sh + r;
    int ww = j * sh + c;
    U[f] = x1[((n * C_ + cidx * CB_ + cb) * HW_ + hh) * HW_ + ww];
}

// ---------------- q/k/v 1x1 convs ----------------
__global__ __launch_bounds__(256) void qkv_k(
    const float* __restrict__ U,
    const float* __restrict__ qw, const float* __restrict__ kw,
    const float* __restrict__ vw,
    float* __restrict__ Q, float* __restrict__ K, float* __restrict__ V,
    int L, int total)
{
    int idx = blockIdx.x * 256 + threadIdx.x;           // (b, co, p)
    if (idx >= total) return;
    int p  = idx % L;
    int co = (idx / L) % CB_;
    int b  = idx / (L * CB_);
    const float* ub = U + b * CB_ * L + p;
    const float* qr = qw + co * CB_;
    const float* kr = kw + co * CB_;
    const float* vr = vw + co * CB_;
    float aq = 0.f, ak = 0.f, av = 0.f;
    #pragma unroll 4
    for (int ci = 0; ci < CB_; ++ci) {
        float u = ub[ci * L];
        aq += u * qr[ci];
        ak += u * kr[ci];
        av += u * vr[ci];
    }
    Q[idx] = aq; K[idx] = ak; V[idx] = av;
}

// ---------------- attention: one wave per (b, h, l) row ----------------
__global__ __launch_bounds__(256) void attn_k(
    const float* __restrict__ Q, const float* __restrict__ K,
    const float* __restrict__ V, float* __restrict__ O,
    int L, int rows)
{
    extern __shared__ float smem[];
    int gtid = blockIdx.x * 256 + threadIdx.x;
    int wave = gtid >> 6;
    int lane = threadIdx.x & 63;
    int wslot = threadIdx.x >> 6;
    float* sc = smem + wslot * L;
    if (wave >= rows) return;
    int l = wave % L;
    int h = (wave / L) & 3;
    int b = wave / (L * 4);
    const float* qb = Q + (b * CB_ + h * 16) * L;
    const float* kb = K + (b * CB_ + h * 16) * L;
    const float* vb = V + (b * CB_ + h * 16) * L;
    float q[16];
    #pragma unroll
    for (int d = 0; d < 16; ++d) q[d] = qb[d * L + l];
    float mx = -1e30f;
    for (int m = lane; m < L; m += 64) {
        float s = 0.f;
        #pragma unroll
        for (int d = 0; d < 16; ++d) s += q[d] * kb[d * L + m];
        s *= 0.25f;
        sc[m] = s;
        mx = fmaxf(mx, s);
    }
    #pragma unroll
    for (int o = 32; o > 0; o >>= 1) mx = fmaxf(mx, __shfl_xor(mx, o, 64));
    float sum = 0.f;
    for (int m = lane; m < L; m += 64) {
        float e = __expf(sc[m] - mx);
        sc[m] = e;
        sum += e;
    }
    #pragma unroll
    for (int o = 32; o > 0; o >>= 1) sum += __shfl_xor(sum, o, 64);
    float inv = 1.0f / sum;
    float acc[16];
    #pragma unroll
    for (int d = 0; d < 16; ++d) acc[d] = 0.f;
    for (int m = lane; m < L; m += 64) {
        float pm = sc[m];
        #pragma unroll
        for (int d = 0; d < 16; ++d) acc[d] += pm * vb[d * L + m];
    }
    #pragma unroll
    for (int d = 0; d < 16; ++d) {
        float a = acc[d];
        #pragma unroll
        for (int o = 32; o > 0; o >>= 1) a += __shfl_xor(a, o, 64);
        if (lane == 0) O[(b * CB_ + h * 16 + d) * L + l] = a * inv;
    }
}

// ---------------- proj 1x1 + residual(U) -> A ----------------
__global__ __launch_bounds__(256) void proj_res_k(
    const float* __restrict__ O, const float* __restrict__ U,
    const float* __restrict__ pw, float* __restrict__ A,
    int L, int total)
{
    int idx = blockIdx.x * 256 + threadIdx.x;
    if (idx >= total) return;
    int p  = idx % L;
    int co = (idx / L) % CB_;
    int b  = idx / (L * CB_);
    const float* ob = O + b * CB_ * L + p;
    const float* pr = pw + co * CB_;
    float acc = 0.f;
    #pragma unroll 4
    for (int ci = 0; ci < CB_; ++ci) acc += ob[ci * L] * pr[ci];
    A[idx] = acc + U[idx];
}

// ---------------- fold (gather-style overlap-add with count div) ----------------
__global__ __launch_bounds__(256) void fold_k(
    const float* __restrict__ A, float* __restrict__ cat,
    int cidx, int nw, int sh, int kh)
{
    int idx = blockIdx.x * 256 + threadIdx.x;           // (n, cb, h, w)
    if (idx >= N_ * CB_ * PIX_) return;
    int w  = idx % HW_;
    int h  = (idx / HW_) % HW_;
    int cb = (idx / PIX_) % CB_;
    int n  = idx / (PIX_ * CB_);
    int numh = h - kh + 1;
    int ilo = numh > 0 ? (numh + sh - 1) / sh : 0;
    int ihi = min(nw - 1, h / sh);
    int numw = w - kh + 1;
    int jlo = numw > 0 ? (numw + sh - 1) / sh : 0;
    int jhi = min(nw - 1, w / sh);
    float sum = 0.f;
    for (int i = ilo; i <= ihi; ++i) {
        int r = h - i * sh;
        for (int j = jlo; j <= jhi; ++j) {
            int c = w - j * sh;
            int f = ((((n * CB_ + cb) * kh + r) * kh + c) * nw + i) * nw + j;
            sum += A[f];
        }
    }
    float cnt = (float)((ihi - ilo + 1) * (jhi - jlo + 1));
    cat[((n * C_ + cidx * CB_ + cb) * HW_ + h) * HW_ + w] = sum / cnt;
}

// ---------------- prep: pad fp32 image -> bf16 [N][C][102][102] ----------------
__global__ __launch_bounds__(256) void pad_bf16_k(
    const float* __restrict__ in, unsigned short* __restrict__ out)
{
    int idx = blockIdx.x * 256 + threadIdx.x;
    if (idx >= N_ * C_ * PADPIX_) return;
    int xx = idx % PADW_;
    int yy = (idx / PADW_) % PADW_;
    int c  = (idx / PADPIX_) % C_;
    int n  = idx / (PADPIX_ * C_);
    float v = 0.f;
    if (xx >= 1 && xx <= HW_ && yy >= 1 && yy <= HW_)
        v = in[((n * C_ + c) * HW_ + (yy - 1)) * HW_ + (xx - 1)];
    out[idx] = f2bf(v);
}

// ---------------- prep: weights fp32 -> bf16 flat ----------------
__global__ __launch_bounds__(256) void wcvt_k(
    const float* __restrict__ in, unsigned short* __restrict__ out, int total)
{
    int idx = blockIdx.x * 256 + threadIdx.x;
    if (idx >= total) return;
    out[idx] = f2bf(in[idx]);
}

// ---------------- prep: address tables (big conv) ----------------
__global__ __launch_bounds__(256) void tables_k(int* __restrict__ koff, int* __restrict__ poff)
{
    int i = blockIdx.x * 256 + threadIdx.x;
    if (i < KTOT_) {
        int ci = i / 9, off = i % 9;
        koff[i] = ci * PADPIX_ + (off / 3) * PADW_ + (off % 3);
    }
    if (i < 10048) {
        poff[i] = (i < PIX_) ? (i / HW_) * PADW_ + (i % HW_) : 0;
    }
}

// ---------------- prep: pad U (per chunk) -> bf16 [Bp][64][kh+2][kh+2] ----------
__global__ __launch_bounds__(256) void padU_bf16_k(
    const float* __restrict__ U, unsigned short* __restrict__ Up,
    int kh, int total)   // total = Bp*64*(kh+2)*(kh+2)
{
    int pw = kh + 2;
    int idx = blockIdx.x * 256 + threadIdx.x;
    if (idx >= total) return;
    int xx = idx % pw;
    int yy = (idx / pw) % pw;
    int bc = idx / (pw * pw);            // b*64+cb
    float v = 0.f;
    if (xx >= 1 && xx <= kh && yy >= 1 && yy <= kh)
        v = U[bc * kh * kh + (yy - 1) * kh + (xx - 1)];
    Up[idx] = f2bf(v);
}

// ---------------- prep: address tables for posconv (per chunk) ----------------
// poff must be the TOP-LEFT of the 3x3 window in padded coords (no +1),
// matching tables_k; koff supplies the (dy,dx) tap offsets.
__global__ __launch_bounds__(256) void tables_pos_k(
    int* __restrict__ koff, int* __restrict__ poff,
    int kh, int npix, int npix_pad)
{
    int pw = kh + 2;
    int i = blockIdx.x * 256 + threadIdx.x;
    if (i < KPOS_) {
        int ci = i / 9, off = i % 9;
        koff[i] = ci * pw * pw + (off / 3) * pw + (off % 3);
    }
    if (i < npix_pad) {
        if (i < npix) {
            int b = i / (kh * kh), p = i % (kh * kh);
            poff[i] = b * 64 * pw * pw + (p / kh) * pw + (p % kh);
        } else {
            poff[i] = 0;
        }
    }
}

// ---------------- 3x3 conv as implicit GEMM, bf16 MFMA (192ch, big image) -----
template<bool RES>
__global__ __launch_bounds__(256) void conv3x3_mfma_k(
    const unsigned short* __restrict__ Xp,   // [N][C][102][102] bf16
    const unsigned short* __restrict__ Wb,   // [192][1728] bf16
    const int* __restrict__ koff,            // [1728]
    const int* __restrict__ poff,            // [10048]
    const float* __restrict__ g, const float* __restrict__ bb,
    const float* __restrict__ res, float* __restrict__ out)
{
    __shared__ unsigned short lds[64][40];   // [p][k] padded to 40 (80B rows)
    int tid  = threadIdx.x;
    int lane = tid & 63;
    int w    = tid >> 6;
    int p0   = blockIdx.x * 64;
    int co0  = blockIdx.y * 64;
    int n    = blockIdx.z;
    const unsigned short* Xn = Xp + (size_t)n * C_ * PADPIX_;

    int sp = tid >> 2;
    int sk = (tid & 3) * 8;
    int po = poff[p0 + sp];

    const unsigned short* arow =
        Wb + (size_t)(co0 + w * 16 + (lane & 15)) * KTOT_ + ((lane >> 4) * 8);

    f32x4 acc[4];
    #pragma unroll
    for (int f = 0; f < 4; ++f) acc[f] = (f32x4){0.f, 0.f, 0.f, 0.f};

    for (int k0 = 0; k0 < KTOT_; k0 += KSTEP_) {
        const int4* kp = (const int4*)(koff + k0 + sk);
        int4 ka = kp[0], kc = kp[1];
        int kk[8] = {ka.x, ka.y, ka.z, ka.w, kc.x, kc.y, kc.z, kc.w};
        bf16x8 bv;
        #pragma unroll
        for (int j = 0; j < 8; ++j) bv[j] = (short)Xn[kk[j] + po];
        __syncthreads();
        *(bf16x8*)(&lds[sp][sk]) = bv;
        __syncthreads();
        bf16x8 a = *(const bf16x8*)(arow + k0);
        #pragma unroll
        for (int f = 0; f < 4; ++f) {
            bf16x8 b = *(const bf16x8*)(&lds[f * 16 + (lane & 15)][(lane >> 4) * 8]);
            acc[f] = __builtin_amdgcn_mfma_f32_16x16x32_bf16(a, b, acc[f], 0, 0, 0);
        }
    }

    #pragma unroll
    for (int f = 0; f < 4; ++f) {
        int p = p0 + f * 16 + (lane & 15);
        if (p < PIX_) {
            #pragma unroll
            for (int r = 0; r < 4; ++r) {
                int co = co0 + w * 16 + (lane >> 4) * 4 + r;
                float v = acc[f][r] * bn_scale(g[co]) + bb[co];
                if (RES) v += res[(size_t)(n * C_ + co) * PIX_ + p];
                out[(size_t)(n * C_ + co) * PIX_ + p] = v;
            }
        }
    }
}

// ---------------- posconv as implicit GEMM, bf16 MFMA (64ch, patches) ---------
// A[(b*64+co)*L + p] += BN(conv3x3(U)).  M=64 co (whole block), N=64 pixels.
__global__ __launch_bounds__(256) void posconv_mfma_k(
    const unsigned short* __restrict__ Up,   // padded patches bf16
    const unsigned short* __restrict__ Wb,   // [64][576] bf16
    const int* __restrict__ koff,            // [576]
    const int* __restrict__ poff,            // [npix_pad]
    const float* __restrict__ g, const float* __restrict__ bb,
    float* __restrict__ A, int L, int npix)
{
    __shared__ unsigned short lds[64][40];
    int tid  = threadIdx.x;
    int lane = tid & 63;
    int w    = tid >> 6;
    int p0   = blockIdx.x * 64;

    int sp = tid >> 2;
    int sk = (tid & 3) * 8;
    int po = poff[p0 + sp];

    const unsigned short* arow =
        Wb + (size_t)(w * 16 + (lane & 15)) * KPOS_ + ((lane >> 4) * 8);

    f32x4 acc[4];
    #pragma unroll
    for (int f = 0; f < 4; ++f) acc[f] = (f32x4){0.f, 0.f, 0.f, 0.f};

    for (int k0 = 0; k0 < KPOS_; k0 += KSTEP_) {
        const int4* kp = (const int4*)(koff + k0 + sk);
        int4 ka = kp[0], kc = kp[1];
        int kk[8] = {ka.x, ka.y, ka.z, ka.w, kc.x, kc.y, kc.z, kc.w};
        bf16x8 bv;
        #pragma unroll
        for (int j = 0; j < 8; ++j) bv[j] = (short)Up[kk[j] + po];
        __syncthreads();
        *(bf16x8*)(&lds[sp][sk]) = bv;
        __syncthreads();
        bf16x8 a = *(const bf16x8*)(arow + k0);
        #pragma unroll
        for (int f = 0; f < 4; ++f) {
            bf16x8 b = *(const bf16x8*)(&lds[f * 16 + (lane & 15)][(lane >> 4) * 8]);
            acc[f] = __builtin_amdgcn_mfma_f32_16x16x32_bf16(a, b, acc[f], 0, 0, 0);
        }
    }

    #pragma unroll
    for (int f = 0; f < 4; ++f) {
        int q = p0 + f * 16 + (lane & 15);
        if (q < npix) {
            int b = q / L, p = q % L;
            #pragma unroll
            for (int r = 0; r < 4; ++r) {
                int co = w * 16 + (lane >> 4) * 4 + r;
                A[(size_t)(b * 64 + co) * L + p] += acc[f][r] * bn_scale(g[co]) + bb[co];
            }
        }
    }
}

extern "C" void kernel_launch(void* const* d_in, const int* in_sizes, int n_in,
                              void* d_out, int out_size, void* d_ws, size_t ws_size,
                              hipStream_t stream) {
    const float* x       = (const float*)d_in[0];
    const float* conv1_w = (const float*)d_in[1];
    const float* bn1_g   = (const float*)d_in[2];
    const float* bn1_b   = (const float*)d_in[3];
    const float* conv2_w = (const float*)d_in[4];
    const float* bn2_g   = (const float*)d_in[5];
    const float* bn2_b   = (const float*)d_in[6];
    const float* conv3_w = (const float*)d_in[7];
    const float* bn3_g   = (const float*)d_in[8];
    const float* bn3_b   = (const float*)d_in[9];
    const float* pos_w   = (const float*)d_in[10];
    const float* bnp_g   = (const float*)d_in[11];
    const float* bnp_b   = (const float*)d_in[12];
    const float* q_w     = (const float*)d_in[13];
    const float* k_w     = (const float*)d_in[14];
    const float* v_w     = (const float*)d_in[15];
    const float* proj_w  = (const float*)d_in[16];

    float* ws  = (float*)d_ws;
    const int TENS = N_ * C_ * PIX_;          // 3,840,000
    const int UCAP = 288 * CB_ * 144;         // 2,654,208 (largest chunk)
    float* x1  = ws;
    float* cat = ws + TENS;
    float* h2  = ws + 2 * TENS;
    float* U   = ws + 3 * TENS;
    float* Qb  = U  + UCAP;
    float* Kb  = Qb + UCAP;
    float* Vb  = Kb + UCAP;
    float* Ob  = Vb + UCAP;
    float* Ab  = Ob + UCAP;

    // posconv scratch aliases h2 (dead until conv2 writes it after the loop)
    unsigned short* Up    = (unsigned short*)h2;              // <= 3,612,672 bf16
    unsigned short* pwb   = (unsigned short*)(h2 + 1900000);  // 36,864 bf16
    int*            koffp = (int*)(h2 + 1950000);             // 576
    int*            poffp = (int*)(h2 + 1960000);             // <= 41,536

    conv1x1_bn_k<<<(TENS + 255) / 256, 256, 0, stream>>>(x, conv1_w, bn1_g, bn1_b, x1);
    wcvt_k<<<(CB_ * KPOS_ + 255) / 256, 256, 0, stream>>>(pos_w, pwb, CB_ * KPOS_);

    const int NWs[3] = {4, 8, 12};
    const int SHs[3] = {25, 12, 8};
    const int KHs[3] = {25, 16, 12};
    const int BPs[3] = {32, 128, 288};

    for (int cidx = 0; cidx < 3; ++cidx) {
        int nw = NWs[cidx], sh = SHs[cidx], kh = KHs[cidx], Bp = BPs[cidx];
        int L = kh * kh;
        int totalU = Bp * CB_ * L;
        gather_u_k<<<(totalU + 255) / 256, 256, 0, stream>>>(x1, U, cidx, nw, sh, kh, totalU);
        qkv_k<<<(totalU + 255) / 256, 256, 0, stream>>>(U, q_w, k_w, v_w, Qb, Kb, Vb, L, totalU);
        int rows = Bp * 4 * L;
        attn_k<<<(rows + 3) / 4, 256, 4 * L * sizeof(float), stream>>>(Qb, Kb, Vb, Ob, L, rows);
        proj_res_k<<<(totalU + 255) / 256, 256, 0, stream>>>(Ob, U, proj_w, Ab, L, totalU);

        // posconv via MFMA
        int pw = kh + 2;
        int padTot = Bp * CB_ * pw * pw;
        int npix = Bp * L;
        int nblk = (npix + 63) / 64;
        int npix_pad = nblk * 64;
        padU_bf16_k<<<(padTot + 255) / 256, 256, 0, stream>>>(U, Up, kh, padTot);
        tables_pos_k<<<(npix_pad + 255) / 256, 256, 0, stream>>>(koffp, poffp, kh, npix, npix_pad);
        posconv_mfma_k<<<nblk, 256, 0, stream>>>(Up, pwb, koffp, poffp, bnp_g, bnp_b, Ab, L, npix);

        fold_k<<<(N_ * CB_ * PIX_ + 255) / 256, 256, 0, stream>>>(Ab, cat, cidx, nw, sh, kh);
    }

    // ---- MFMA path for the two 3x3 convs (buffers alias dead U region) ----
    unsigned short* Xb   = (unsigned short*)U;    // 3,995,136 bf16 (~8MB) <= UCAP floats
    unsigned short* w2b  = (unsigned short*)Qb;   // 331,776 bf16
    unsigned short* w3b  = (unsigned short*)Kb;   // 331,776 bf16
    int*            koff = (int*)Vb;              // 1728
    int*            poff = (int*)Ob;              // 10048

    tables_k<<<(10048 + 255) / 256, 256, 0, stream>>>(koff, poff);
    wcvt_k<<<(C_ * KTOT_ + 255) / 256, 256, 0, stream>>>(conv2_w, w2b, C_ * KTOT_);
    wcvt_k<<<(C_ * KTOT_ + 255) / 256, 256, 0, stream>>>(conv3_w, w3b, C_ * KTOT_);

    const int PADTOT = N_ * C_ * PADPIX_;
    pad_bf16_k<<<(PADTOT + 255) / 256, 256, 0, stream>>>(cat, Xb);
    conv3x3_mfma_k<true><<<dim3(157, 3, 2), 256, 0, stream>>>(
        Xb, w2b, koff, poff, bn2_g, bn2_b, x1, h2);
    pad_bf16_k<<<(PADTOT + 255) / 256, 256, 0, stream>>>(h2, Xb);
    conv3x3_mfma_k<false><<<dim3(157, 3, 2), 256, 0, stream>>>(
        Xb, w3b, koff, poff, bn3_g, bn3_b, nullptr, (float*)d_out);
}

// Round 5
// 956.327 us; speedup vs baseline: 3.7789x; 1.5375x over previous
//
#include <hip/hip_runtime.h>
#include <hip/hip_bf16.h>

#define N_ 2
#define C_ 192
#define CB_ 64
#define HW_ 100
#define PIX_ (HW_*HW_)
#define PADW_ 102
#define PADPIX_ (PADW_*PADW_)
#define KTOT_ 1728
#define KPOS_ 576
#define KSTEP_ 32

typedef __attribute__((ext_vector_type(8))) short bf16x8;
typedef __attribute__((ext_vector_type(4))) float f32x4;

static __device__ __forceinline__ float bn_scale(float g) {
    return g * rsqrtf(1.0f + 1e-5f);
}

static __device__ __forceinline__ unsigned short f2bf(float v) {
    __hip_bfloat16 h = __float2bfloat16(v);
    return *(unsigned short*)&h;
}

// ---------------- conv1x1 + BN (192->192) ----------------
__global__ __launch_bounds__(256) void conv1x1_bn_k(
    const float* __restrict__ x, const float* __restrict__ w,
    const float* __restrict__ g, const float* __restrict__ b,
    float* __restrict__ out)
{
    int idx = blockIdx.x * 256 + threadIdx.x;           // (n, co, p)
    if (idx >= N_ * C_ * PIX_) return;
    int p  = idx % PIX_;
    int co = (idx / PIX_) % C_;
    int n  = idx / (PIX_ * C_);
    const float* xn = x + n * C_ * PIX_ + p;
    const float* wr = w + co * C_;
    float acc = 0.f;
    #pragma unroll 4
    for (int ci = 0; ci < C_; ++ci) acc += xn[ci * PIX_] * wr[ci];
    out[idx] = acc * bn_scale(g[co]) + b[co];
}

// ---------------- gather patches into U (flat order n,cb,r,c,i,j) ----------------
__global__ __launch_bounds__(256) void gather_u_k(
    const float* __restrict__ x1, float* __restrict__ U,
    int cidx, int nw, int sh, int kh, int total)
{
    int f = blockIdx.x * 256 + threadIdx.x;
    if (f >= total) return;
    int t = f;
    int j = t % nw; t /= nw;
    int i = t % nw; t /= nw;
    int c = t % kh; t /= kh;
    int r = t % kh; t /= kh;
    int cb = t % CB_;
    int n  = t / CB_;
    int hh = i * sh + r;
    int ww = j * sh + c;
    U[f] = x1[((n * C_ + cidx * CB_ + cb) * HW_ + hh) * HW_ + ww];
}

// ---------------- q/k/v 1x1 convs -> bf16 ----------------
__global__ __launch_bounds__(256) void qkv_k(
    const float* __restrict__ U,
    const float* __restrict__ qw, const float* __restrict__ kw,
    const float* __restrict__ vw,
    unsigned short* __restrict__ Q, unsigned short* __restrict__ K,
    unsigned short* __restrict__ V,
    int L, int total)
{
    int idx = blockIdx.x * 256 + threadIdx.x;           // (b, co, p)
    if (idx >= total) return;
    int p  = idx % L;
    int co = (idx / L) % CB_;
    int b  = idx / (L * CB_);
    const float* ub = U + b * CB_ * L + p;
    const float* qr = qw + co * CB_;
    const float* kr = kw + co * CB_;
    const float* vr = vw + co * CB_;
    float aq = 0.f, ak = 0.f, av = 0.f;
    #pragma unroll 4
    for (int ci = 0; ci < CB_; ++ci) {
        float u = ub[ci * L];
        aq += u * qr[ci];
        ak += u * kr[ci];
        av += u * vr[ci];
    }
    Q[idx] = f2bf(aq); K[idx] = f2bf(ak); V[idx] = f2bf(av);
}

// ---------------- MFMA flash attention ----------------
// Per block: one (b,h), 64 query cols (4 waves x 16 l). S^T = K^T Q via 2 MFMAs
// (d=16 zero-padded to 32); online softmax per col l=lane&15; PV via 1 MFMA per
// 32-m tile. O written fp32.
__global__ __launch_bounds__(256) void attn_mfma_k(
    const unsigned short* __restrict__ Q, const unsigned short* __restrict__ K,
    const unsigned short* __restrict__ V, float* __restrict__ O,
    int L, int nMt)
{
    __shared__ unsigned short kt[32][24];   // [m][d], 48B rows (16B aligned)
    __shared__ unsigned short vt[16][40];   // [d][m], 80B rows
    int tid  = threadIdx.x;
    int lane = tid & 63;
    int wv   = tid >> 6;
    int c    = lane & 15;
    int g    = lane >> 4;
    int bh = blockIdx.y;
    int b = bh >> 2, h = bh & 3;
    const unsigned short* qb = Q + (size_t)(b * 64 + h * 16) * L;
    const unsigned short* kb = K + (size_t)(b * 64 + h * 16) * L;
    const unsigned short* vb = V + (size_t)(b * 64 + h * 16) * L;
    float* ob = O + (size_t)(b * 64 + h * 16) * L;

    int l = blockIdx.x * 64 + wv * 16 + c;
    bool lval = (l < L);
    int lc = lval ? l : (L - 1);

    // Q B-frag: B[l=c][d=g*8+j], d>=16 -> 0
    bf16x8 qf = (bf16x8){0,0,0,0,0,0,0,0};
    if (g < 2) {
        #pragma unroll
        for (int j = 0; j < 8; ++j) qf[j] = (short)qb[(g * 8 + j) * L + lc];
    }

    f32x4 acc = (f32x4){0.f, 0.f, 0.f, 0.f};
    float mrun = -1e30f, srun = 0.f;

    for (int mt = 0; mt < nMt; ++mt) {
        int m0 = mt * 32;
        __syncthreads();
        for (int e = tid; e < 1024; e += 256) {
            int m = e & 31, d = (e >> 5) & 15;
            int src = d * L + min(m0 + m, L - 1);
            if (e < 512) kt[m][d] = kb[src];
            else         vt[d][m] = vb[src];
        }
        __syncthreads();

        // K A-frags: A[m=c][d=g*8+j] (rows c and c+16)
        bf16x8 kf1 = (bf16x8){0,0,0,0,0,0,0,0}, kf2 = kf1;
        if (g < 2) {
            kf1 = *(const bf16x8*)(&kt[c][g * 8]);
            kf2 = *(const bf16x8*)(&kt[c + 16][g * 8]);
        }
        f32x4 s1 = __builtin_amdgcn_mfma_f32_16x16x32_bf16(
            kf1, qf, (f32x4){0.f,0.f,0.f,0.f}, 0, 0, 0);
        f32x4 s2 = __builtin_amdgcn_mfma_f32_16x16x32_bf16(
            kf2, qf, (f32x4){0.f,0.f,0.f,0.f}, 0, 0, 0);

        // lane holds S^T rows m' = g*4+r (s1) and 16+g*4+r (s2), col l=c
        float p1[4], p2[4];
        float tmax = -1e30f;
        #pragma unroll
        for (int r = 0; r < 4; ++r) {
            int ma = m0 + g * 4 + r;
            float a  = (ma      < L) ? s1[r] * 0.25f : -1e30f;
            float b2 = (ma + 16 < L) ? s2[r] * 0.25f : -1e30f;
            p1[r] = a; p2[r] = b2;
            tmax = fmaxf(tmax, fmaxf(a, b2));
        }
        tmax = fmaxf(tmax, __shfl_xor(tmax, 16, 64));
        tmax = fmaxf(tmax, __shfl_xor(tmax, 32, 64));
        float mnew = fmaxf(mrun, tmax);
        float corr = __expf(mrun - mnew);
        float psum = 0.f;
        #pragma unroll
        for (int r = 0; r < 4; ++r) {
            p1[r] = __expf(p1[r] - mnew);
            p2[r] = __expf(p2[r] - mnew);
            psum += p1[r] + p2[r];
        }
        srun = srun * corr + psum;
        mrun = mnew;
        #pragma unroll
        for (int r = 0; r < 4; ++r) acc[r] *= corr;

        // P -> PV B-frag: B[l=c][m=g*8+j]; source lane ((2g+(j>>2))&3)*16+c,
        // reg r=j&3, from s1 if g<2 else s2.
        bf16x8 pbf;
        int t = g >> 1;
        #pragma unroll
        for (int j = 0; j < 8; ++j) {
            int srcLane = (((2 * g + (j >> 2)) & 3) << 4) | c;
            float v1 = __shfl(p1[j & 3], srcLane, 64);
            float v2 = __shfl(p2[j & 3], srcLane, 64);
            pbf[j] = (short)f2bf(t ? v2 : v1);
        }
        // V A-frag: A[d=c][m=g*8+j]
        bf16x8 vf = *(const bf16x8*)(&vt[c][g * 8]);
        acc = __builtin_amdgcn_mfma_f32_16x16x32_bf16(vf, pbf, acc, 0, 0, 0);
    }

    float stot = srun;
    stot += __shfl_xor(stot, 16, 64);
    stot += __shfl_xor(stot, 32, 64);
    float inv = 1.f / stot;
    if (lval) {
        #pragma unroll
        for (int r = 0; r < 4; ++r)
            ob[(size_t)(g * 4 + r) * L + l] = acc[r] * inv;
    }
}

// ---------------- proj 1x1 + residual(U) -> A ----------------
__global__ __launch_bounds__(256) void proj_res_k(
    const float* __restrict__ O, const float* __restrict__ U,
    const float* __restrict__ pw, float* __restrict__ A,
    int L, int total)
{
    int idx = blockIdx.x * 256 + threadIdx.x;
    if (idx >= total) return;
    int p  = idx % L;
    int co = (idx / L) % CB_;
    int b  = idx / (L * CB_);
    const float* ob = O + b * CB_ * L + p;
    const float* pr = pw + co * CB_;
    float acc = 0.f;
    #pragma unroll 4
    for (int ci = 0; ci < CB_; ++ci) acc += ob[ci * L] * pr[ci];
    A[idx] = acc + U[idx];
}

// ---------------- fold (gather-style overlap-add with count div) ----------------
__global__ __launch_bounds__(256) void fold_k(
    const float* __restrict__ A, float* __restrict__ cat,
    int cidx, int nw, int sh, int kh)
{
    int idx = blockIdx.x * 256 + threadIdx.x;           // (n, cb, h, w)
    if (idx >= N_ * CB_ * PIX_) return;
    int w  = idx % HW_;
    int h  = (idx / HW_) % HW_;
    int cb = (idx / PIX_) % CB_;
    int n  = idx / (PIX_ * CB_);
    int numh = h - kh + 1;
    int ilo = numh > 0 ? (numh + sh - 1) / sh : 0;
    int ihi = min(nw - 1, h / sh);
    int numw = w - kh + 1;
    int jlo = numw > 0 ? (numw + sh - 1) / sh : 0;
    int jhi = min(nw - 1, w / sh);
    float sum = 0.f;
    for (int i = ilo; i <= ihi; ++i) {
        int r = h - i * sh;
        for (int j = jlo; j <= jhi; ++j) {
            int c = w - j * sh;
            int f = ((((n * CB_ + cb) * kh + r) * kh + c) * nw + i) * nw + j;
            sum += A[f];
        }
    }
    float cnt = (float)((ihi - ilo + 1) * (jhi - jlo + 1));
    cat[((n * C_ + cidx * CB_ + cb) * HW_ + h) * HW_ + w] = sum / cnt;
}

// ---------------- prep: pad fp32 image -> bf16 [N][C][102][102] ----------------
__global__ __launch_bounds__(256) void pad_bf16_k(
    const float* __restrict__ in, unsigned short* __restrict__ out)
{
    int idx = blockIdx.x * 256 + threadIdx.x;
    if (idx >= N_ * C_ * PADPIX_) return;
    int xx = idx % PADW_;
    int yy = (idx / PADW_) % PADW_;
    int c  = (idx / PADPIX_) % C_;
    int n  = idx / (PADPIX_ * C_);
    float v = 0.f;
    if (xx >= 1 && xx <= HW_ && yy >= 1 && yy <= HW_)
        v = in[((n * C_ + c) * HW_ + (yy - 1)) * HW_ + (xx - 1)];
    out[idx] = f2bf(v);
}

// ---------------- prep: weights fp32 -> bf16 flat ----------------
__global__ __launch_bounds__(256) void wcvt_k(
    const float* __restrict__ in, unsigned short* __restrict__ out, int total)
{
    int idx = blockIdx.x * 256 + threadIdx.x;
    if (idx >= total) return;
    out[idx] = f2bf(in[idx]);
}

// ---------------- prep: address tables (big conv) ----------------
__global__ __launch_bounds__(256) void tables_k(int* __restrict__ koff, int* __restrict__ poff)
{
    int i = blockIdx.x * 256 + threadIdx.x;
    if (i < KTOT_) {
        int ci = i / 9, off = i % 9;
        koff[i] = ci * PADPIX_ + (off / 3) * PADW_ + (off % 3);
    }
    if (i < 10048) {
        poff[i] = (i < PIX_) ? (i / HW_) * PADW_ + (i % HW_) : 0;
    }
}

// ---------------- prep: pad U (per chunk) -> bf16 [Bp][64][kh+2][kh+2] ----------
__global__ __launch_bounds__(256) void padU_bf16_k(
    const float* __restrict__ U, unsigned short* __restrict__ Up,
    int kh, int total)   // total = Bp*64*(kh+2)*(kh+2)
{
    int pw = kh + 2;
    int idx = blockIdx.x * 256 + threadIdx.x;
    if (idx >= total) return;
    int xx = idx % pw;
    int yy = (idx / pw) % pw;
    int bc = idx / (pw * pw);            // b*64+cb
    float v = 0.f;
    if (xx >= 1 && xx <= kh && yy >= 1 && yy <= kh)
        v = U[bc * kh * kh + (yy - 1) * kh + (xx - 1)];
    Up[idx] = f2bf(v);
}

// ---------------- prep: address tables for posconv (per chunk) ----------------
// poff = TOP-LEFT of the 3x3 window in padded coords (no +1), matching tables_k.
__global__ __launch_bounds__(256) void tables_pos_k(
    int* __restrict__ koff, int* __restrict__ poff,
    int kh, int npix, int npix_pad)
{
    int pw = kh + 2;
    int i = blockIdx.x * 256 + threadIdx.x;
    if (i < KPOS_) {
        int ci = i / 9, off = i % 9;
        koff[i] = ci * pw * pw + (off / 3) * pw + (off % 3);
    }
    if (i < npix_pad) {
        if (i < npix) {
            int b = i / (kh * kh), p = i % (kh * kh);
            poff[i] = b * 64 * pw * pw + (p / kh) * pw + (p % kh);
        } else {
            poff[i] = 0;
        }
    }
}

// ---------------- 3x3 conv as implicit GEMM, bf16 MFMA (192ch, big image) -----
template<bool RES>
__global__ __launch_bounds__(256) void conv3x3_mfma_k(
    const unsigned short* __restrict__ Xp,   // [N][C][102][102] bf16
    const unsigned short* __restrict__ Wb,   // [192][1728] bf16
    const int* __restrict__ koff,            // [1728]
    const int* __restrict__ poff,            // [10048]
    const float* __restrict__ g, const float* __restrict__ bb,
    const float* __restrict__ res, float* __restrict__ out)
{
    __shared__ unsigned short lds[64][40];   // [p][k] padded to 40 (80B rows)
    int tid  = threadIdx.x;
    int lane = tid & 63;
    int w    = tid >> 6;
    int p0   = blockIdx.x * 64;
    int co0  = blockIdx.y * 64;
    int n    = blockIdx.z;
    const unsigned short* Xn = Xp + (size_t)n * C_ * PADPIX_;

    int sp = tid >> 2;
    int sk = (tid & 3) * 8;
    int po = poff[p0 + sp];

    const unsigned short* arow =
        Wb + (size_t)(co0 + w * 16 + (lane & 15)) * KTOT_ + ((lane >> 4) * 8);

    f32x4 acc[4];
    #pragma unroll
    for (int f = 0; f < 4; ++f) acc[f] = (f32x4){0.f, 0.f, 0.f, 0.f};

    for (int k0 = 0; k0 < KTOT_; k0 += KSTEP_) {
        const int4* kp = (const int4*)(koff + k0 + sk);
        int4 ka = kp[0], kc = kp[1];
        int kk[8] = {ka.x, ka.y, ka.z, ka.w, kc.x, kc.y, kc.z, kc.w};
        bf16x8 bv;
        #pragma unroll
        for (int j = 0; j < 8; ++j) bv[j] = (short)Xn[kk[j] + po];
        __syncthreads();
        *(bf16x8*)(&lds[sp][sk]) = bv;
        __syncthreads();
        bf16x8 a = *(const bf16x8*)(arow + k0);
        #pragma unroll
        for (int f = 0; f < 4; ++f) {
            bf16x8 b = *(const bf16x8*)(&lds[f * 16 + (lane & 15)][(lane >> 4) * 8]);
            acc[f] = __builtin_amdgcn_mfma_f32_16x16x32_bf16(a, b, acc[f], 0, 0, 0);
        }
    }

    #pragma unroll
    for (int f = 0; f < 4; ++f) {
        int p = p0 + f * 16 + (lane & 15);
        if (p < PIX_) {
            #pragma unroll
            for (int r = 0; r < 4; ++r) {
                int co = co0 + w * 16 + (lane >> 4) * 4 + r;
                float v = acc[f][r] * bn_scale(g[co]) + bb[co];
                if (RES) v += res[(size_t)(n * C_ + co) * PIX_ + p];
                out[(size_t)(n * C_ + co) * PIX_ + p] = v;
            }
        }
    }
}

// ---------------- posconv as implicit GEMM, bf16 MFMA (64ch, patches) ---------
__global__ __launch_bounds__(256) void posconv_mfma_k(
    const unsigned short* __restrict__ Up,   // padded patches bf16
    const unsigned short* __restrict__ Wb,   // [64][576] bf16
    const int* __restrict__ koff,            // [576]
    const int* __restrict__ poff,            // [npix_pad]
    const float* __restrict__ g, const float* __restrict__ bb,
    float* __restrict__ A, int L, int npix)
{
    __shared__ unsigned short lds[64][40];
    int tid  = threadIdx.x;
    int lane = tid & 63;
    int w    = tid >> 6;
    int p0   = blockIdx.x * 64;

    int sp = tid >> 2;
    int sk = (tid & 3) * 8;
    int po = poff[p0 + sp];

    const unsigned short* arow =
        Wb + (size_t)(w * 16 + (lane & 15)) * KPOS_ + ((lane >> 4) * 8);

    f32x4 acc[4];
    #pragma unroll
    for (int f = 0; f < 4; ++f) acc[f] = (f32x4){0.f, 0.f, 0.f, 0.f};

    for (int k0 = 0; k0 < KPOS_; k0 += KSTEP_) {
        const int4* kp = (const int4*)(koff + k0 + sk);
        int4 ka = kp[0], kc = kp[1];
        int kk[8] = {ka.x, ka.y, ka.z, ka.w, kc.x, kc.y, kc.z, kc.w};
        bf16x8 bv;
        #pragma unroll
        for (int j = 0; j < 8; ++j) bv[j] = (short)Up[kk[j] + po];
        __syncthreads();
        *(bf16x8*)(&lds[sp][sk]) = bv;
        __syncthreads();
        bf16x8 a = *(const bf16x8*)(arow + k0);
        #pragma unroll
        for (int f = 0; f < 4; ++f) {
            bf16x8 b = *(const bf16x8*)(&lds[f * 16 + (lane & 15)][(lane >> 4) * 8]);
            acc[f] = __builtin_amdgcn_mfma_f32_16x16x32_bf16(a, b, acc[f], 0, 0, 0);
        }
    }

    #pragma unroll
    for (int f = 0; f < 4; ++f) {
        int q = p0 + f * 16 + (lane & 15);
        if (q < npix) {
            int b = q / L, p = q % L;
            #pragma unroll
            for (int r = 0; r < 4; ++r) {
                int co = w * 16 + (lane >> 4) * 4 + r;
                A[(size_t)(b * 64 + co) * L + p] += acc[f][r] * bn_scale(g[co]) + bb[co];
            }
        }
    }
}

extern "C" void kernel_launch(void* const* d_in, const int* in_sizes, int n_in,
                              void* d_out, int out_size, void* d_ws, size_t ws_size,
                              hipStream_t stream) {
    const float* x       = (const float*)d_in[0];
    const float* conv1_w = (const float*)d_in[1];
    const float* bn1_g   = (const float*)d_in[2];
    const float* bn1_b   = (const float*)d_in[3];
    const float* conv2_w = (const float*)d_in[4];
    const float* bn2_g   = (const float*)d_in[5];
    const float* bn2_b   = (const float*)d_in[6];
    const float* conv3_w = (const float*)d_in[7];
    const float* bn3_g   = (const float*)d_in[8];
    const float* bn3_b   = (const float*)d_in[9];
    const float* pos_w   = (const float*)d_in[10];
    const float* bnp_g   = (const float*)d_in[11];
    const float* bnp_b   = (const float*)d_in[12];
    const float* q_w     = (const float*)d_in[13];
    const float* k_w     = (const float*)d_in[14];
    const float* v_w     = (const float*)d_in[15];
    const float* proj_w  = (const float*)d_in[16];

    float* ws  = (float*)d_ws;
    const int TENS = N_ * C_ * PIX_;          // 3,840,000
    const int UCAP = 288 * CB_ * 144;         // 2,654,208 (largest chunk)
    float* x1  = ws;
    float* cat = ws + TENS;
    float* h2  = ws + 2 * TENS;
    float* U   = ws + 3 * TENS;
    float* Qb  = U  + UCAP;
    float* Kb  = Qb + UCAP;
    float* Vb  = Kb + UCAP;
    float* Ob  = Vb + UCAP;
    float* Ab  = Ob + UCAP;

    // posconv scratch aliases h2 (dead until conv2 writes it after the loop)
    unsigned short* Up    = (unsigned short*)h2;              // <= 3,612,672 bf16
    unsigned short* pwb   = (unsigned short*)(h2 + 1900000);  // 36,864 bf16
    int*            koffp = (int*)(h2 + 1950000);             // 576
    int*            poffp = (int*)(h2 + 1960000);             // <= 41,536

    conv1x1_bn_k<<<(TENS + 255) / 256, 256, 0, stream>>>(x, conv1_w, bn1_g, bn1_b, x1);
    wcvt_k<<<(CB_ * KPOS_ + 255) / 256, 256, 0, stream>>>(pos_w, pwb, CB_ * KPOS_);

    const int NWs[3] = {4, 8, 12};
    const int SHs[3] = {25, 12, 8};
    const int KHs[3] = {25, 16, 12};
    const int BPs[3] = {32, 128, 288};

    for (int cidx = 0; cidx < 3; ++cidx) {
        int nw = NWs[cidx], sh = SHs[cidx], kh = KHs[cidx], Bp = BPs[cidx];
        int L = kh * kh;
        int totalU = Bp * CB_ * L;
        gather_u_k<<<(totalU + 255) / 256, 256, 0, stream>>>(x1, U, cidx, nw, sh, kh, totalU);

        unsigned short* Q16 = (unsigned short*)Qb;
        unsigned short* K16 = (unsigned short*)Kb;
        unsigned short* V16 = (unsigned short*)Vb;
        qkv_k<<<(totalU + 255) / 256, 256, 0, stream>>>(U, q_w, k_w, v_w, Q16, K16, V16, L, totalU);

        int nMt = (L + 31) / 32;
        int nLb = (L + 63) / 64;
        attn_mfma_k<<<dim3(nLb, Bp * 4), 256, 0, stream>>>(Q16, K16, V16, Ob, L, nMt);

        proj_res_k<<<(totalU + 255) / 256, 256, 0, stream>>>(Ob, U, proj_w, Ab, L, totalU);

        // posconv via MFMA
        int pw = kh + 2;
        int padTot = Bp * CB_ * pw * pw;
        int npix = Bp * L;
        int nblk = (npix + 63) / 64;
        int npix_pad = nblk * 64;
        padU_bf16_k<<<(padTot + 255) / 256, 256, 0, stream>>>(U, Up, kh, padTot);
        tables_pos_k<<<(npix_pad + 255) / 256, 256, 0, stream>>>(koffp, poffp, kh, npix, npix_pad);
        posconv_mfma_k<<<nblk, 256, 0, stream>>>(Up, pwb, koffp, poffp, bnp_g, bnp_b, Ab, L, npix);

        fold_k<<<(N_ * CB_ * PIX_ + 255) / 256, 256, 0, stream>>>(Ab, cat, cidx, nw, sh, kh);
    }

    // ---- MFMA path for the two 3x3 convs (buffers alias dead U region) ----
    unsigned short* Xb   = (unsigned short*)U;    // 3,995,136 bf16 (~8MB) <= UCAP floats
    unsigned short* w2b  = (unsigned short*)Qb;   // 331,776 bf16
    unsigned short* w3b  = (unsigned short*)Kb;   // 331,776 bf16
    int*            koff = (int*)Vb;              // 1728
    int*            poff = (int*)Ob;              // 10048

    tables_k<<<(10048 + 255) / 256, 256, 0, stream>>>(koff, poff);
    wcvt_k<<<(C_ * KTOT_ + 255) / 256, 256, 0, stream>>>(conv2_w, w2b, C_ * KTOT_);
    wcvt_k<<<(C_ * KTOT_ + 255) / 256, 256, 0, stream>>>(conv3_w, w3b, C_ * KTOT_);

    const int PADTOT = N_ * C_ * PADPIX_;
    pad_bf16_k<<<(PADTOT + 255) / 256, 256, 0, stream>>>(cat, Xb);
    conv3x3_mfma_k<true><<<dim3(157, 3, 2), 256, 0, stream>>>(
        Xb, w2b, koff, poff, bn2_g, bn2_b, x1, h2);
    pad_bf16_k<<<(PADTOT + 255) / 256, 256, 0, stream>>>(h2, Xb);
    conv3x3_mfma_k<false><<<dim3(157, 3, 2), 256, 0, stream>>>(
        Xb, w3b, koff, poff, bn3_g, bn3_b, nullptr, (float*)d_out);
}

// Round 6
// 788.818 us; speedup vs baseline: 4.5814x; 1.2124x over previous
//
#include <hip/hip_runtime.h>
#include <hip/hip_bf16.h>

#define N_ 2
#define C_ 192
#define CB_ 64
#define HW_ 100
#define PIX_ (HW_*HW_)
#define PADW_ 102
#define PADPIX_ (PADW_*PADW_)
#define KTOT_ 1728
#define KPOS_ 576
#define KSTEP_ 32

typedef __attribute__((ext_vector_type(8))) short bf16x8;
typedef __attribute__((ext_vector_type(4))) float f32x4;

static __device__ __forceinline__ float bn_scale(float g) {
    return g * rsqrtf(1.0f + 1e-5f);
}

static __device__ __forceinline__ unsigned short f2bf(float v) {
    __hip_bfloat16 h = __float2bfloat16(v);
    return *(unsigned short*)&h;
}

// ---------------- conv1x1 + BN as GEMM, bf16 MFMA ----------------
// D[co][p] = sum_ci W[co][ci] * x[ci][p]; x and w read fp32, cvt in-register.
__global__ __launch_bounds__(256) void conv1x1_mfma_k(
    const float* __restrict__ x, const float* __restrict__ w,
    const float* __restrict__ g, const float* __restrict__ bb,
    float* __restrict__ out)
{
    __shared__ unsigned short lds[64][40];   // [p][k] padded to 40
    int tid  = threadIdx.x;
    int lane = tid & 63;
    int wv   = tid >> 6;
    int p0   = blockIdx.x * 64;
    int co0  = blockIdx.y * 64;
    int n    = blockIdx.z;
    const float* xn = x + (size_t)n * C_ * PIX_;

    int sp = tid >> 2;
    int sk = (tid & 3) * 8;
    int pc = min(p0 + sp, PIX_ - 1);         // clamp tail

    const float* arow = w + (size_t)(co0 + wv * 16 + (lane & 15)) * C_ + ((lane >> 4) * 8);

    f32x4 acc[4];
    #pragma unroll
    for (int f = 0; f < 4; ++f) acc[f] = (f32x4){0.f, 0.f, 0.f, 0.f};

    for (int k0 = 0; k0 < C_; k0 += KSTEP_) {
        bf16x8 bv;
        #pragma unroll
        for (int j = 0; j < 8; ++j) bv[j] = (short)f2bf(xn[(size_t)(k0 + sk + j) * PIX_ + pc]);
        __syncthreads();
        *(bf16x8*)(&lds[sp][sk]) = bv;
        __syncthreads();
        bf16x8 a;
        const float* ap = arow + k0;
        #pragma unroll
        for (int j = 0; j < 8; ++j) a[j] = (short)f2bf(ap[j]);
        #pragma unroll
        for (int f = 0; f < 4; ++f) {
            bf16x8 b = *(const bf16x8*)(&lds[f * 16 + (lane & 15)][(lane >> 4) * 8]);
            acc[f] = __builtin_amdgcn_mfma_f32_16x16x32_bf16(a, b, acc[f], 0, 0, 0);
        }
    }

    #pragma unroll
    for (int f = 0; f < 4; ++f) {
        int p = p0 + f * 16 + (lane & 15);
        if (p < PIX_) {
            #pragma unroll
            for (int r = 0; r < 4; ++r) {
                int co = co0 + wv * 16 + (lane >> 4) * 4 + r;
                out[(size_t)(n * C_ + co) * PIX_ + p] = acc[f][r] * bn_scale(g[co]) + bb[co];
            }
        }
    }
}

// ---------------- gather patches into U (flat order n,cb,r,c,i,j) ----------------
__global__ __launch_bounds__(256) void gather_u_k(
    const float* __restrict__ x1, float* __restrict__ U,
    int cidx, int nw, int sh, int kh, int total)
{
    int f = blockIdx.x * 256 + threadIdx.x;
    if (f >= total) return;
    int t = f;
    int j = t % nw; t /= nw;
    int i = t % nw; t /= nw;
    int c = t % kh; t /= kh;
    int r = t % kh; t /= kh;
    int cb = t % CB_;
    int n  = t / CB_;
    int hh = i * sh + r;
    int ww = j * sh + c;
    U[f] = x1[((n * C_ + cidx * CB_ + cb) * HW_ + hh) * HW_ + ww];
}

// ---------------- q/k/v 1x1 convs -> bf16 ----------------
__global__ __launch_bounds__(256) void qkv_k(
    const float* __restrict__ U,
    const float* __restrict__ qw, const float* __restrict__ kw,
    const float* __restrict__ vw,
    unsigned short* __restrict__ Q, unsigned short* __restrict__ K,
    unsigned short* __restrict__ V,
    int L, int total)
{
    int idx = blockIdx.x * 256 + threadIdx.x;           // (b, co, p)
    if (idx >= total) return;
    int p  = idx % L;
    int co = (idx / L) % CB_;
    int b  = idx / (L * CB_);
    const float* ub = U + b * CB_ * L + p;
    const float* qr = qw + co * CB_;
    const float* kr = kw + co * CB_;
    const float* vr = vw + co * CB_;
    float aq = 0.f, ak = 0.f, av = 0.f;
    #pragma unroll 4
    for (int ci = 0; ci < CB_; ++ci) {
        float u = ub[ci * L];
        aq += u * qr[ci];
        ak += u * kr[ci];
        av += u * vr[ci];
    }
    Q[idx] = f2bf(aq); K[idx] = f2bf(ak); V[idx] = f2bf(av);
}

// ---------------- MFMA flash attention ----------------
__global__ __launch_bounds__(256) void attn_mfma_k(
    const unsigned short* __restrict__ Q, const unsigned short* __restrict__ K,
    const unsigned short* __restrict__ V, float* __restrict__ O,
    int L, int nMt)
{
    __shared__ unsigned short kt[32][24];   // [m][d]
    __shared__ unsigned short vt[16][40];   // [d][m]
    int tid  = threadIdx.x;
    int lane = tid & 63;
    int wv   = tid >> 6;
    int c    = lane & 15;
    int g    = lane >> 4;
    int bh = blockIdx.y;
    int b = bh >> 2, h = bh & 3;
    const unsigned short* qb = Q + (size_t)(b * 64 + h * 16) * L;
    const unsigned short* kb = K + (size_t)(b * 64 + h * 16) * L;
    const unsigned short* vb = V + (size_t)(b * 64 + h * 16) * L;
    float* ob = O + (size_t)(b * 64 + h * 16) * L;

    int l = blockIdx.x * 64 + wv * 16 + c;
    bool lval = (l < L);
    int lc = lval ? l : (L - 1);

    bf16x8 qf = (bf16x8){0,0,0,0,0,0,0,0};
    if (g < 2) {
        #pragma unroll
        for (int j = 0; j < 8; ++j) qf[j] = (short)qb[(g * 8 + j) * L + lc];
    }

    f32x4 acc = (f32x4){0.f, 0.f, 0.f, 0.f};
    float mrun = -1e30f, srun = 0.f;

    for (int mt = 0; mt < nMt; ++mt) {
        int m0 = mt * 32;
        __syncthreads();
        for (int e = tid; e < 1024; e += 256) {
            int m = e & 31, d = (e >> 5) & 15;
            int src = d * L + min(m0 + m, L - 1);
            if (e < 512) kt[m][d] = kb[src];
            else         vt[d][m] = vb[src];
        }
        __syncthreads();

        bf16x8 kf1 = (bf16x8){0,0,0,0,0,0,0,0}, kf2 = kf1;
        if (g < 2) {
            kf1 = *(const bf16x8*)(&kt[c][g * 8]);
            kf2 = *(const bf16x8*)(&kt[c + 16][g * 8]);
        }
        f32x4 s1 = __builtin_amdgcn_mfma_f32_16x16x32_bf16(
            kf1, qf, (f32x4){0.f,0.f,0.f,0.f}, 0, 0, 0);
        f32x4 s2 = __builtin_amdgcn_mfma_f32_16x16x32_bf16(
            kf2, qf, (f32x4){0.f,0.f,0.f,0.f}, 0, 0, 0);

        float p1[4], p2[4];
        float tmax = -1e30f;
        #pragma unroll
        for (int r = 0; r < 4; ++r) {
            int ma = m0 + g * 4 + r;
            float a  = (ma      < L) ? s1[r] * 0.25f : -1e30f;
            float b2 = (ma + 16 < L) ? s2[r] * 0.25f : -1e30f;
            p1[r] = a; p2[r] = b2;
            tmax = fmaxf(tmax, fmaxf(a, b2));
        }
        tmax = fmaxf(tmax, __shfl_xor(tmax, 16, 64));
        tmax = fmaxf(tmax, __shfl_xor(tmax, 32, 64));
        float mnew = fmaxf(mrun, tmax);
        float corr = __expf(mrun - mnew);
        float psum = 0.f;
        #pragma unroll
        for (int r = 0; r < 4; ++r) {
            p1[r] = __expf(p1[r] - mnew);
            p2[r] = __expf(p2[r] - mnew);
            psum += p1[r] + p2[r];
        }
        srun = srun * corr + psum;
        mrun = mnew;
        #pragma unroll
        for (int r = 0; r < 4; ++r) acc[r] *= corr;

        bf16x8 pbf;
        int t = g >> 1;
        #pragma unroll
        for (int j = 0; j < 8; ++j) {
            int srcLane = (((2 * g + (j >> 2)) & 3) << 4) | c;
            float v1 = __shfl(p1[j & 3], srcLane, 64);
            float v2 = __shfl(p2[j & 3], srcLane, 64);
            pbf[j] = (short)f2bf(t ? v2 : v1);
        }
        bf16x8 vf = *(const bf16x8*)(&vt[c][g * 8]);
        acc = __builtin_amdgcn_mfma_f32_16x16x32_bf16(vf, pbf, acc, 0, 0, 0);
    }

    float stot = srun;
    stot += __shfl_xor(stot, 16, 64);
    stot += __shfl_xor(stot, 32, 64);
    float inv = 1.f / stot;
    if (lval) {
        #pragma unroll
        for (int r = 0; r < 4; ++r)
            ob[(size_t)(g * 4 + r) * L + l] = acc[r] * inv;
    }
}

// ---------------- proj 1x1 + residual(U) -> A ----------------
__global__ __launch_bounds__(256) void proj_res_k(
    const float* __restrict__ O, const float* __restrict__ U,
    const float* __restrict__ pw, float* __restrict__ A,
    int L, int total)
{
    int idx = blockIdx.x * 256 + threadIdx.x;
    if (idx >= total) return;
    int p  = idx % L;
    int co = (idx / L) % CB_;
    int b  = idx / (L * CB_);
    const float* ob = O + b * CB_ * L + p;
    const float* pr = pw + co * CB_;
    float acc = 0.f;
    #pragma unroll 4
    for (int ci = 0; ci < CB_; ++ci) acc += ob[ci * L] * pr[ci];
    A[idx] = acc + U[idx];
}

// ---------------- fold (gather-style overlap-add with count div) ----------------
__global__ __launch_bounds__(256) void fold_k(
    const float* __restrict__ A, float* __restrict__ cat,
    int cidx, int nw, int sh, int kh)
{
    int idx = blockIdx.x * 256 + threadIdx.x;           // (n, cb, h, w)
    if (idx >= N_ * CB_ * PIX_) return;
    int w  = idx % HW_;
    int h  = (idx / HW_) % HW_;
    int cb = (idx / PIX_) % CB_;
    int n  = idx / (PIX_ * CB_);
    int numh = h - kh + 1;
    int ilo = numh > 0 ? (numh + sh - 1) / sh : 0;
    int ihi = min(nw - 1, h / sh);
    int numw = w - kh + 1;
    int jlo = numw > 0 ? (numw + sh - 1) / sh : 0;
    int jhi = min(nw - 1, w / sh);
    float sum = 0.f;
    for (int i = ilo; i <= ihi; ++i) {
        int r = h - i * sh;
        for (int j = jlo; j <= jhi; ++j) {
            int c = w - j * sh;
            int f = ((((n * CB_ + cb) * kh + r) * kh + c) * nw + i) * nw + j;
            sum += A[f];
        }
    }
    float cnt = (float)((ihi - ilo + 1) * (jhi - jlo + 1));
    cat[((n * C_ + cidx * CB_ + cb) * HW_ + h) * HW_ + w] = sum / cnt;
}

// ---------------- prep: pad fp32 image -> bf16 [N][C][102][102] ----------------
__global__ __launch_bounds__(256) void pad_bf16_k(
    const float* __restrict__ in, unsigned short* __restrict__ out)
{
    int idx = blockIdx.x * 256 + threadIdx.x;
    if (idx >= N_ * C_ * PADPIX_) return;
    int xx = idx % PADW_;
    int yy = (idx / PADW_) % PADW_;
    int c  = (idx / PADPIX_) % C_;
    int n  = idx / (PADPIX_ * C_);
    float v = 0.f;
    if (xx >= 1 && xx <= HW_ && yy >= 1 && yy <= HW_)
        v = in[((n * C_ + c) * HW_ + (yy - 1)) * HW_ + (xx - 1)];
    out[idx] = f2bf(v);
}

// ---------------- prep: weights fp32 -> bf16 flat ----------------
__global__ __launch_bounds__(256) void wcvt_k(
    const float* __restrict__ in, unsigned short* __restrict__ out, int total)
{
    int idx = blockIdx.x * 256 + threadIdx.x;
    if (idx >= total) return;
    out[idx] = f2bf(in[idx]);
}

// ---------------- prep: address tables (big conv) ----------------
__global__ __launch_bounds__(256) void tables_k(int* __restrict__ koff, int* __restrict__ poff)
{
    int i = blockIdx.x * 256 + threadIdx.x;
    if (i < KTOT_) {
        int ci = i / 9, off = i % 9;
        koff[i] = ci * PADPIX_ + (off / 3) * PADW_ + (off % 3);
    }
    if (i < 10048) {
        poff[i] = (i < PIX_) ? (i / HW_) * PADW_ + (i % HW_) : 0;
    }
}

// ---------------- prep: pad U (per chunk) -> bf16 [Bp][64][kh+2][kh+2] ----------
__global__ __launch_bounds__(256) void padU_bf16_k(
    const float* __restrict__ U, unsigned short* __restrict__ Up,
    int kh, int total)
{
    int pw = kh + 2;
    int idx = blockIdx.x * 256 + threadIdx.x;
    if (idx >= total) return;
    int xx = idx % pw;
    int yy = (idx / pw) % pw;
    int bc = idx / (pw * pw);
    float v = 0.f;
    if (xx >= 1 && xx <= kh && yy >= 1 && yy <= kh)
        v = U[bc * kh * kh + (yy - 1) * kh + (xx - 1)];
    Up[idx] = f2bf(v);
}

// ---------------- prep: address tables for posconv (per chunk) ----------------
__global__ __launch_bounds__(256) void tables_pos_k(
    int* __restrict__ koff, int* __restrict__ poff,
    int kh, int npix, int npix_pad)
{
    int pw = kh + 2;
    int i = blockIdx.x * 256 + threadIdx.x;
    if (i < KPOS_) {
        int ci = i / 9, off = i % 9;
        koff[i] = ci * pw * pw + (off / 3) * pw + (off % 3);
    }
    if (i < npix_pad) {
        if (i < npix) {
            int b = i / (kh * kh), p = i % (kh * kh);
            poff[i] = b * 64 * pw * pw + (p / kh) * pw + (p % kh);
        } else {
            poff[i] = 0;
        }
    }
}

// ---------------- 3x3 conv as implicit GEMM, bf16 MFMA (192ch, big image) -----
template<bool RES>
__global__ __launch_bounds__(256) void conv3x3_mfma_k(
    const unsigned short* __restrict__ Xp,
    const unsigned short* __restrict__ Wb,
    const int* __restrict__ koff,
    const int* __restrict__ poff,
    const float* __restrict__ g, const float* __restrict__ bb,
    const float* __restrict__ res, float* __restrict__ out)
{
    __shared__ unsigned short lds[64][40];
    int tid  = threadIdx.x;
    int lane = tid & 63;
    int w    = tid >> 6;
    int p0   = blockIdx.x * 64;
    int co0  = blockIdx.y * 64;
    int n    = blockIdx.z;
    const unsigned short* Xn = Xp + (size_t)n * C_ * PADPIX_;

    int sp = tid >> 2;
    int sk = (tid & 3) * 8;
    int po = poff[p0 + sp];

    const unsigned short* arow =
        Wb + (size_t)(co0 + w * 16 + (lane & 15)) * KTOT_ + ((lane >> 4) * 8);

    f32x4 acc[4];
    #pragma unroll
    for (int f = 0; f < 4; ++f) acc[f] = (f32x4){0.f, 0.f, 0.f, 0.f};

    for (int k0 = 0; k0 < KTOT_; k0 += KSTEP_) {
        const int4* kp = (const int4*)(koff + k0 + sk);
        int4 ka = kp[0], kc = kp[1];
        int kk[8] = {ka.x, ka.y, ka.z, ka.w, kc.x, kc.y, kc.z, kc.w};
        bf16x8 bv;
        #pragma unroll
        for (int j = 0; j < 8; ++j) bv[j] = (short)Xn[kk[j] + po];
        __syncthreads();
        *(bf16x8*)(&lds[sp][sk]) = bv;
        __syncthreads();
        bf16x8 a = *(const bf16x8*)(arow + k0);
        #pragma unroll
        for (int f = 0; f < 4; ++f) {
            bf16x8 b = *(const bf16x8*)(&lds[f * 16 + (lane & 15)][(lane >> 4) * 8]);
            acc[f] = __builtin_amdgcn_mfma_f32_16x16x32_bf16(a, b, acc[f], 0, 0, 0);
        }
    }

    #pragma unroll
    for (int f = 0; f < 4; ++f) {
        int p = p0 + f * 16 + (lane & 15);
        if (p < PIX_) {
            #pragma unroll
            for (int r = 0; r < 4; ++r) {
                int co = co0 + w * 16 + (lane >> 4) * 4 + r;
                float v = acc[f][r] * bn_scale(g[co]) + bb[co];
                if (RES) v += res[(size_t)(n * C_ + co) * PIX_ + p];
                out[(size_t)(n * C_ + co) * PIX_ + p] = v;
            }
        }
    }
}

// ---------------- posconv as implicit GEMM, bf16 MFMA (64ch, patches) ---------
__global__ __launch_bounds__(256) void posconv_mfma_k(
    const unsigned short* __restrict__ Up,
    const unsigned short* __restrict__ Wb,
    const int* __restrict__ koff,
    const int* __restrict__ poff,
    const float* __restrict__ g, const float* __restrict__ bb,
    float* __restrict__ A, int L, int npix)
{
    __shared__ unsigned short lds[64][40];
    int tid  = threadIdx.x;
    int lane = tid & 63;
    int w    = tid >> 6;
    int p0   = blockIdx.x * 64;

    int sp = tid >> 2;
    int sk = (tid & 3) * 8;
    int po = poff[p0 + sp];

    const unsigned short* arow =
        Wb + (size_t)(w * 16 + (lane & 15)) * KPOS_ + ((lane >> 4) * 8);

    f32x4 acc[4];
    #pragma unroll
    for (int f = 0; f < 4; ++f) acc[f] = (f32x4){0.f, 0.f, 0.f, 0.f};

    for (int k0 = 0; k0 < KPOS_; k0 += KSTEP_) {
        const int4* kp = (const int4*)(koff + k0 + sk);
        int4 ka = kp[0], kc = kp[1];
        int kk[8] = {ka.x, ka.y, ka.z, ka.w, kc.x, kc.y, kc.z, kc.w};
        bf16x8 bv;
        #pragma unroll
        for (int j = 0; j < 8; ++j) bv[j] = (short)Up[kk[j] + po];
        __syncthreads();
        *(bf16x8*)(&lds[sp][sk]) = bv;
        __syncthreads();
        bf16x8 a = *(const bf16x8*)(arow + k0);
        #pragma unroll
        for (int f = 0; f < 4; ++f) {
            bf16x8 b = *(const bf16x8*)(&lds[f * 16 + (lane & 15)][(lane >> 4) * 8]);
            acc[f] = __builtin_amdgcn_mfma_f32_16x16x32_bf16(a, b, acc[f], 0, 0, 0);
        }
    }

    #pragma unroll
    for (int f = 0; f < 4; ++f) {
        int q = p0 + f * 16 + (lane & 15);
        if (q < npix) {
            int b = q / L, p = q % L;
            #pragma unroll
            for (int r = 0; r < 4; ++r) {
                int co = w * 16 + (lane >> 4) * 4 + r;
                A[(size_t)(b * 64 + co) * L + p] += acc[f][r] * bn_scale(g[co]) + bb[co];
            }
        }
    }
}

extern "C" void kernel_launch(void* const* d_in, const int* in_sizes, int n_in,
                              void* d_out, int out_size, void* d_ws, size_t ws_size,
                              hipStream_t stream) {
    const float* x       = (const float*)d_in[0];
    const float* conv1_w = (const float*)d_in[1];
    const float* bn1_g   = (const float*)d_in[2];
    const float* bn1_b   = (const float*)d_in[3];
    const float* conv2_w = (const float*)d_in[4];
    const float* bn2_g   = (const float*)d_in[5];
    const float* bn2_b   = (const float*)d_in[6];
    const float* conv3_w = (const float*)d_in[7];
    const float* bn3_g   = (const float*)d_in[8];
    const float* bn3_b   = (const float*)d_in[9];
    const float* pos_w   = (const float*)d_in[10];
    const float* bnp_g   = (const float*)d_in[11];
    const float* bnp_b   = (const float*)d_in[12];
    const float* q_w     = (const float*)d_in[13];
    const float* k_w     = (const float*)d_in[14];
    const float* v_w     = (const float*)d_in[15];
    const float* proj_w  = (const float*)d_in[16];

    float* ws  = (float*)d_ws;
    const int TENS = N_ * C_ * PIX_;          // 3,840,000
    const int UCAP = 288 * CB_ * 144;         // 2,654,208 (largest chunk)
    float* x1  = ws;
    float* cat = ws + TENS;
    float* h2  = ws + 2 * TENS;
    float* U   = ws + 3 * TENS;
    float* Qb  = U  + UCAP;
    float* Kb  = Qb + UCAP;
    float* Vb  = Kb + UCAP;
    float* Ob  = Vb + UCAP;
    float* Ab  = Ob + UCAP;

    // posconv scratch aliases h2 (dead until conv2 writes it after the loop)
    unsigned short* Up    = (unsigned short*)h2;              // <= 3,612,672 bf16
    unsigned short* pwb   = (unsigned short*)(h2 + 1900000);  // 36,864 bf16
    int*            koffp = (int*)(h2 + 1950000);             // 576
    int*            poffp = (int*)(h2 + 1960000);             // <= 41,536

    conv1x1_mfma_k<<<dim3(157, 3, 2), 256, 0, stream>>>(x, conv1_w, bn1_g, bn1_b, x1);
    wcvt_k<<<(CB_ * KPOS_ + 255) / 256, 256, 0, stream>>>(pos_w, pwb, CB_ * KPOS_);

    const int NWs[3] = {4, 8, 12};
    const int SHs[3] = {25, 12, 8};
    const int KHs[3] = {25, 16, 12};
    const int BPs[3] = {32, 128, 288};

    for (int cidx = 0; cidx < 3; ++cidx) {
        int nw = NWs[cidx], sh = SHs[cidx], kh = KHs[cidx], Bp = BPs[cidx];
        int L = kh * kh;
        int totalU = Bp * CB_ * L;
        gather_u_k<<<(totalU + 255) / 256, 256, 0, stream>>>(x1, U, cidx, nw, sh, kh, totalU);

        unsigned short* Q16 = (unsigned short*)Qb;
        unsigned short* K16 = (unsigned short*)Kb;
        unsigned short* V16 = (unsigned short*)Vb;
        qkv_k<<<(totalU + 255) / 256, 256, 0, stream>>>(U, q_w, k_w, v_w, Q16, K16, V16, L, totalU);

        int nMt = (L + 31) / 32;
        int nLb = (L + 63) / 64;
        attn_mfma_k<<<dim3(nLb, Bp * 4), 256, 0, stream>>>(Q16, K16, V16, Ob, L, nMt);

        proj_res_k<<<(totalU + 255) / 256, 256, 0, stream>>>(Ob, U, proj_w, Ab, L, totalU);

        // posconv via MFMA
        int pw = kh + 2;
        int padTot = Bp * CB_ * pw * pw;
        int npix = Bp * L;
        int nblk = (npix + 63) / 64;
        int npix_pad = nblk * 64;
        padU_bf16_k<<<(padTot + 255) / 256, 256, 0, stream>>>(U, Up, kh, padTot);
        tables_pos_k<<<(npix_pad + 255) / 256, 256, 0, stream>>>(koffp, poffp, kh, npix, npix_pad);
        posconv_mfma_k<<<nblk, 256, 0, stream>>>(Up, pwb, koffp, poffp, bnp_g, bnp_b, Ab, L, npix);

        fold_k<<<(N_ * CB_ * PIX_ + 255) / 256, 256, 0, stream>>>(Ab, cat, cidx, nw, sh, kh);
    }

    // ---- MFMA path for the two 3x3 convs (buffers alias dead U region) ----
    unsigned short* Xb   = (unsigned short*)U;    // 3,995,136 bf16 (~8MB)
    unsigned short* w2b  = (unsigned short*)Qb;   // 331,776 bf16
    unsigned short* w3b  = (unsigned short*)Kb;   // 331,776 bf16
    int*            koff = (int*)Vb;              // 1728
    int*            poff = (int*)Ob;              // 10048

    tables_k<<<(10048 + 255) / 256, 256, 0, stream>>>(koff, poff);
    wcvt_k<<<(C_ * KTOT_ + 255) / 256, 256, 0, stream>>>(conv2_w, w2b, C_ * KTOT_);
    wcvt_k<<<(C_ * KTOT_ + 255) / 256, 256, 0, stream>>>(conv3_w, w3b, C_ * KTOT_);

    const int PADTOT = N_ * C_ * PADPIX_;
    pad_bf16_k<<<(PADTOT + 255) / 256, 256, 0, stream>>>(cat, Xb);
    conv3x3_mfma_k<true><<<dim3(157, 3, 2), 256, 0, stream>>>(
        Xb, w2b, koff, poff, bn2_g, bn2_b, x1, h2);
    pad_bf16_k<<<(PADTOT + 255) / 256, 256, 0, stream>>>(h2, Xb);
    conv3x3_mfma_k<false><<<dim3(157, 3, 2), 256, 0, stream>>>(
        Xb, w3b, koff, poff, bn3_g, bn3_b, nullptr, (float*)d_out);
}

// Round 7
// 555.350 us; speedup vs baseline: 6.5074x; 1.4204x over previous
//
#include <hip/hip_runtime.h>
#include <hip/hip_bf16.h>

#define N_ 2
#define C_ 192
#define CB_ 64
#define HW_ 100
#define PIX_ (HW_*HW_)
#define PADW_ 102
#define PADPIX_ (PADW_*PADW_)
#define KTOT_ 1728
#define KPOS_ 576

typedef __attribute__((ext_vector_type(8))) short bf16x8;
typedef __attribute__((ext_vector_type(4))) float f32x4;

static __device__ __forceinline__ float bn_scale(float g) {
    return g * rsqrtf(1.0f + 1e-5f);
}

static __device__ __forceinline__ unsigned short f2bf(float v) {
    __hip_bfloat16 h = __float2bfloat16(v);
    return *(unsigned short*)&h;
}

// ---------------- conv1x1 + BN as GEMM, bf16 MFMA (K=192, 3 pipelined steps) --
__global__ __launch_bounds__(256) void conv1x1_mfma_k(
    const float* __restrict__ x, const float* __restrict__ w,
    const float* __restrict__ g, const float* __restrict__ bb,
    float* __restrict__ out)
{
    __shared__ unsigned short lds[64][72];
    int tid  = threadIdx.x;
    int lane = tid & 63;
    int wv   = tid >> 6;
    int c    = lane & 15;
    int g8   = (lane >> 4) * 8;
    int p0   = blockIdx.x * 64;
    int co0  = blockIdx.y * 64;
    int n    = blockIdx.z;
    const float* xn = x + (size_t)n * C_ * PIX_;

    int sp = tid >> 2;
    int sk = (tid & 3) * 8;
    int pc = min(p0 + sp, PIX_ - 1);

    const float* arow = w + (size_t)(co0 + wv * 16 + c) * C_;

    f32x4 acc[4];
    #pragma unroll
    for (int f = 0; f < 4; ++f) acc[f] = (f32x4){0.f, 0.f, 0.f, 0.f};

    bf16x8 b0, b1;
    #pragma unroll
    for (int j = 0; j < 8; ++j) {
        b0[j] = (short)f2bf(xn[(size_t)(sk + j) * PIX_ + pc]);
        b1[j] = (short)f2bf(xn[(size_t)(32 + sk + j) * PIX_ + pc]);
    }

    for (int k0 = 0; k0 < C_; k0 += 64) {
        __syncthreads();
        *(bf16x8*)(&lds[sp][sk])      = b0;
        *(bf16x8*)(&lds[sp][32 + sk]) = b1;
        __syncthreads();
        if (k0 + 64 < C_) {
            #pragma unroll
            for (int j = 0; j < 8; ++j) {
                b0[j] = (short)f2bf(xn[(size_t)(k0 + 64 + sk + j) * PIX_ + pc]);
                b1[j] = (short)f2bf(xn[(size_t)(k0 + 96 + sk + j) * PIX_ + pc]);
            }
        }
        #pragma unroll
        for (int h = 0; h < 2; ++h) {
            bf16x8 a;
            const float* ap = arow + k0 + h * 32 + g8;
            #pragma unroll
            for (int j = 0; j < 8; ++j) a[j] = (short)f2bf(ap[j]);
            #pragma unroll
            for (int f = 0; f < 4; ++f) {
                bf16x8 b = *(const bf16x8*)(&lds[f * 16 + c][h * 32 + g8]);
                acc[f] = __builtin_amdgcn_mfma_f32_16x16x32_bf16(a, b, acc[f], 0, 0, 0);
            }
        }
    }

    #pragma unroll
    for (int f = 0; f < 4; ++f) {
        int p = p0 + f * 16 + c;
        if (p < PIX_) {
            #pragma unroll
            for (int r = 0; r < 4; ++r) {
                int co = co0 + wv * 16 + (lane >> 4) * 4 + r;
                out[(size_t)(n * C_ + co) * PIX_ + p] = acc[f][r] * bn_scale(g[co]) + bb[co];
            }
        }
    }
}

// ---------------- gather patches into U (flat order n,cb,r,c,i,j) ----------------
__global__ __launch_bounds__(256) void gather_u_k(
    const float* __restrict__ x1, float* __restrict__ U,
    int cidx, int nw, int sh, int kh, int total)
{
    int f = blockIdx.x * 256 + threadIdx.x;
    if (f >= total) return;
    int t = f;
    int j = t % nw; t /= nw;
    int i = t % nw; t /= nw;
    int c = t % kh; t /= kh;
    int r = t % kh; t /= kh;
    int cb = t % CB_;
    int n  = t / CB_;
    int hh = i * sh + r;
    int ww = j * sh + c;
    U[f] = x1[((n * C_ + cidx * CB_ + cb) * HW_ + hh) * HW_ + ww];
}

// ---------------- q/k/v 1x1 convs as GEMM, bf16 MFMA (K=64) -------------------
// blockIdx.y selects q/k/v. D[co][q] = sum_ci W[co][ci] * U[b(q)][ci][p(q)].
__global__ __launch_bounds__(256) void qkv_mfma_k(
    const float* __restrict__ U,
    const float* __restrict__ qw, const float* __restrict__ kw,
    const float* __restrict__ vw,
    unsigned short* __restrict__ Q, unsigned short* __restrict__ K,
    unsigned short* __restrict__ V,
    int L, int npix)
{
    __shared__ unsigned short lds[64][72];
    int tid  = threadIdx.x;
    int lane = tid & 63;
    int wv   = tid >> 6;
    int c    = lane & 15;
    int g8   = (lane >> 4) * 8;
    int q0   = blockIdx.x * 64;
    int sel  = blockIdx.y;
    const float* wsel = (sel == 0) ? qw : (sel == 1) ? kw : vw;
    unsigned short* osel = (sel == 0) ? Q : (sel == 1) ? K : V;

    int sp = tid >> 2;
    int sk = (tid & 3) * 8;
    int qc = min(q0 + sp, npix - 1);
    int b  = qc / L, p = qc % L;
    const float* ub = U + (size_t)b * 64 * L + p;

    bf16x8 b0, b1;
    #pragma unroll
    for (int j = 0; j < 8; ++j) {
        b0[j] = (short)f2bf(ub[(size_t)(sk + j) * L]);
        b1[j] = (short)f2bf(ub[(size_t)(32 + sk + j) * L]);
    }
    __syncthreads();
    *(bf16x8*)(&lds[sp][sk])      = b0;
    *(bf16x8*)(&lds[sp][32 + sk]) = b1;
    __syncthreads();

    f32x4 acc[4];
    #pragma unroll
    for (int f = 0; f < 4; ++f) acc[f] = (f32x4){0.f, 0.f, 0.f, 0.f};

    const float* arow = wsel + (size_t)(wv * 16 + c) * 64;
    #pragma unroll
    for (int h = 0; h < 2; ++h) {
        bf16x8 a;
        const float* ap = arow + h * 32 + g8;
        #pragma unroll
        for (int j = 0; j < 8; ++j) a[j] = (short)f2bf(ap[j]);
        #pragma unroll
        for (int f = 0; f < 4; ++f) {
            bf16x8 bfr = *(const bf16x8*)(&lds[f * 16 + c][h * 32 + g8]);
            acc[f] = __builtin_amdgcn_mfma_f32_16x16x32_bf16(a, bfr, acc[f], 0, 0, 0);
        }
    }

    #pragma unroll
    for (int f = 0; f < 4; ++f) {
        int qq = q0 + f * 16 + c;
        if (qq < npix) {
            int bo = qq / L, po = qq % L;
            #pragma unroll
            for (int r = 0; r < 4; ++r) {
                int co = wv * 16 + (lane >> 4) * 4 + r;
                osel[(size_t)(bo * 64 + co) * L + po] = f2bf(acc[f][r]);
            }
        }
    }
}

// ---------------- proj 1x1 + residual(U) as GEMM, bf16 MFMA (K=64) ------------
__global__ __launch_bounds__(256) void proj_mfma_k(
    const float* __restrict__ O, const float* __restrict__ U,
    const float* __restrict__ pw, float* __restrict__ A,
    int L, int npix)
{
    __shared__ unsigned short lds[64][72];
    int tid  = threadIdx.x;
    int lane = tid & 63;
    int wv   = tid >> 6;
    int c    = lane & 15;
    int g8   = (lane >> 4) * 8;
    int q0   = blockIdx.x * 64;

    int sp = tid >> 2;
    int sk = (tid & 3) * 8;
    int qc = min(q0 + sp, npix - 1);
    int b  = qc / L, p = qc % L;
    const float* ob = O + (size_t)b * 64 * L + p;

    bf16x8 b0, b1;
    #pragma unroll
    for (int j = 0; j < 8; ++j) {
        b0[j] = (short)f2bf(ob[(size_t)(sk + j) * L]);
        b1[j] = (short)f2bf(ob[(size_t)(32 + sk + j) * L]);
    }
    __syncthreads();
    *(bf16x8*)(&lds[sp][sk])      = b0;
    *(bf16x8*)(&lds[sp][32 + sk]) = b1;
    __syncthreads();

    f32x4 acc[4];
    #pragma unroll
    for (int f = 0; f < 4; ++f) acc[f] = (f32x4){0.f, 0.f, 0.f, 0.f};

    const float* arow = pw + (size_t)(wv * 16 + c) * 64;
    #pragma unroll
    for (int h = 0; h < 2; ++h) {
        bf16x8 a;
        const float* ap = arow + h * 32 + g8;
        #pragma unroll
        for (int j = 0; j < 8; ++j) a[j] = (short)f2bf(ap[j]);
        #pragma unroll
        for (int f = 0; f < 4; ++f) {
            bf16x8 bfr = *(const bf16x8*)(&lds[f * 16 + c][h * 32 + g8]);
            acc[f] = __builtin_amdgcn_mfma_f32_16x16x32_bf16(a, bfr, acc[f], 0, 0, 0);
        }
    }

    #pragma unroll
    for (int f = 0; f < 4; ++f) {
        int qq = q0 + f * 16 + c;
        if (qq < npix) {
            int bo = qq / L, po = qq % L;
            #pragma unroll
            for (int r = 0; r < 4; ++r) {
                int co = wv * 16 + (lane >> 4) * 4 + r;
                size_t oi = (size_t)(bo * 64 + co) * L + po;
                A[oi] = acc[f][r] + U[oi];
            }
        }
    }
}

// ---------------- MFMA flash attention ----------------
__global__ __launch_bounds__(256) void attn_mfma_k(
    const unsigned short* __restrict__ Q, const unsigned short* __restrict__ K,
    const unsigned short* __restrict__ V, float* __restrict__ O,
    int L, int nMt)
{
    __shared__ unsigned short kt[32][24];   // [m][d]
    __shared__ unsigned short vt[16][40];   // [d][m]
    int tid  = threadIdx.x;
    int lane = tid & 63;
    int wv   = tid >> 6;
    int c    = lane & 15;
    int g    = lane >> 4;
    int bh = blockIdx.y;
    int b = bh >> 2, h = bh & 3;
    const unsigned short* qb = Q + (size_t)(b * 64 + h * 16) * L;
    const unsigned short* kb = K + (size_t)(b * 64 + h * 16) * L;
    const unsigned short* vb = V + (size_t)(b * 64 + h * 16) * L;
    float* ob = O + (size_t)(b * 64 + h * 16) * L;

    int l = blockIdx.x * 64 + wv * 16 + c;
    bool lval = (l < L);
    int lc = lval ? l : (L - 1);

    bf16x8 qf = (bf16x8){0,0,0,0,0,0,0,0};
    if (g < 2) {
        #pragma unroll
        for (int j = 0; j < 8; ++j) qf[j] = (short)qb[(g * 8 + j) * L + lc];
    }

    f32x4 acc = (f32x4){0.f, 0.f, 0.f, 0.f};
    float mrun = -1e30f, srun = 0.f;

    for (int mt = 0; mt < nMt; ++mt) {
        int m0 = mt * 32;
        __syncthreads();
        for (int e = tid; e < 1024; e += 256) {
            int m = e & 31, d = (e >> 5) & 15;
            int src = d * L + min(m0 + m, L - 1);
            if (e < 512) kt[m][d] = kb[src];
            else         vt[d][m] = vb[src];
        }
        __syncthreads();

        bf16x8 kf1 = (bf16x8){0,0,0,0,0,0,0,0}, kf2 = kf1;
        if (g < 2) {
            kf1 = *(const bf16x8*)(&kt[c][g * 8]);
            kf2 = *(const bf16x8*)(&kt[c + 16][g * 8]);
        }
        f32x4 s1 = __builtin_amdgcn_mfma_f32_16x16x32_bf16(
            kf1, qf, (f32x4){0.f,0.f,0.f,0.f}, 0, 0, 0);
        f32x4 s2 = __builtin_amdgcn_mfma_f32_16x16x32_bf16(
            kf2, qf, (f32x4){0.f,0.f,0.f,0.f}, 0, 0, 0);

        float p1[4], p2[4];
        float tmax = -1e30f;
        #pragma unroll
        for (int r = 0; r < 4; ++r) {
            int ma = m0 + g * 4 + r;
            float a  = (ma      < L) ? s1[r] * 0.25f : -1e30f;
            float b2 = (ma + 16 < L) ? s2[r] * 0.25f : -1e30f;
            p1[r] = a; p2[r] = b2;
            tmax = fmaxf(tmax, fmaxf(a, b2));
        }
        tmax = fmaxf(tmax, __shfl_xor(tmax, 16, 64));
        tmax = fmaxf(tmax, __shfl_xor(tmax, 32, 64));
        float mnew = fmaxf(mrun, tmax);
        float corr = __expf(mrun - mnew);
        float psum = 0.f;
        #pragma unroll
        for (int r = 0; r < 4; ++r) {
            p1[r] = __expf(p1[r] - mnew);
            p2[r] = __expf(p2[r] - mnew);
            psum += p1[r] + p2[r];
        }
        srun = srun * corr + psum;
        mrun = mnew;
        #pragma unroll
        for (int r = 0; r < 4; ++r) acc[r] *= corr;

        bf16x8 pbf;
        int t = g >> 1;
        #pragma unroll
        for (int j = 0; j < 8; ++j) {
            int srcLane = (((2 * g + (j >> 2)) & 3) << 4) | c;
            float v1 = __shfl(p1[j & 3], srcLane, 64);
            float v2 = __shfl(p2[j & 3], srcLane, 64);
            pbf[j] = (short)f2bf(t ? v2 : v1);
        }
        bf16x8 vf = *(const bf16x8*)(&vt[c][g * 8]);
        acc = __builtin_amdgcn_mfma_f32_16x16x32_bf16(vf, pbf, acc, 0, 0, 0);
    }

    float stot = srun;
    stot += __shfl_xor(stot, 16, 64);
    stot += __shfl_xor(stot, 32, 64);
    float inv = 1.f / stot;
    if (lval) {
        #pragma unroll
        for (int r = 0; r < 4; ++r)
            ob[(size_t)(g * 4 + r) * L + l] = acc[r] * inv;
    }
}

// ---------------- fold (gather-style overlap-add with count div) ----------------
__global__ __launch_bounds__(256) void fold_k(
    const float* __restrict__ A, float* __restrict__ cat,
    int cidx, int nw, int sh, int kh)
{
    int idx = blockIdx.x * 256 + threadIdx.x;           // (n, cb, h, w)
    if (idx >= N_ * CB_ * PIX_) return;
    int w  = idx % HW_;
    int h  = (idx / HW_) % HW_;
    int cb = (idx / PIX_) % CB_;
    int n  = idx / (PIX_ * CB_);
    int numh = h - kh + 1;
    int ilo = numh > 0 ? (numh + sh - 1) / sh : 0;
    int ihi = min(nw - 1, h / sh);
    int numw = w - kh + 1;
    int jlo = numw > 0 ? (numw + sh - 1) / sh : 0;
    int jhi = min(nw - 1, w / sh);
    float sum = 0.f;
    for (int i = ilo; i <= ihi; ++i) {
        int r = h - i * sh;
        for (int j = jlo; j <= jhi; ++j) {
            int c = w - j * sh;
            int f = ((((n * CB_ + cb) * kh + r) * kh + c) * nw + i) * nw + j;
            sum += A[f];
        }
    }
    float cnt = (float)((ihi - ilo + 1) * (jhi - jlo + 1));
    cat[((n * C_ + cidx * CB_ + cb) * HW_ + h) * HW_ + w] = sum / cnt;
}

// ---------------- prep: pad fp32 image -> bf16 [N][C][102][102] ----------------
__global__ __launch_bounds__(256) void pad_bf16_k(
    const float* __restrict__ in, unsigned short* __restrict__ out)
{
    int idx = blockIdx.x * 256 + threadIdx.x;
    if (idx >= N_ * C_ * PADPIX_) return;
    int xx = idx % PADW_;
    int yy = (idx / PADW_) % PADW_;
    int c  = (idx / PADPIX_) % C_;
    int n  = idx / (PADPIX_ * C_);
    float v = 0.f;
    if (xx >= 1 && xx <= HW_ && yy >= 1 && yy <= HW_)
        v = in[((n * C_ + c) * HW_ + (yy - 1)) * HW_ + (xx - 1)];
    out[idx] = f2bf(v);
}

// ---------------- prep: weights fp32 -> bf16 flat ----------------
__global__ __launch_bounds__(256) void wcvt_k(
    const float* __restrict__ in, unsigned short* __restrict__ out, int total)
{
    int idx = blockIdx.x * 256 + threadIdx.x;
    if (idx >= total) return;
    out[idx] = f2bf(in[idx]);
}

// ---------------- prep: address tables (big conv) ----------------
__global__ __launch_bounds__(256) void tables_k(int* __restrict__ koff, int* __restrict__ poff)
{
    int i = blockIdx.x * 256 + threadIdx.x;
    if (i < KTOT_) {
        int ci = i / 9, off = i % 9;
        koff[i] = ci * PADPIX_ + (off / 3) * PADW_ + (off % 3);
    }
    if (i < 10048) {
        poff[i] = (i < PIX_) ? (i / HW_) * PADW_ + (i % HW_) : 0;
    }
}

// ---------------- prep: pad U (per chunk) -> bf16 [Bp][64][kh+2][kh+2] ----------
__global__ __launch_bounds__(256) void padU_bf16_k(
    const float* __restrict__ U, unsigned short* __restrict__ Up,
    int kh, int total)
{
    int pw = kh + 2;
    int idx = blockIdx.x * 256 + threadIdx.x;
    if (idx >= total) return;
    int xx = idx % pw;
    int yy = (idx / pw) % pw;
    int bc = idx / (pw * pw);
    float v = 0.f;
    if (xx >= 1 && xx <= kh && yy >= 1 && yy <= kh)
        v = U[bc * kh * kh + (yy - 1) * kh + (xx - 1)];
    Up[idx] = f2bf(v);
}

// ---------------- prep: address tables for posconv (per chunk) ----------------
__global__ __launch_bounds__(256) void tables_pos_k(
    int* __restrict__ koff, int* __restrict__ poff,
    int kh, int npix, int npix_pad)
{
    int pw = kh + 2;
    int i = blockIdx.x * 256 + threadIdx.x;
    if (i < KPOS_) {
        int ci = i / 9, off = i % 9;
        koff[i] = ci * pw * pw + (off / 3) * pw + (off % 3);
    }
    if (i < npix_pad) {
        if (i < npix) {
            int b = i / (kh * kh), p = i % (kh * kh);
            poff[i] = b * 64 * pw * pw + (p / kh) * pw + (p % kh);
        } else {
            poff[i] = 0;
        }
    }
}

// ---------------- 3x3 conv as implicit GEMM, bf16 MFMA, pipelined K=64 steps --
template<bool RES>
__global__ __launch_bounds__(256) void conv3x3_mfma_k(
    const unsigned short* __restrict__ Xp,
    const unsigned short* __restrict__ Wb,
    const int* __restrict__ koff,
    const int* __restrict__ poff,
    const float* __restrict__ g, const float* __restrict__ bb,
    const float* __restrict__ res, float* __restrict__ out)
{
    __shared__ unsigned short lds[64][72];
    int tid  = threadIdx.x;
    int lane = tid & 63;
    int wv   = tid >> 6;
    int c    = lane & 15;
    int g8   = (lane >> 4) * 8;
    int p0   = blockIdx.x * 64;
    int co0  = blockIdx.y * 64;
    int n    = blockIdx.z;
    const unsigned short* Xn = Xp + (size_t)n * C_ * PADPIX_;

    int sp = tid >> 2;
    int sk = (tid & 3) * 8;
    int po = poff[p0 + sp];

    const unsigned short* arow = Wb + (size_t)(co0 + wv * 16 + c) * KTOT_;

    f32x4 acc[4];
    #pragma unroll
    for (int f = 0; f < 4; ++f) acc[f] = (f32x4){0.f, 0.f, 0.f, 0.f};

    bf16x8 b0, b1, a0, a1;
    #pragma unroll
    for (int h = 0; h < 2; ++h) {
        const int4* kp = (const int4*)(koff + h * 32 + sk);
        int4 ka = kp[0], kc = kp[1];
        int kk[8] = {ka.x, ka.y, ka.z, ka.w, kc.x, kc.y, kc.z, kc.w};
        bf16x8 v;
        #pragma unroll
        for (int j = 0; j < 8; ++j) v[j] = (short)Xn[kk[j] + po];
        if (h) b1 = v; else b0 = v;
    }
    a0 = *(const bf16x8*)(arow + g8);
    a1 = *(const bf16x8*)(arow + 32 + g8);

    for (int k0 = 0; k0 < KTOT_; k0 += 64) {
        __syncthreads();
        *(bf16x8*)(&lds[sp][sk])      = b0;
        *(bf16x8*)(&lds[sp][32 + sk]) = b1;
        __syncthreads();
        bf16x8 a0n = a0, a1n = a1;
        if (k0 + 64 < KTOT_) {
            #pragma unroll
            for (int h = 0; h < 2; ++h) {
                const int4* kp = (const int4*)(koff + k0 + 64 + h * 32 + sk);
                int4 ka = kp[0], kc = kp[1];
                int kk[8] = {ka.x, ka.y, ka.z, ka.w, kc.x, kc.y, kc.z, kc.w};
                bf16x8 v;
                #pragma unroll
                for (int j = 0; j < 8; ++j) v[j] = (short)Xn[kk[j] + po];
                if (h) b1 = v; else b0 = v;
            }
            a0n = *(const bf16x8*)(arow + k0 + 64 + g8);
            a1n = *(const bf16x8*)(arow + k0 + 96 + g8);
        }
        #pragma unroll
        for (int f = 0; f < 4; ++f) {
            bf16x8 bf0 = *(const bf16x8*)(&lds[f * 16 + c][g8]);
            acc[f] = __builtin_amdgcn_mfma_f32_16x16x32_bf16(a0, bf0, acc[f], 0, 0, 0);
            bf16x8 bf1 = *(const bf16x8*)(&lds[f * 16 + c][32 + g8]);
            acc[f] = __builtin_amdgcn_mfma_f32_16x16x32_bf16(a1, bf1, acc[f], 0, 0, 0);
        }
        a0 = a0n; a1 = a1n;
    }

    #pragma unroll
    for (int f = 0; f < 4; ++f) {
        int p = p0 + f * 16 + c;
        if (p < PIX_) {
            #pragma unroll
            for (int r = 0; r < 4; ++r) {
                int co = co0 + wv * 16 + (lane >> 4) * 4 + r;
                float v = acc[f][r] * bn_scale(g[co]) + bb[co];
                if (RES) v += res[(size_t)(n * C_ + co) * PIX_ + p];
                out[(size_t)(n * C_ + co) * PIX_ + p] = v;
            }
        }
    }
}

// ---------------- posconv as implicit GEMM, bf16 MFMA, pipelined K=64 steps ---
__global__ __launch_bounds__(256) void posconv_mfma_k(
    const unsigned short* __restrict__ Up,
    const unsigned short* __restrict__ Wb,
    const int* __restrict__ koff,
    const int* __restrict__ poff,
    const float* __restrict__ g, const float* __restrict__ bb,
    float* __restrict__ A, int L, int npix)
{
    __shared__ unsigned short lds[64][72];
    int tid  = threadIdx.x;
    int lane = tid & 63;
    int wv   = tid >> 6;
    int c    = lane & 15;
    int g8   = (lane >> 4) * 8;
    int p0   = blockIdx.x * 64;

    int sp = tid >> 2;
    int sk = (tid & 3) * 8;
    int po = poff[p0 + sp];

    const unsigned short* arow = Wb + (size_t)(wv * 16 + c) * KPOS_;

    f32x4 acc[4];
    #pragma unroll
    for (int f = 0; f < 4; ++f) acc[f] = (f32x4){0.f, 0.f, 0.f, 0.f};

    bf16x8 b0, b1, a0, a1;
    #pragma unroll
    for (int h = 0; h < 2; ++h) {
        const int4* kp = (const int4*)(koff + h * 32 + sk);
        int4 ka = kp[0], kc = kp[1];
        int kk[8] = {ka.x, ka.y, ka.z, ka.w, kc.x, kc.y, kc.z, kc.w};
        bf16x8 v;
        #pragma unroll
        for (int j = 0; j < 8; ++j) v[j] = (short)Up[kk[j] + po];
        if (h) b1 = v; else b0 = v;
    }
    a0 = *(const bf16x8*)(arow + g8);
    a1 = *(const bf16x8*)(arow + 32 + g8);

    for (int k0 = 0; k0 < KPOS_; k0 += 64) {
        __syncthreads();
        *(bf16x8*)(&lds[sp][sk])      = b0;
        *(bf16x8*)(&lds[sp][32 + sk]) = b1;
        __syncthreads();
        bf16x8 a0n = a0, a1n = a1;
        if (k0 + 64 < KPOS_) {
            #pragma unroll
            for (int h = 0; h < 2; ++h) {
                const int4* kp = (const int4*)(koff + k0 + 64 + h * 32 + sk);
                int4 ka = kp[0], kc = kp[1];
                int kk[8] = {ka.x, ka.y, ka.z, ka.w, kc.x, kc.y, kc.z, kc.w};
                bf16x8 v;
                #pragma unroll
                for (int j = 0; j < 8; ++j) v[j] = (short)Up[kk[j] + po];
                if (h) b1 = v; else b0 = v;
            }
            a0n = *(const bf16x8*)(arow + k0 + 64 + g8);
            a1n = *(const bf16x8*)(arow + k0 + 96 + g8);
        }
        #pragma unroll
        for (int f = 0; f < 4; ++f) {
            bf16x8 bf0 = *(const bf16x8*)(&lds[f * 16 + c][g8]);
            acc[f] = __builtin_amdgcn_mfma_f32_16x16x32_bf16(a0, bf0, acc[f], 0, 0, 0);
            bf16x8 bf1 = *(const bf16x8*)(&lds[f * 16 + c][32 + g8]);
            acc[f] = __builtin_amdgcn_mfma_f32_16x16x32_bf16(a1, bf1, acc[f], 0, 0, 0);
        }
        a0 = a0n; a1 = a1n;
    }

    #pragma unroll
    for (int f = 0; f < 4; ++f) {
        int q = p0 + f * 16 + c;
        if (q < npix) {
            int b = q / L, p = q % L;
            #pragma unroll
            for (int r = 0; r < 4; ++r) {
                int co = wv * 16 + (lane >> 4) * 4 + r;
                A[(size_t)(b * 64 + co) * L + p] += acc[f][r] * bn_scale(g[co]) + bb[co];
            }
        }
    }
}

extern "C" void kernel_launch(void* const* d_in, const int* in_sizes, int n_in,
                              void* d_out, int out_size, void* d_ws, size_t ws_size,
                              hipStream_t stream) {
    const float* x       = (const float*)d_in[0];
    const float* conv1_w = (const float*)d_in[1];
    const float* bn1_g   = (const float*)d_in[2];
    const float* bn1_b   = (const float*)d_in[3];
    const float* conv2_w = (const float*)d_in[4];
    const float* bn2_g   = (const float*)d_in[5];
    const float* bn2_b   = (const float*)d_in[6];
    const float* conv3_w = (const float*)d_in[7];
    const float* bn3_g   = (const float*)d_in[8];
    const float* bn3_b   = (const float*)d_in[9];
    const float* pos_w   = (const float*)d_in[10];
    const float* bnp_g   = (const float*)d_in[11];
    const float* bnp_b   = (const float*)d_in[12];
    const float* q_w     = (const float*)d_in[13];
    const float* k_w     = (const float*)d_in[14];
    const float* v_w     = (const float*)d_in[15];
    const float* proj_w  = (const float*)d_in[16];

    float* ws  = (float*)d_ws;
    const int TENS = N_ * C_ * PIX_;          // 3,840,000
    const int UCAP = 288 * CB_ * 144;         // 2,654,208 (largest chunk)
    float* x1  = ws;
    float* cat = ws + TENS;
    float* h2  = ws + 2 * TENS;
    float* U   = ws + 3 * TENS;
    float* Qb  = U  + UCAP;
    float* Kb  = Qb + UCAP;
    float* Vb  = Kb + UCAP;
    float* Ob  = Vb + UCAP;
    float* Ab  = Ob + UCAP;

    // posconv scratch aliases h2 (dead until conv2 writes it after the loop)
    unsigned short* Up    = (unsigned short*)h2;              // <= 3,612,672 bf16
    unsigned short* pwb   = (unsigned short*)(h2 + 1900000);  // 36,864 bf16
    int*            koffp = (int*)(h2 + 1950000);             // 576
    int*            poffp = (int*)(h2 + 1960000);             // <= 41,536

    conv1x1_mfma_k<<<dim3(157, 3, 2), 256, 0, stream>>>(x, conv1_w, bn1_g, bn1_b, x1);
    wcvt_k<<<(CB_ * KPOS_ + 255) / 256, 256, 0, stream>>>(pos_w, pwb, CB_ * KPOS_);

    const int NWs[3] = {4, 8, 12};
    const int SHs[3] = {25, 12, 8};
    const int KHs[3] = {25, 16, 12};
    const int BPs[3] = {32, 128, 288};

    for (int cidx = 0; cidx < 3; ++cidx) {
        int nw = NWs[cidx], sh = SHs[cidx], kh = KHs[cidx], Bp = BPs[cidx];
        int L = kh * kh;
        int totalU = Bp * CB_ * L;
        int npix = Bp * L;
        int nq = (npix + 63) / 64;
        gather_u_k<<<(totalU + 255) / 256, 256, 0, stream>>>(x1, U, cidx, nw, sh, kh, totalU);

        unsigned short* Q16 = (unsigned short*)Qb;
        unsigned short* K16 = (unsigned short*)Kb;
        unsigned short* V16 = (unsigned short*)Vb;
        qkv_mfma_k<<<dim3(nq, 3), 256, 0, stream>>>(U, q_w, k_w, v_w, Q16, K16, V16, L, npix);

        int nMt = (L + 31) / 32;
        int nLb = (L + 63) / 64;
        attn_mfma_k<<<dim3(nLb, Bp * 4), 256, 0, stream>>>(Q16, K16, V16, Ob, L, nMt);

        proj_mfma_k<<<nq, 256, 0, stream>>>(Ob, U, proj_w, Ab, L, npix);

        // posconv via MFMA
        int pw = kh + 2;
        int padTot = Bp * CB_ * pw * pw;
        int npix_pad = nq * 64;
        padU_bf16_k<<<(padTot + 255) / 256, 256, 0, stream>>>(U, Up, kh, padTot);
        tables_pos_k<<<(npix_pad + 255) / 256, 256, 0, stream>>>(koffp, poffp, kh, npix, npix_pad);
        posconv_mfma_k<<<nq, 256, 0, stream>>>(Up, pwb, koffp, poffp, bnp_g, bnp_b, Ab, L, npix);

        fold_k<<<(N_ * CB_ * PIX_ + 255) / 256, 256, 0, stream>>>(Ab, cat, cidx, nw, sh, kh);
    }

    // ---- MFMA path for the two 3x3 convs (buffers alias dead U region) ----
    unsigned short* Xb   = (unsigned short*)U;    // 3,995,136 bf16 (~8MB)
    unsigned short* w2b  = (unsigned short*)Qb;   // 331,776 bf16
    unsigned short* w3b  = (unsigned short*)Kb;   // 331,776 bf16
    int*            koff = (int*)Vb;              // 1728
    int*            poff = (int*)Ob;              // 10048

    tables_k<<<(10048 + 255) / 256, 256, 0, stream>>>(koff, poff);
    wcvt_k<<<(C_ * KTOT_ + 255) / 256, 256, 0, stream>>>(conv2_w, w2b, C_ * KTOT_);
    wcvt_k<<<(C_ * KTOT_ + 255) / 256, 256, 0, stream>>>(conv3_w, w3b, C_ * KTOT_);

    const int PADTOT = N_ * C_ * PADPIX_;
    pad_bf16_k<<<(PADTOT + 255) / 256, 256, 0, stream>>>(cat, Xb);
    conv3x3_mfma_k<true><<<dim3(157, 3, 2), 256, 0, stream>>>(
        Xb, w2b, koff, poff, bn2_g, bn2_b, x1, h2);
    pad_bf16_k<<<(PADTOT + 255) / 256, 256, 0, stream>>>(h2, Xb);
    conv3x3_mfma_k<false><<<dim3(157, 3, 2), 256, 0, stream>>>(
        Xb, w3b, koff, poff, bn3_g, bn3_b, nullptr, (float*)d_out);
}

// Round 8
// 459.563 us; speedup vs baseline: 7.8637x; 1.2084x over previous
//
#include <hip/hip_runtime.h>
#include <hip/hip_bf16.h>

#define N_ 2
#define C_ 192
#define CB_ 64
#define HW_ 100
#define PIX_ (HW_*HW_)
#define PADW_ 102
#define PADPIX_ (PADW_*PADW_)
#define KTOT_ 1728
#define KPOS_ 576

typedef __attribute__((ext_vector_type(8))) short bf16x8;
typedef __attribute__((ext_vector_type(4))) float f32x4;

static __device__ __forceinline__ float bn_scale(float g) {
    return g * rsqrtf(1.0f + 1e-5f);
}

static __device__ __forceinline__ unsigned short f2bf(float v) {
    __hip_bfloat16 h = __float2bfloat16(v);
    return *(unsigned short*)&h;
}

// ---------------- conv1x1 + BN as GEMM, bf16 MFMA (K=192, pipelined) ----------
__global__ __launch_bounds__(256) void conv1x1_mfma_k(
    const float* __restrict__ x, const float* __restrict__ w,
    const float* __restrict__ g, const float* __restrict__ bb,
    float* __restrict__ out)
{
    __shared__ unsigned short lds[64][72];
    int tid  = threadIdx.x;
    int lane = tid & 63;
    int wv   = tid >> 6;
    int c    = lane & 15;
    int g8   = (lane >> 4) * 8;
    int p0   = blockIdx.x * 64;
    int co0  = blockIdx.y * 64;
    int n    = blockIdx.z;
    const float* xn = x + (size_t)n * C_ * PIX_;

    int sp = tid >> 2;
    int sk = (tid & 3) * 8;
    int pc = min(p0 + sp, PIX_ - 1);

    const float* arow = w + (size_t)(co0 + wv * 16 + c) * C_;

    f32x4 acc[4];
    #pragma unroll
    for (int f = 0; f < 4; ++f) acc[f] = (f32x4){0.f, 0.f, 0.f, 0.f};

    bf16x8 b0, b1;
    #pragma unroll
    for (int j = 0; j < 8; ++j) {
        b0[j] = (short)f2bf(xn[(size_t)(sk + j) * PIX_ + pc]);
        b1[j] = (short)f2bf(xn[(size_t)(32 + sk + j) * PIX_ + pc]);
    }

    for (int k0 = 0; k0 < C_; k0 += 64) {
        __syncthreads();
        *(bf16x8*)(&lds[sp][sk])      = b0;
        *(bf16x8*)(&lds[sp][32 + sk]) = b1;
        __syncthreads();
        if (k0 + 64 < C_) {
            #pragma unroll
            for (int j = 0; j < 8; ++j) {
                b0[j] = (short)f2bf(xn[(size_t)(k0 + 64 + sk + j) * PIX_ + pc]);
                b1[j] = (short)f2bf(xn[(size_t)(k0 + 96 + sk + j) * PIX_ + pc]);
            }
        }
        #pragma unroll
        for (int h = 0; h < 2; ++h) {
            bf16x8 a;
            const float* ap = arow + k0 + h * 32 + g8;
            #pragma unroll
            for (int j = 0; j < 8; ++j) a[j] = (short)f2bf(ap[j]);
            #pragma unroll
            for (int f = 0; f < 4; ++f) {
                bf16x8 b = *(const bf16x8*)(&lds[f * 16 + c][h * 32 + g8]);
                acc[f] = __builtin_amdgcn_mfma_f32_16x16x32_bf16(a, b, acc[f], 0, 0, 0);
            }
        }
    }

    #pragma unroll
    for (int f = 0; f < 4; ++f) {
        int p = p0 + f * 16 + c;
        if (p < PIX_) {
            #pragma unroll
            for (int r = 0; r < 4; ++r) {
                int co = co0 + wv * 16 + (lane >> 4) * 4 + r;
                out[(size_t)(n * C_ + co) * PIX_ + p] = acc[f][r] * bn_scale(g[co]) + bb[co];
            }
        }
    }
}

// ---------------- gather patches into U (flat order n,cb,r,c,i,j) ----------------
__global__ __launch_bounds__(256) void gather_u_k(
    const float* __restrict__ x1, float* __restrict__ U,
    int cidx, int nw, int sh, int kh, int total)
{
    int f = blockIdx.x * 256 + threadIdx.x;
    if (f >= total) return;
    int t = f;
    int j = t % nw; t /= nw;
    int i = t % nw; t /= nw;
    int c = t % kh; t /= kh;
    int r = t % kh; t /= kh;
    int cb = t % CB_;
    int n  = t / CB_;
    int hh = i * sh + r;
    int ww = j * sh + c;
    U[f] = x1[((n * C_ + cidx * CB_ + cb) * HW_ + hh) * HW_ + ww];
}

// ---------------- q/k/v 1x1 convs as GEMM, bf16 MFMA (K=64) -------------------
__global__ __launch_bounds__(256) void qkv_mfma_k(
    const float* __restrict__ U,
    const float* __restrict__ qw, const float* __restrict__ kw,
    const float* __restrict__ vw,
    unsigned short* __restrict__ Q, unsigned short* __restrict__ K,
    unsigned short* __restrict__ V,
    int L, int npix)
{
    __shared__ unsigned short lds[64][72];
    int tid  = threadIdx.x;
    int lane = tid & 63;
    int wv   = tid >> 6;
    int c    = lane & 15;
    int g8   = (lane >> 4) * 8;
    int q0   = blockIdx.x * 64;
    int sel  = blockIdx.y;
    const float* wsel = (sel == 0) ? qw : (sel == 1) ? kw : vw;
    unsigned short* osel = (sel == 0) ? Q : (sel == 1) ? K : V;

    int sp = tid >> 2;
    int sk = (tid & 3) * 8;
    int qc = min(q0 + sp, npix - 1);
    int b  = qc / L, p = qc % L;
    const float* ub = U + (size_t)b * 64 * L + p;

    bf16x8 b0, b1;
    #pragma unroll
    for (int j = 0; j < 8; ++j) {
        b0[j] = (short)f2bf(ub[(size_t)(sk + j) * L]);
        b1[j] = (short)f2bf(ub[(size_t)(32 + sk + j) * L]);
    }
    __syncthreads();
    *(bf16x8*)(&lds[sp][sk])      = b0;
    *(bf16x8*)(&lds[sp][32 + sk]) = b1;
    __syncthreads();

    f32x4 acc[4];
    #pragma unroll
    for (int f = 0; f < 4; ++f) acc[f] = (f32x4){0.f, 0.f, 0.f, 0.f};

    const float* arow = wsel + (size_t)(wv * 16 + c) * 64;
    #pragma unroll
    for (int h = 0; h < 2; ++h) {
        bf16x8 a;
        const float* ap = arow + h * 32 + g8;
        #pragma unroll
        for (int j = 0; j < 8; ++j) a[j] = (short)f2bf(ap[j]);
        #pragma unroll
        for (int f = 0; f < 4; ++f) {
            bf16x8 bfr = *(const bf16x8*)(&lds[f * 16 + c][h * 32 + g8]);
            acc[f] = __builtin_amdgcn_mfma_f32_16x16x32_bf16(a, bfr, acc[f], 0, 0, 0);
        }
    }

    #pragma unroll
    for (int f = 0; f < 4; ++f) {
        int qq = q0 + f * 16 + c;
        if (qq < npix) {
            int bo = qq / L, po = qq % L;
            #pragma unroll
            for (int r = 0; r < 4; ++r) {
                int co = wv * 16 + (lane >> 4) * 4 + r;
                osel[(size_t)(bo * 64 + co) * L + po] = f2bf(acc[f][r]);
            }
        }
    }
}

// ---------------- proj 1x1 + residual(U) as GEMM, bf16 MFMA (K=64) ------------
__global__ __launch_bounds__(256) void proj_mfma_k(
    const float* __restrict__ O, const float* __restrict__ U,
    const float* __restrict__ pw, float* __restrict__ A,
    int L, int npix)
{
    __shared__ unsigned short lds[64][72];
    int tid  = threadIdx.x;
    int lane = tid & 63;
    int wv   = tid >> 6;
    int c    = lane & 15;
    int g8   = (lane >> 4) * 8;
    int q0   = blockIdx.x * 64;

    int sp = tid >> 2;
    int sk = (tid & 3) * 8;
    int qc = min(q0 + sp, npix - 1);
    int b  = qc / L, p = qc % L;
    const float* ob = O + (size_t)b * 64 * L + p;

    bf16x8 b0, b1;
    #pragma unroll
    for (int j = 0; j < 8; ++j) {
        b0[j] = (short)f2bf(ob[(size_t)(sk + j) * L]);
        b1[j] = (short)f2bf(ob[(size_t)(32 + sk + j) * L]);
    }
    __syncthreads();
    *(bf16x8*)(&lds[sp][sk])      = b0;
    *(bf16x8*)(&lds[sp][32 + sk]) = b1;
    __syncthreads();

    f32x4 acc[4];
    #pragma unroll
    for (int f = 0; f < 4; ++f) acc[f] = (f32x4){0.f, 0.f, 0.f, 0.f};

    const float* arow = pw + (size_t)(wv * 16 + c) * 64;
    #pragma unroll
    for (int h = 0; h < 2; ++h) {
        bf16x8 a;
        const float* ap = arow + h * 32 + g8;
        #pragma unroll
        for (int j = 0; j < 8; ++j) a[j] = (short)f2bf(ap[j]);
        #pragma unroll
        for (int f = 0; f < 4; ++f) {
            bf16x8 bfr = *(const bf16x8*)(&lds[f * 16 + c][h * 32 + g8]);
            acc[f] = __builtin_amdgcn_mfma_f32_16x16x32_bf16(a, bfr, acc[f], 0, 0, 0);
        }
    }

    #pragma unroll
    for (int f = 0; f < 4; ++f) {
        int qq = q0 + f * 16 + c;
        if (qq < npix) {
            int bo = qq / L, po = qq % L;
            #pragma unroll
            for (int r = 0; r < 4; ++r) {
                int co = wv * 16 + (lane >> 4) * 4 + r;
                size_t oi = (size_t)(bo * 64 + co) * L + po;
                A[oi] = acc[f][r] + U[oi];
            }
        }
    }
}

// ---------------- MFMA flash attention ----------------
__global__ __launch_bounds__(256) void attn_mfma_k(
    const unsigned short* __restrict__ Q, const unsigned short* __restrict__ K,
    const unsigned short* __restrict__ V, float* __restrict__ O,
    int L, int nMt)
{
    __shared__ unsigned short kt[32][24];   // [m][d]
    __shared__ unsigned short vt[16][40];   // [d][m]
    int tid  = threadIdx.x;
    int lane = tid & 63;
    int wv   = tid >> 6;
    int c    = lane & 15;
    int g    = lane >> 4;
    int bh = blockIdx.y;
    int b = bh >> 2, h = bh & 3;
    const unsigned short* qb = Q + (size_t)(b * 64 + h * 16) * L;
    const unsigned short* kb = K + (size_t)(b * 64 + h * 16) * L;
    const unsigned short* vb = V + (size_t)(b * 64 + h * 16) * L;
    float* ob = O + (size_t)(b * 64 + h * 16) * L;

    int l = blockIdx.x * 64 + wv * 16 + c;
    bool lval = (l < L);
    int lc = lval ? l : (L - 1);

    bf16x8 qf = (bf16x8){0,0,0,0,0,0,0,0};
    if (g < 2) {
        #pragma unroll
        for (int j = 0; j < 8; ++j) qf[j] = (short)qb[(g * 8 + j) * L + lc];
    }

    f32x4 acc = (f32x4){0.f, 0.f, 0.f, 0.f};
    float mrun = -1e30f, srun = 0.f;

    for (int mt = 0; mt < nMt; ++mt) {
        int m0 = mt * 32;
        __syncthreads();
        for (int e = tid; e < 1024; e += 256) {
            int m = e & 31, d = (e >> 5) & 15;
            int src = d * L + min(m0 + m, L - 1);
            if (e < 512) kt[m][d] = kb[src];
            else         vt[d][m] = vb[src];
        }
        __syncthreads();

        bf16x8 kf1 = (bf16x8){0,0,0,0,0,0,0,0}, kf2 = kf1;
        if (g < 2) {
            kf1 = *(const bf16x8*)(&kt[c][g * 8]);
            kf2 = *(const bf16x8*)(&kt[c + 16][g * 8]);
        }
        f32x4 s1 = __builtin_amdgcn_mfma_f32_16x16x32_bf16(
            kf1, qf, (f32x4){0.f,0.f,0.f,0.f}, 0, 0, 0);
        f32x4 s2 = __builtin_amdgcn_mfma_f32_16x16x32_bf16(
            kf2, qf, (f32x4){0.f,0.f,0.f,0.f}, 0, 0, 0);

        float p1[4], p2[4];
        float tmax = -1e30f;
        #pragma unroll
        for (int r = 0; r < 4; ++r) {
            int ma = m0 + g * 4 + r;
            float a  = (ma      < L) ? s1[r] * 0.25f : -1e30f;
            float b2 = (ma + 16 < L) ? s2[r] * 0.25f : -1e30f;
            p1[r] = a; p2[r] = b2;
            tmax = fmaxf(tmax, fmaxf(a, b2));
        }
        tmax = fmaxf(tmax, __shfl_xor(tmax, 16, 64));
        tmax = fmaxf(tmax, __shfl_xor(tmax, 32, 64));
        float mnew = fmaxf(mrun, tmax);
        float corr = __expf(mrun - mnew);
        float psum = 0.f;
        #pragma unroll
        for (int r = 0; r < 4; ++r) {
            p1[r] = __expf(p1[r] - mnew);
            p2[r] = __expf(p2[r] - mnew);
            psum += p1[r] + p2[r];
        }
        srun = srun * corr + psum;
        mrun = mnew;
        #pragma unroll
        for (int r = 0; r < 4; ++r) acc[r] *= corr;

        bf16x8 pbf;
        int t = g >> 1;
        #pragma unroll
        for (int j = 0; j < 8; ++j) {
            int srcLane = (((2 * g + (j >> 2)) & 3) << 4) | c;
            float v1 = __shfl(p1[j & 3], srcLane, 64);
            float v2 = __shfl(p2[j & 3], srcLane, 64);
            pbf[j] = (short)f2bf(t ? v2 : v1);
        }
        bf16x8 vf = *(const bf16x8*)(&vt[c][g * 8]);
        acc = __builtin_amdgcn_mfma_f32_16x16x32_bf16(vf, pbf, acc, 0, 0, 0);
    }

    float stot = srun;
    stot += __shfl_xor(stot, 16, 64);
    stot += __shfl_xor(stot, 32, 64);
    float inv = 1.f / stot;
    if (lval) {
        #pragma unroll
        for (int r = 0; r < 4; ++r)
            ob[(size_t)(g * 4 + r) * L + l] = acc[r] * inv;
    }
}

// ---------------- fold (gather-style overlap-add with count div) ----------------
__global__ __launch_bounds__(256) void fold_k(
    const float* __restrict__ A, float* __restrict__ cat,
    int cidx, int nw, int sh, int kh)
{
    int idx = blockIdx.x * 256 + threadIdx.x;           // (n, cb, h, w)
    if (idx >= N_ * CB_ * PIX_) return;
    int w  = idx % HW_;
    int h  = (idx / HW_) % HW_;
    int cb = (idx / PIX_) % CB_;
    int n  = idx / (PIX_ * CB_);
    int numh = h - kh + 1;
    int ilo = numh > 0 ? (numh + sh - 1) / sh : 0;
    int ihi = min(nw - 1, h / sh);
    int numw = w - kh + 1;
    int jlo = numw > 0 ? (numw + sh - 1) / sh : 0;
    int jhi = min(nw - 1, w / sh);
    float sum = 0.f;
    for (int i = ilo; i <= ihi; ++i) {
        int r = h - i * sh;
        for (int j = jlo; j <= jhi; ++j) {
            int c = w - j * sh;
            int f = ((((n * CB_ + cb) * kh + r) * kh + c) * nw + i) * nw + j;
            sum += A[f];
        }
    }
    float cnt = (float)((ihi - ilo + 1) * (jhi - jlo + 1));
    cat[((n * C_ + cidx * CB_ + cb) * HW_ + h) * HW_ + w] = sum / cnt;
}

// ---------------- prep: fp32 NCHW -> bf16 NHWC padded [n][102][102][192] ------
__global__ __launch_bounds__(256) void pad_nhwc_k(
    const float* __restrict__ in, unsigned short* __restrict__ out)
{
    int idx = blockIdx.x * 256 + threadIdx.x;   // (n, chunk, padpix)
    if (idx >= N_ * 4 * PADPIX_) return;
    int pp    = idx % PADPIX_;
    int chunk = (idx / PADPIX_) & 3;
    int n     = idx / (PADPIX_ * 4);
    int xx = pp % PADW_, yy = pp / PADW_;
    int c0 = chunk * 48;
    bool inter = (xx >= 1 && xx <= HW_ && yy >= 1 && yy <= HW_);
    const float* ip = in + ((size_t)n * C_ + c0) * PIX_ + (yy - 1) * HW_ + (xx - 1);
    unsigned short vals[48];
    #pragma unroll
    for (int j = 0; j < 48; ++j) vals[j] = inter ? f2bf(ip[(size_t)j * PIX_]) : 0;
    unsigned short* op = out + ((size_t)n * PADPIX_ + pp) * 192 + c0;
    #pragma unroll
    for (int v = 0; v < 6; ++v) {
        bf16x8 pack;
        #pragma unroll
        for (int j = 0; j < 8; ++j) pack[j] = (short)vals[v * 8 + j];
        *(bf16x8*)(op + v * 8) = pack;
    }
}

// ---------------- prep: weights [co][ci][3][3] fp32 -> bf16 [co][t*Ci+ci] -----
__global__ __launch_bounds__(256) void wcvt_tap_k(
    const float* __restrict__ in, unsigned short* __restrict__ out,
    int Ci, int total)
{
    int idx = blockIdx.x * 256 + threadIdx.x;
    if (idx >= total) return;
    int t  = idx % 9;
    int ci = (idx / 9) % Ci;
    int co = idx / (9 * Ci);
    out[(size_t)co * Ci * 9 + t * Ci + ci] = f2bf(in[idx]);
}

// ---------------- prep: pixel table (big conv): top-left in padded coords -----
__global__ __launch_bounds__(256) void tables_k(int* __restrict__ poff)
{
    int i = blockIdx.x * 256 + threadIdx.x;
    if (i < 10048) {
        poff[i] = (i < PIX_) ? (i / HW_) * PADW_ + (i % HW_) : 0;
    }
}

// ---------------- prep: U fp32 [b*64+cb][kh][kh] -> bf16 NHWC padded ----------
// Up[(b*pw*pw + yy*pw + xx)*64 + cb]
__global__ __launch_bounds__(256) void padU_nhwc_k(
    const float* __restrict__ U, unsigned short* __restrict__ Up,
    int kh, int pw, int L, int total)   // total = Bp*pw*pw
{
    int idx = blockIdx.x * 256 + threadIdx.x;
    if (idx >= total) return;
    int pp = idx % (pw * pw);
    int b  = idx / (pw * pw);
    int xx = pp % pw, yy = pp / pw;
    bool inter = (xx >= 1 && xx <= kh && yy >= 1 && yy <= kh);
    const float* up = U + (size_t)b * 64 * L + (yy - 1) * kh + (xx - 1);
    unsigned short vals[64];
    #pragma unroll
    for (int j = 0; j < 64; ++j) vals[j] = inter ? f2bf(up[(size_t)j * L]) : 0;
    unsigned short* op = Up + (size_t)idx * 64;
    #pragma unroll
    for (int v = 0; v < 8; ++v) {
        bf16x8 pack;
        #pragma unroll
        for (int j = 0; j < 8; ++j) pack[j] = (short)vals[v * 8 + j];
        *(bf16x8*)(op + v * 8) = pack;
    }
}

// ---------------- prep: pixel table for posconv (per chunk) -------------------
// poff[i] = b*pw*pw + y*pw + x (top-left, pixel units within NHWC patch buffer)
__global__ __launch_bounds__(256) void tables_pos_k(
    int* __restrict__ poff, int kh, int pw, int L, int npix, int npix_pad)
{
    int i = blockIdx.x * 256 + threadIdx.x;
    if (i < npix_pad) {
        if (i < npix) {
            int b = i / L, p = i % L;
            poff[i] = b * pw * pw + (p / kh) * pw + (p % kh);
        } else {
            poff[i] = 0;
        }
    }
}

// ---------------- 3x3 conv implicit GEMM, NHWC bf16, vectorized staging -------
template<bool RES>
__global__ __launch_bounds__(256) void conv3x3_mfma_k(
    const unsigned short* __restrict__ Xp,   // NHWC padded bf16 [n][102][102][192]
    const unsigned short* __restrict__ Wb,   // [192][1728] bf16, k=(tap,ci)
    const int* __restrict__ poff,            // [10048]
    const float* __restrict__ g, const float* __restrict__ bb,
    const float* __restrict__ res, float* __restrict__ out)
{
    __shared__ unsigned short lds[64][72];
    int tid  = threadIdx.x;
    int lane = tid & 63;
    int wv   = tid >> 6;
    int c    = lane & 15;
    int g8   = (lane >> 4) * 8;
    int p0   = blockIdx.x * 64;
    int co0  = blockIdx.y * 64;
    int n    = blockIdx.z;
    const unsigned short* Xn = Xp + (size_t)n * PADPIX_ * 192;

    int sp = tid >> 2;
    int sk = (tid & 3) * 8;
    int po = poff[p0 + sp];

    const unsigned short* arow = Wb + (size_t)(co0 + wv * 16 + c) * KTOT_;

    f32x4 acc[4];
    #pragma unroll
    for (int f = 0; f < 4; ++f) acc[f] = (f32x4){0.f, 0.f, 0.f, 0.f};

    // prefetch k0 = 0 (tap 0, ci0 = 0)
    bf16x8 b0, b1, a0, a1;
    {
        const unsigned short* bp = Xn + (size_t)po * 192;
        b0 = *(const bf16x8*)(bp + sk);
        b1 = *(const bf16x8*)(bp + 32 + sk);
    }
    a0 = *(const bf16x8*)(arow + g8);
    a1 = *(const bf16x8*)(arow + 32 + g8);

    for (int k0 = 0; k0 < KTOT_; k0 += 64) {
        __syncthreads();
        *(bf16x8*)(&lds[sp][sk])      = b0;
        *(bf16x8*)(&lds[sp][32 + sk]) = b1;
        __syncthreads();
        bf16x8 a0n = a0, a1n = a1;
        if (k0 + 64 < KTOT_) {
            int k1 = k0 + 64;
            int t  = k1 / 192;
            int ci0 = k1 - t * 192;
            int toff = (t / 3) * PADW_ + (t % 3);
            const unsigned short* bp = Xn + (size_t)(po + toff) * 192 + ci0;
            b0 = *(const bf16x8*)(bp + sk);
            b1 = *(const bf16x8*)(bp + 32 + sk);
            a0n = *(const bf16x8*)(arow + k1 + g8);
            a1n = *(const bf16x8*)(arow + k1 + 32 + g8);
        }
        #pragma unroll
        for (int f = 0; f < 4; ++f) {
            bf16x8 bf0 = *(const bf16x8*)(&lds[f * 16 + c][g8]);
            acc[f] = __builtin_amdgcn_mfma_f32_16x16x32_bf16(a0, bf0, acc[f], 0, 0, 0);
            bf16x8 bf1 = *(const bf16x8*)(&lds[f * 16 + c][32 + g8]);
            acc[f] = __builtin_amdgcn_mfma_f32_16x16x32_bf16(a1, bf1, acc[f], 0, 0, 0);
        }
        a0 = a0n; a1 = a1n;
    }

    #pragma unroll
    for (int f = 0; f < 4; ++f) {
        int p = p0 + f * 16 + c;
        if (p < PIX_) {
            #pragma unroll
            for (int r = 0; r < 4; ++r) {
                int co = co0 + wv * 16 + (lane >> 4) * 4 + r;
                float v = acc[f][r] * bn_scale(g[co]) + bb[co];
                if (RES) v += res[(size_t)(n * C_ + co) * PIX_ + p];
                out[(size_t)(n * C_ + co) * PIX_ + p] = v;
            }
        }
    }
}

// ---------------- posconv implicit GEMM, NHWC bf16, vectorized staging --------
__global__ __launch_bounds__(256) void posconv_mfma_k(
    const unsigned short* __restrict__ Up,   // [Bp][pw*pw][64] bf16
    const unsigned short* __restrict__ Wb,   // [64][576] bf16, k=(tap,ci)
    const int* __restrict__ poff,            // [npix_pad]
    const float* __restrict__ g, const float* __restrict__ bb,
    float* __restrict__ A, int L, int npix, int pw)
{
    __shared__ unsigned short lds[64][72];
    int tid  = threadIdx.x;
    int lane = tid & 63;
    int wv   = tid >> 6;
    int c    = lane & 15;
    int g8   = (lane >> 4) * 8;
    int p0   = blockIdx.x * 64;

    int sp = tid >> 2;
    int sk = (tid & 3) * 8;
    int po = poff[p0 + sp];

    const unsigned short* arow = Wb + (size_t)(wv * 16 + c) * KPOS_;

    f32x4 acc[4];
    #pragma unroll
    for (int f = 0; f < 4; ++f) acc[f] = (f32x4){0.f, 0.f, 0.f, 0.f};

    // prefetch k0 = 0 (tap 0)
    bf16x8 b0, b1, a0, a1;
    {
        const unsigned short* bp = Up + ((size_t)po << 6);
        b0 = *(const bf16x8*)(bp + sk);
        b1 = *(const bf16x8*)(bp + 32 + sk);
    }
    a0 = *(const bf16x8*)(arow + g8);
    a1 = *(const bf16x8*)(arow + 32 + g8);

    for (int k0 = 0; k0 < KPOS_; k0 += 64) {
        __syncthreads();
        *(bf16x8*)(&lds[sp][sk])      = b0;
        *(bf16x8*)(&lds[sp][32 + sk]) = b1;
        __syncthreads();
        bf16x8 a0n = a0, a1n = a1;
        if (k0 + 64 < KPOS_) {
            int t = (k0 + 64) >> 6;               // one tap per 64-k step
            int toff = (t / 3) * pw + (t % 3);
            const unsigned short* bp = Up + ((size_t)(po + toff) << 6);
            b0 = *(const bf16x8*)(bp + sk);
            b1 = *(const bf16x8*)(bp + 32 + sk);
            a0n = *(const bf16x8*)(arow + k0 + 64 + g8);
            a1n = *(const bf16x8*)(arow + k0 + 96 + g8);
        }
        #pragma unroll
        for (int f = 0; f < 4; ++f) {
            bf16x8 bf0 = *(const bf16x8*)(&lds[f * 16 + c][g8]);
            acc[f] = __builtin_amdgcn_mfma_f32_16x16x32_bf16(a0, bf0, acc[f], 0, 0, 0);
            bf16x8 bf1 = *(const bf16x8*)(&lds[f * 16 + c][32 + g8]);
            acc[f] = __builtin_amdgcn_mfma_f32_16x16x32_bf16(a1, bf1, acc[f], 0, 0, 0);
        }
        a0 = a0n; a1 = a1n;
    }

    #pragma unroll
    for (int f = 0; f < 4; ++f) {
        int q = p0 + f * 16 + c;
        if (q < npix) {
            int b = q / L, p = q % L;
            #pragma unroll
            for (int r = 0; r < 4; ++r) {
                int co = wv * 16 + (lane >> 4) * 4 + r;
                A[(size_t)(b * 64 + co) * L + p] += acc[f][r] * bn_scale(g[co]) + bb[co];
            }
        }
    }
}

extern "C" void kernel_launch(void* const* d_in, const int* in_sizes, int n_in,
                              void* d_out, int out_size, void* d_ws, size_t ws_size,
                              hipStream_t stream) {
    const float* x       = (const float*)d_in[0];
    const float* conv1_w = (const float*)d_in[1];
    const float* bn1_g   = (const float*)d_in[2];
    const float* bn1_b   = (const float*)d_in[3];
    const float* conv2_w = (const float*)d_in[4];
    const float* bn2_g   = (const float*)d_in[5];
    const float* bn2_b   = (const float*)d_in[6];
    const float* conv3_w = (const float*)d_in[7];
    const float* bn3_g   = (const float*)d_in[8];
    const float* bn3_b   = (const float*)d_in[9];
    const float* pos_w   = (const float*)d_in[10];
    const float* bnp_g   = (const float*)d_in[11];
    const float* bnp_b   = (const float*)d_in[12];
    const float* q_w     = (const float*)d_in[13];
    const float* k_w     = (const float*)d_in[14];
    const float* v_w     = (const float*)d_in[15];
    const float* proj_w  = (const float*)d_in[16];

    float* ws  = (float*)d_ws;
    const int TENS = N_ * C_ * PIX_;          // 3,840,000
    const int UCAP = 288 * CB_ * 144;         // 2,654,208 (largest chunk)
    float* x1  = ws;
    float* cat = ws + TENS;
    float* h2  = ws + 2 * TENS;
    float* U   = ws + 3 * TENS;
    float* Qb  = U  + UCAP;
    float* Kb  = Qb + UCAP;
    float* Vb  = Kb + UCAP;
    float* Ob  = Vb + UCAP;
    float* Ab  = Ob + UCAP;

    // posconv scratch aliases h2 (dead until conv2 writes it after the loop)
    unsigned short* Up    = (unsigned short*)h2;              // <= 3,612,672 bf16
    unsigned short* pwb   = (unsigned short*)(h2 + 1900000);  // 36,864 bf16
    int*            poffp = (int*)(h2 + 1960000);             // <= 56,448

    conv1x1_mfma_k<<<dim3(157, 3, 2), 256, 0, stream>>>(x, conv1_w, bn1_g, bn1_b, x1);
    wcvt_tap_k<<<(CB_ * KPOS_ + 255) / 256, 256, 0, stream>>>(pos_w, pwb, CB_, CB_ * KPOS_);

    const int NWs[3] = {4, 8, 12};
    const int SHs[3] = {25, 12, 8};
    const int KHs[3] = {25, 16, 12};
    const int BPs[3] = {32, 128, 288};

    for (int cidx = 0; cidx < 3; ++cidx) {
        int nw = NWs[cidx], sh = SHs[cidx], kh = KHs[cidx], Bp = BPs[cidx];
        int L = kh * kh;
        int totalU = Bp * CB_ * L;
        int npix = Bp * L;
        int nq = (npix + 63) / 64;
        gather_u_k<<<(totalU + 255) / 256, 256, 0, stream>>>(x1, U, cidx, nw, sh, kh, totalU);

        unsigned short* Q16 = (unsigned short*)Qb;
        unsigned short* K16 = (unsigned short*)Kb;
        unsigned short* V16 = (unsigned short*)Vb;
        qkv_mfma_k<<<dim3(nq, 3), 256, 0, stream>>>(U, q_w, k_w, v_w, Q16, K16, V16, L, npix);

        int nMt = (L + 31) / 32;
        int nLb = (L + 63) / 64;
        attn_mfma_k<<<dim3(nLb, Bp * 4), 256, 0, stream>>>(Q16, K16, V16, Ob, L, nMt);

        proj_mfma_k<<<nq, 256, 0, stream>>>(Ob, U, proj_w, Ab, L, npix);

        // posconv via MFMA (NHWC patches)
        int pw = kh + 2;
        int padTot = Bp * pw * pw;
        int npix_pad = nq * 64;
        padU_nhwc_k<<<(padTot + 255) / 256, 256, 0, stream>>>(U, Up, kh, pw, L, padTot);
        tables_pos_k<<<(npix_pad + 255) / 256, 256, 0, stream>>>(poffp, kh, pw, L, npix, npix_pad);
        posconv_mfma_k<<<nq, 256, 0, stream>>>(Up, pwb, poffp, bnp_g, bnp_b, Ab, L, npix, pw);

        fold_k<<<(N_ * CB_ * PIX_ + 255) / 256, 256, 0, stream>>>(Ab, cat, cidx, nw, sh, kh);
    }

    // ---- MFMA path for the two 3x3 convs (buffers alias dead U region) ----
    unsigned short* Xb   = (unsigned short*)U;    // 3,995,136 bf16 NHWC padded
    unsigned short* w2b  = (unsigned short*)Qb;   // 331,776 bf16 (tap,ci)
    unsigned short* w3b  = (unsigned short*)Kb;   // 331,776 bf16 (tap,ci)
    int*            poff = (int*)Ob;              // 10048

    tables_k<<<(10048 + 255) / 256, 256, 0, stream>>>(poff);
    wcvt_tap_k<<<(C_ * KTOT_ + 255) / 256, 256, 0, stream>>>(conv2_w, w2b, C_, C_ * KTOT_);
    wcvt_tap_k<<<(C_ * KTOT_ + 255) / 256, 256, 0, stream>>>(conv3_w, w3b, C_, C_ * KTOT_);

    const int PADTOT = N_ * 4 * PADPIX_;
    pad_nhwc_k<<<(PADTOT + 255) / 256, 256, 0, stream>>>(cat, Xb);
    conv3x3_mfma_k<true><<<dim3(157, 3, 2), 256, 0, stream>>>(
        Xb, w2b, poff, bn2_g, bn2_b, x1, h2);
    pad_nhwc_k<<<(PADTOT + 255) / 256, 256, 0, stream>>>(h2, Xb);
    conv3x3_mfma_k<false><<<dim3(157, 3, 2), 256, 0, stream>>>(
        Xb, w3b, poff, bn3_g, bn3_b, nullptr, (float*)d_out);
}

// Round 9
// 445.361 us; speedup vs baseline: 8.1145x; 1.0319x over previous
//
#include <hip/hip_runtime.h>
#include <hip/hip_bf16.h>

#define N_ 2
#define C_ 192
#define CB_ 64
#define HW_ 100
#define PIX_ (HW_*HW_)
#define PADW_ 102
#define PADPIX_ (PADW_*PADW_)
#define KTOT_ 1728
#define KPOS_ 576

typedef __attribute__((ext_vector_type(8))) short bf16x8;
typedef __attribute__((ext_vector_type(4))) float f32x4;

static __device__ __forceinline__ float bn_scale(float g) {
    return g * rsqrtf(1.0f + 1e-5f);
}

static __device__ __forceinline__ unsigned short f2bf(float v) {
    __hip_bfloat16 h = __float2bfloat16(v);
    return *(unsigned short*)&h;
}

// ---------------- conv1x1 + BN as GEMM, bf16 MFMA (K=192, pipelined) ----------
__global__ __launch_bounds__(256) void conv1x1_mfma_k(
    const float* __restrict__ x, const float* __restrict__ w,
    const float* __restrict__ g, const float* __restrict__ bb,
    float* __restrict__ out)
{
    __shared__ unsigned short lds[64][72];
    int tid  = threadIdx.x;
    int lane = tid & 63;
    int wv   = tid >> 6;
    int c    = lane & 15;
    int g8   = (lane >> 4) * 8;
    int p0   = blockIdx.x * 64;
    int co0  = blockIdx.y * 64;
    int n    = blockIdx.z;
    const float* xn = x + (size_t)n * C_ * PIX_;

    int sp = tid >> 2;
    int sk = (tid & 3) * 8;
    int pc = min(p0 + sp, PIX_ - 1);

    const float* arow = w + (size_t)(co0 + wv * 16 + c) * C_;

    f32x4 acc[4];
    #pragma unroll
    for (int f = 0; f < 4; ++f) acc[f] = (f32x4){0.f, 0.f, 0.f, 0.f};

    bf16x8 b0, b1;
    #pragma unroll
    for (int j = 0; j < 8; ++j) {
        b0[j] = (short)f2bf(xn[(size_t)(sk + j) * PIX_ + pc]);
        b1[j] = (short)f2bf(xn[(size_t)(32 + sk + j) * PIX_ + pc]);
    }

    for (int k0 = 0; k0 < C_; k0 += 64) {
        __syncthreads();
        *(bf16x8*)(&lds[sp][sk])      = b0;
        *(bf16x8*)(&lds[sp][32 + sk]) = b1;
        __syncthreads();
        if (k0 + 64 < C_) {
            #pragma unroll
            for (int j = 0; j < 8; ++j) {
                b0[j] = (short)f2bf(xn[(size_t)(k0 + 64 + sk + j) * PIX_ + pc]);
                b1[j] = (short)f2bf(xn[(size_t)(k0 + 96 + sk + j) * PIX_ + pc]);
            }
        }
        #pragma unroll
        for (int h = 0; h < 2; ++h) {
            bf16x8 a;
            const float* ap = arow + k0 + h * 32 + g8;
            #pragma unroll
            for (int j = 0; j < 8; ++j) a[j] = (short)f2bf(ap[j]);
            #pragma unroll
            for (int f = 0; f < 4; ++f) {
                bf16x8 b = *(const bf16x8*)(&lds[f * 16 + c][h * 32 + g8]);
                acc[f] = __builtin_amdgcn_mfma_f32_16x16x32_bf16(a, b, acc[f], 0, 0, 0);
            }
        }
    }

    #pragma unroll
    for (int f = 0; f < 4; ++f) {
        int p = p0 + f * 16 + c;
        if (p < PIX_) {
            #pragma unroll
            for (int r = 0; r < 4; ++r) {
                int co = co0 + wv * 16 + (lane >> 4) * 4 + r;
                out[(size_t)(n * C_ + co) * PIX_ + p] = acc[f][r] * bn_scale(g[co]) + bb[co];
            }
        }
    }
}

// ---------------- gather patches into U (flat order n,cb,r,c,i,j) ----------------
__global__ __launch_bounds__(256) void gather_u_k(
    const float* __restrict__ x1, float* __restrict__ U,
    int cidx, int nw, int sh, int kh, int total)
{
    int f = blockIdx.x * 256 + threadIdx.x;
    if (f >= total) return;
    int t = f;
    int j = t % nw; t /= nw;
    int i = t % nw; t /= nw;
    int c = t % kh; t /= kh;
    int r = t % kh; t /= kh;
    int cb = t % CB_;
    int n  = t / CB_;
    int hh = i * sh + r;
    int ww = j * sh + c;
    U[f] = x1[((n * C_ + cidx * CB_ + cb) * HW_ + hh) * HW_ + ww];
}

// ---------------- q/k/v 1x1 convs as GEMM, bf16 MFMA (K=64) -------------------
// Q: [b*64+co][L], pre-scaled by 0.25. Kt: [(b*4+h)*L + p][16] transposed.
// V: [b*64+co][Lp] (Lp = L rounded up to 8 for 16B-aligned rows).
__global__ __launch_bounds__(256) void qkv_mfma_k(
    const float* __restrict__ U,
    const float* __restrict__ qw, const float* __restrict__ kw,
    const float* __restrict__ vw,
    unsigned short* __restrict__ Q, unsigned short* __restrict__ Kt,
    unsigned short* __restrict__ V,
    int L, int Lp, int npix)
{
    __shared__ unsigned short lds[64][72];
    int tid  = threadIdx.x;
    int lane = tid & 63;
    int wv   = tid >> 6;
    int c    = lane & 15;
    int g8   = (lane >> 4) * 8;
    int q0   = blockIdx.x * 64;
    int sel  = blockIdx.y;
    const float* wsel = (sel == 0) ? qw : (sel == 1) ? kw : vw;

    int sp = tid >> 2;
    int sk = (tid & 3) * 8;
    int qc = min(q0 + sp, npix - 1);
    int b  = qc / L, p = qc % L;
    const float* ub = U + (size_t)b * 64 * L + p;

    bf16x8 b0, b1;
    #pragma unroll
    for (int j = 0; j < 8; ++j) {
        b0[j] = (short)f2bf(ub[(size_t)(sk + j) * L]);
        b1[j] = (short)f2bf(ub[(size_t)(32 + sk + j) * L]);
    }
    __syncthreads();
    *(bf16x8*)(&lds[sp][sk])      = b0;
    *(bf16x8*)(&lds[sp][32 + sk]) = b1;
    __syncthreads();

    f32x4 acc[4];
    #pragma unroll
    for (int f = 0; f < 4; ++f) acc[f] = (f32x4){0.f, 0.f, 0.f, 0.f};

    const float* arow = wsel + (size_t)(wv * 16 + c) * 64;
    #pragma unroll
    for (int h = 0; h < 2; ++h) {
        bf16x8 a;
        const float* ap = arow + h * 32 + g8;
        #pragma unroll
        for (int j = 0; j < 8; ++j) a[j] = (short)f2bf(ap[j]);
        #pragma unroll
        for (int f = 0; f < 4; ++f) {
            bf16x8 bfr = *(const bf16x8*)(&lds[f * 16 + c][h * 32 + g8]);
            acc[f] = __builtin_amdgcn_mfma_f32_16x16x32_bf16(a, bfr, acc[f], 0, 0, 0);
        }
    }

    #pragma unroll
    for (int f = 0; f < 4; ++f) {
        int qq = q0 + f * 16 + c;
        if (qq < npix) {
            int bo = qq / L, po = qq % L;
            #pragma unroll
            for (int r = 0; r < 4; ++r) {
                int co = wv * 16 + (lane >> 4) * 4 + r;
                float v = acc[f][r];
                if (sel == 0) {
                    Q[(size_t)(bo * 64 + co) * L + po] = f2bf(v * 0.25f);
                } else if (sel == 1) {
                    Kt[((size_t)(bo * 4 + wv) * L + po) * 16 + ((lane >> 4) * 4 + r)] = f2bf(v);
                } else {
                    V[(size_t)(bo * 64 + co) * Lp + po] = f2bf(v);
                }
            }
        }
    }
}

// ---------------- MFMA flash attention, KVBLK=64, vectorized staging ----------
// Q pre-scaled by 0.25. Kt transposed [bh*L + m][16]. V leading dim Lp.
__global__ __launch_bounds__(256) void attn_mfma_k(
    const unsigned short* __restrict__ Q, const unsigned short* __restrict__ Kt,
    const unsigned short* __restrict__ V, float* __restrict__ O,
    int L, int Lp, int nMt)
{
    __shared__ unsigned short kt[64][20];   // [m][d], 40B rows
    __shared__ unsigned short vt[16][68];   // [d][m], 136B rows
    int tid  = threadIdx.x;
    int lane = tid & 63;
    int wv   = tid >> 6;
    int c    = lane & 15;
    int g    = lane >> 4;
    int bh = blockIdx.y;
    int b = bh >> 2, h = bh & 3;
    const unsigned short* qb = Q + (size_t)(b * 64 + h * 16) * L;
    const unsigned short* kb = Kt + (size_t)bh * L * 16;
    const unsigned short* vb = V + (size_t)(b * 64 + h * 16) * Lp;
    float* ob = O + (size_t)(b * 64 + h * 16) * L;

    int l = blockIdx.x * 64 + wv * 16 + c;
    bool lval = (l < L);
    int lc = lval ? l : (L - 1);

    // Q B-frag: B[l=c][d=g*8+j], d>=16 -> 0
    bf16x8 qf = (bf16x8){0,0,0,0,0,0,0,0};
    if (g < 2) {
        #pragma unroll
        for (int j = 0; j < 8; ++j) qf[j] = (short)qb[(g * 8 + j) * L + lc];
    }

    f32x4 acc = (f32x4){0.f, 0.f, 0.f, 0.f};
    float mrun = -1e30f, srun = 0.f;

    for (int mt = 0; mt < nMt; ++mt) {
        int m0 = mt * 64;
        bool full = (m0 + 64 <= L);
        __syncthreads();
        if (tid < 128) {
            int m = tid >> 1, hf = tid & 1;
            int mm = full ? (m0 + m) : min(m0 + m, L - 1);
            bf16x8 kv = *(const bf16x8*)(kb + (size_t)mm * 16 + hf * 8);
            *(bf16x8*)(&kt[m][hf * 8]) = kv;
        } else {
            int idx = tid - 128;
            int d = idx >> 3, s = idx & 7;
            if (full) {
                bf16x8 vv = *(const bf16x8*)(vb + (size_t)d * Lp + m0 + s * 8);
                *(bf16x8*)(&vt[d][s * 8]) = vv;
            } else {
                #pragma unroll
                for (int j = 0; j < 8; ++j) {
                    int m = m0 + s * 8 + j;
                    vt[d][s * 8 + j] = (m < L) ? vb[(size_t)d * Lp + m] : 0;
                }
            }
        }
        __syncthreads();

        // S^T = K^T Q : 4 MFMAs (A rows m = c + t*16)
        f32x4 s[4];
        #pragma unroll
        for (int t = 0; t < 4; ++t) {
            bf16x8 kf = (bf16x8){0,0,0,0,0,0,0,0};
            if (g < 2) kf = *(const bf16x8*)(&kt[c + t * 16][g * 8]);
            s[t] = __builtin_amdgcn_mfma_f32_16x16x32_bf16(
                kf, qf, (f32x4){0.f,0.f,0.f,0.f}, 0, 0, 0);
        }

        // softmax over this 64-m tile (per column l=c within 4-lane group)
        float p[16];
        float tmax = -1e30f;
        #pragma unroll
        for (int t = 0; t < 4; ++t) {
            #pragma unroll
            for (int r = 0; r < 4; ++r) {
                int m = m0 + t * 16 + g * 4 + r;
                float v = s[t][r];
                if (!full && m >= L) v = -1e30f;
                p[t * 4 + r] = v;
                tmax = fmaxf(tmax, v);
            }
        }
        tmax = fmaxf(tmax, __shfl_xor(tmax, 16, 64));
        tmax = fmaxf(tmax, __shfl_xor(tmax, 32, 64));
        float mnew = fmaxf(mrun, tmax);
        float corr = __expf(mrun - mnew);
        float psum = 0.f;
        #pragma unroll
        for (int t = 0; t < 16; ++t) {
            p[t] = __expf(p[t] - mnew);
            psum += p[t];
        }
        srun = srun * corr + psum;
        mrun = mnew;
        #pragma unroll
        for (int r = 0; r < 4; ++r) acc[r] *= corr;

        // PV: two B-frags (m halves), K-dim 32 each
        int hi = g >> 1;
        #pragma unroll
        for (int H = 0; H < 2; ++H) {
            bf16x8 pb;
            #pragma unroll
            for (int j = 0; j < 8; ++j) {
                int srcLane = (((2 * g + (j >> 2)) & 3) << 4) | c;
                float v1 = __shfl(p[(H * 2) * 4 + (j & 3)], srcLane, 64);
                float v2 = __shfl(p[(H * 2 + 1) * 4 + (j & 3)], srcLane, 64);
                pb[j] = (short)f2bf(hi ? v2 : v1);
            }
            bf16x8 vf = *(const bf16x8*)(&vt[c][H * 32 + g * 8]);
            acc = __builtin_amdgcn_mfma_f32_16x16x32_bf16(vf, pb, acc, 0, 0, 0);
        }
    }

    float stot = srun;
    stot += __shfl_xor(stot, 16, 64);
    stot += __shfl_xor(stot, 32, 64);
    float inv = 1.f / stot;
    if (lval) {
        #pragma unroll
        for (int r = 0; r < 4; ++r)
            ob[(size_t)(g * 4 + r) * L + l] = acc[r] * inv;
    }
}

// ---------------- proj 1x1 + residual(U) as GEMM, bf16 MFMA (K=64) ------------
__global__ __launch_bounds__(256) void proj_mfma_k(
    const float* __restrict__ O, const float* __restrict__ U,
    const float* __restrict__ pw, float* __restrict__ A,
    int L, int npix)
{
    __shared__ unsigned short lds[64][72];
    int tid  = threadIdx.x;
    int lane = tid & 63;
    int wv   = tid >> 6;
    int c    = lane & 15;
    int g8   = (lane >> 4) * 8;
    int q0   = blockIdx.x * 64;

    int sp = tid >> 2;
    int sk = (tid & 3) * 8;
    int qc = min(q0 + sp, npix - 1);
    int b  = qc / L, p = qc % L;
    const float* ob = O + (size_t)b * 64 * L + p;

    bf16x8 b0, b1;
    #pragma unroll
    for (int j = 0; j < 8; ++j) {
        b0[j] = (short)f2bf(ob[(size_t)(sk + j) * L]);
        b1[j] = (short)f2bf(ob[(size_t)(32 + sk + j) * L]);
    }
    __syncthreads();
    *(bf16x8*)(&lds[sp][sk])      = b0;
    *(bf16x8*)(&lds[sp][32 + sk]) = b1;
    __syncthreads();

    f32x4 acc[4];
    #pragma unroll
    for (int f = 0; f < 4; ++f) acc[f] = (f32x4){0.f, 0.f, 0.f, 0.f};

    const float* arow = pw + (size_t)(wv * 16 + c) * 64;
    #pragma unroll
    for (int h = 0; h < 2; ++h) {
        bf16x8 a;
        const float* ap = arow + h * 32 + g8;
        #pragma unroll
        for (int j = 0; j < 8; ++j) a[j] = (short)f2bf(ap[j]);
        #pragma unroll
        for (int f = 0; f < 4; ++f) {
            bf16x8 bfr = *(const bf16x8*)(&lds[f * 16 + c][h * 32 + g8]);
            acc[f] = __builtin_amdgcn_mfma_f32_16x16x32_bf16(a, bfr, acc[f], 0, 0, 0);
        }
    }

    #pragma unroll
    for (int f = 0; f < 4; ++f) {
        int qq = q0 + f * 16 + c;
        if (qq < npix) {
            int bo = qq / L, po = qq % L;
            #pragma unroll
            for (int r = 0; r < 4; ++r) {
                int co = wv * 16 + (lane >> 4) * 4 + r;
                size_t oi = (size_t)(bo * 64 + co) * L + po;
                A[oi] = acc[f][r] + U[oi];
            }
        }
    }
}

// ---------------- fold (gather-style overlap-add with count div) ----------------
__global__ __launch_bounds__(256) void fold_k(
    const float* __restrict__ A, float* __restrict__ cat,
    int cidx, int nw, int sh, int kh)
{
    int idx = blockIdx.x * 256 + threadIdx.x;           // (n, cb, h, w)
    if (idx >= N_ * CB_ * PIX_) return;
    int w  = idx % HW_;
    int h  = (idx / HW_) % HW_;
    int cb = (idx / PIX_) % CB_;
    int n  = idx / (PIX_ * CB_);
    int numh = h - kh + 1;
    int ilo = numh > 0 ? (numh + sh - 1) / sh : 0;
    int ihi = min(nw - 1, h / sh);
    int numw = w - kh + 1;
    int jlo = numw > 0 ? (numw + sh - 1) / sh : 0;
    int jhi = min(nw - 1, w / sh);
    float sum = 0.f;
    for (int i = ilo; i <= ihi; ++i) {
        int r = h - i * sh;
        for (int j = jlo; j <= jhi; ++j) {
            int c = w - j * sh;
            int f = ((((n * CB_ + cb) * kh + r) * kh + c) * nw + i) * nw + j;
            sum += A[f];
        }
    }
    float cnt = (float)((ihi - ilo + 1) * (jhi - jlo + 1));
    cat[((n * C_ + cidx * CB_ + cb) * HW_ + h) * HW_ + w] = sum / cnt;
}

// ---------------- prep: fp32 NCHW -> bf16 NHWC padded [n][102][102][192] ------
__global__ __launch_bounds__(256) void pad_nhwc_k(
    const float* __restrict__ in, unsigned short* __restrict__ out)
{
    int idx = blockIdx.x * 256 + threadIdx.x;   // (n, chunk, padpix)
    if (idx >= N_ * 4 * PADPIX_) return;
    int pp    = idx % PADPIX_;
    int chunk = (idx / PADPIX_) & 3;
    int n     = idx / (PADPIX_ * 4);
    int xx = pp % PADW_, yy = pp / PADW_;
    int c0 = chunk * 48;
    bool inter = (xx >= 1 && xx <= HW_ && yy >= 1 && yy <= HW_);
    const float* ip = in + ((size_t)n * C_ + c0) * PIX_ + (yy - 1) * HW_ + (xx - 1);
    unsigned short vals[48];
    #pragma unroll
    for (int j = 0; j < 48; ++j) vals[j] = inter ? f2bf(ip[(size_t)j * PIX_]) : 0;
    unsigned short* op = out + ((size_t)n * PADPIX_ + pp) * 192 + c0;
    #pragma unroll
    for (int v = 0; v < 6; ++v) {
        bf16x8 pack;
        #pragma unroll
        for (int j = 0; j < 8; ++j) pack[j] = (short)vals[v * 8 + j];
        *(bf16x8*)(op + v * 8) = pack;
    }
}

// ---------------- prep: weights [co][ci][3][3] fp32 -> bf16 [co][t*Ci+ci] -----
__global__ __launch_bounds__(256) void wcvt_tap_k(
    const float* __restrict__ in, unsigned short* __restrict__ out,
    int Ci, int total)
{
    int idx = blockIdx.x * 256 + threadIdx.x;
    if (idx >= total) return;
    int t  = idx % 9;
    int ci = (idx / 9) % Ci;
    int co = idx / (9 * Ci);
    out[(size_t)co * Ci * 9 + t * Ci + ci] = f2bf(in[idx]);
}

// ---------------- prep: pixel table (big conv): top-left in padded coords -----
__global__ __launch_bounds__(256) void tables_k(int* __restrict__ poff)
{
    int i = blockIdx.x * 256 + threadIdx.x;
    if (i < 10048) {
        poff[i] = (i < PIX_) ? (i / HW_) * PADW_ + (i % HW_) : 0;
    }
}

// ---------------- prep: U fp32 [b*64+cb][kh][kh] -> bf16 NHWC padded ----------
__global__ __launch_bounds__(256) void padU_nhwc_k(
    const float* __restrict__ U, unsigned short* __restrict__ Up,
    int kh, int pw, int L, int total)   // total = Bp*pw*pw
{
    int idx = blockIdx.x * 256 + threadIdx.x;
    if (idx >= total) return;
    int pp = idx % (pw * pw);
    int b  = idx / (pw * pw);
    int xx = pp % pw, yy = pp / pw;
    bool inter = (xx >= 1 && xx <= kh && yy >= 1 && yy <= kh);
    const float* up = U + (size_t)b * 64 * L + (yy - 1) * kh + (xx - 1);
    unsigned short vals[64];
    #pragma unroll
    for (int j = 0; j < 64; ++j) vals[j] = inter ? f2bf(up[(size_t)j * L]) : 0;
    unsigned short* op = Up + (size_t)idx * 64;
    #pragma unroll
    for (int v = 0; v < 8; ++v) {
        bf16x8 pack;
        #pragma unroll
        for (int j = 0; j < 8; ++j) pack[j] = (short)vals[v * 8 + j];
        *(bf16x8*)(op + v * 8) = pack;
    }
}

// ---------------- prep: pixel table for posconv (per chunk) -------------------
__global__ __launch_bounds__(256) void tables_pos_k(
    int* __restrict__ poff, int kh, int pw, int L, int npix, int npix_pad)
{
    int i = blockIdx.x * 256 + threadIdx.x;
    if (i < npix_pad) {
        if (i < npix) {
            int b = i / L, p = i % L;
            poff[i] = b * pw * pw + (p / kh) * pw + (p % kh);
        } else {
            poff[i] = 0;
        }
    }
}

// ---------------- 3x3 conv implicit GEMM, NHWC bf16, vectorized staging -------
template<bool RES>
__global__ __launch_bounds__(256) void conv3x3_mfma_k(
    const unsigned short* __restrict__ Xp,   // NHWC padded bf16 [n][102][102][192]
    const unsigned short* __restrict__ Wb,   // [192][1728] bf16, k=(tap,ci)
    const int* __restrict__ poff,            // [10048]
    const float* __restrict__ g, const float* __restrict__ bb,
    const float* __restrict__ res, float* __restrict__ out)
{
    __shared__ unsigned short lds[64][72];
    int tid  = threadIdx.x;
    int lane = tid & 63;
    int wv   = tid >> 6;
    int c    = lane & 15;
    int g8   = (lane >> 4) * 8;
    int p0   = blockIdx.x * 64;
    int co0  = blockIdx.y * 64;
    int n    = blockIdx.z;
    const unsigned short* Xn = Xp + (size_t)n * PADPIX_ * 192;

    int sp = tid >> 2;
    int sk = (tid & 3) * 8;
    int po = poff[p0 + sp];

    const unsigned short* arow = Wb + (size_t)(co0 + wv * 16 + c) * KTOT_;

    f32x4 acc[4];
    #pragma unroll
    for (int f = 0; f < 4; ++f) acc[f] = (f32x4){0.f, 0.f, 0.f, 0.f};

    bf16x8 b0, b1, a0, a1;
    {
        const unsigned short* bp = Xn + (size_t)po * 192;
        b0 = *(const bf16x8*)(bp + sk);
        b1 = *(const bf16x8*)(bp + 32 + sk);
    }
    a0 = *(const bf16x8*)(arow + g8);
    a1 = *(const bf16x8*)(arow + 32 + g8);

    for (int k0 = 0; k0 < KTOT_; k0 += 64) {
        __syncthreads();
        *(bf16x8*)(&lds[sp][sk])      = b0;
        *(bf16x8*)(&lds[sp][32 + sk]) = b1;
        __syncthreads();
        bf16x8 a0n = a0, a1n = a1;
        if (k0 + 64 < KTOT_) {
            int k1 = k0 + 64;
            int t  = k1 / 192;
            int ci0 = k1 - t * 192;
            int toff = (t / 3) * PADW_ + (t % 3);
            const unsigned short* bp = Xn + (size_t)(po + toff) * 192 + ci0;
            b0 = *(const bf16x8*)(bp + sk);
            b1 = *(const bf16x8*)(bp + 32 + sk);
            a0n = *(const bf16x8*)(arow + k1 + g8);
            a1n = *(const bf16x8*)(arow + k1 + 32 + g8);
        }
        #pragma unroll
        for (int f = 0; f < 4; ++f) {
            bf16x8 bf0 = *(const bf16x8*)(&lds[f * 16 + c][g8]);
            acc[f] = __builtin_amdgcn_mfma_f32_16x16x32_bf16(a0, bf0, acc[f], 0, 0, 0);
            bf16x8 bf1 = *(const bf16x8*)(&lds[f * 16 + c][32 + g8]);
            acc[f] = __builtin_amdgcn_mfma_f32_16x16x32_bf16(a1, bf1, acc[f], 0, 0, 0);
        }
        a0 = a0n; a1 = a1n;
    }

    #pragma unroll
    for (int f = 0; f < 4; ++f) {
        int p = p0 + f * 16 + c;
        if (p < PIX_) {
            #pragma unroll
            for (int r = 0; r < 4; ++r) {
                int co = co0 + wv * 16 + (lane >> 4) * 4 + r;
                float v = acc[f][r] * bn_scale(g[co]) + bb[co];
                if (RES) v += res[(size_t)(n * C_ + co) * PIX_ + p];
                out[(size_t)(n * C_ + co) * PIX_ + p] = v;
            }
        }
    }
}

// ---------------- posconv implicit GEMM, NHWC bf16, vectorized staging --------
__global__ __launch_bounds__(256) void posconv_mfma_k(
    const unsigned short* __restrict__ Up,   // [Bp][pw*pw][64] bf16
    const unsigned short* __restrict__ Wb,   // [64][576] bf16, k=(tap,ci)
    const int* __restrict__ poff,            // [npix_pad]
    const float* __restrict__ g, const float* __restrict__ bb,
    float* __restrict__ A, int L, int npix, int pw)
{
    __shared__ unsigned short lds[64][72];
    int tid  = threadIdx.x;
    int lane = tid & 63;
    int wv   = tid >> 6;
    int c    = lane & 15;
    int g8   = (lane >> 4) * 8;
    int p0   = blockIdx.x * 64;

    int sp = tid >> 2;
    int sk = (tid & 3) * 8;
    int po = poff[p0 + sp];

    const unsigned short* arow = Wb + (size_t)(wv * 16 + c) * KPOS_;

    f32x4 acc[4];
    #pragma unroll
    for (int f = 0; f < 4; ++f) acc[f] = (f32x4){0.f, 0.f, 0.f, 0.f};

    bf16x8 b0, b1, a0, a1;
    {
        const unsigned short* bp = Up + ((size_t)po << 6);
        b0 = *(const bf16x8*)(bp + sk);
        b1 = *(const bf16x8*)(bp + 32 + sk);
    }
    a0 = *(const bf16x8*)(arow + g8);
    a1 = *(const bf16x8*)(arow + 32 + g8);

    for (int k0 = 0; k0 < KPOS_; k0 += 64) {
        __syncthreads();
        *(bf16x8*)(&lds[sp][sk])      = b0;
        *(bf16x8*)(&lds[sp][32 + sk]) = b1;
        __syncthreads();
        bf16x8 a0n = a0, a1n = a1;
        if (k0 + 64 < KPOS_) {
            int t = (k0 + 64) >> 6;
            int toff = (t / 3) * pw + (t % 3);
            const unsigned short* bp = Up + ((size_t)(po + toff) << 6);
            b0 = *(const bf16x8*)(bp + sk);
            b1 = *(const bf16x8*)(bp + 32 + sk);
            a0n = *(const bf16x8*)(arow + k0 + 64 + g8);
            a1n = *(const bf16x8*)(arow + k0 + 96 + g8);
        }
        #pragma unroll
        for (int f = 0; f < 4; ++f) {
            bf16x8 bf0 = *(const bf16x8*)(&lds[f * 16 + c][g8]);
            acc[f] = __builtin_amdgcn_mfma_f32_16x16x32_bf16(a0, bf0, acc[f], 0, 0, 0);
            bf16x8 bf1 = *(const bf16x8*)(&lds[f * 16 + c][32 + g8]);
            acc[f] = __builtin_amdgcn_mfma_f32_16x16x32_bf16(a1, bf1, acc[f], 0, 0, 0);
        }
        a0 = a0n; a1 = a1n;
    }

    #pragma unroll
    for (int f = 0; f < 4; ++f) {
        int q = p0 + f * 16 + c;
        if (q < npix) {
            int b = q / L, p = q % L;
            #pragma unroll
            for (int r = 0; r < 4; ++r) {
                int co = wv * 16 + (lane >> 4) * 4 + r;
                A[(size_t)(b * 64 + co) * L + p] += acc[f][r] * bn_scale(g[co]) + bb[co];
            }
        }
    }
}

extern "C" void kernel_launch(void* const* d_in, const int* in_sizes, int n_in,
                              void* d_out, int out_size, void* d_ws, size_t ws_size,
                              hipStream_t stream) {
    const float* x       = (const float*)d_in[0];
    const float* conv1_w = (const float*)d_in[1];
    const float* bn1_g   = (const float*)d_in[2];
    const float* bn1_b   = (const float*)d_in[3];
    const float* conv2_w = (const float*)d_in[4];
    const float* bn2_g   = (const float*)d_in[5];
    const float* bn2_b   = (const float*)d_in[6];
    const float* conv3_w = (const float*)d_in[7];
    const float* bn3_g   = (const float*)d_in[8];
    const float* bn3_b   = (const float*)d_in[9];
    const float* pos_w   = (const float*)d_in[10];
    const float* bnp_g   = (const float*)d_in[11];
    const float* bnp_b   = (const float*)d_in[12];
    const float* q_w     = (const float*)d_in[13];
    const float* k_w     = (const float*)d_in[14];
    const float* v_w     = (const float*)d_in[15];
    const float* proj_w  = (const float*)d_in[16];

    float* ws  = (float*)d_ws;
    const int TENS = N_ * C_ * PIX_;          // 3,840,000
    const int UCAP = 288 * CB_ * 144;         // 2,654,208 (largest chunk)
    float* x1  = ws;
    float* cat = ws + TENS;
    float* h2  = ws + 2 * TENS;
    float* U   = ws + 3 * TENS;
    float* Qb  = U  + UCAP;
    float* Kb  = Qb + UCAP;
    float* Vb  = Kb + UCAP;
    float* Ob  = Vb + UCAP;
    float* Ab  = Ob + UCAP;

    // posconv scratch aliases h2 (dead until conv2 writes it after the loop)
    unsigned short* Up    = (unsigned short*)h2;              // <= 3,612,672 bf16
    unsigned short* pwb   = (unsigned short*)(h2 + 1900000);  // 36,864 bf16
    int*            poffp = (int*)(h2 + 1960000);             // <= 56,448

    conv1x1_mfma_k<<<dim3(157, 3, 2), 256, 0, stream>>>(x, conv1_w, bn1_g, bn1_b, x1);
    wcvt_tap_k<<<(CB_ * KPOS_ + 255) / 256, 256, 0, stream>>>(pos_w, pwb, CB_, CB_ * KPOS_);

    const int NWs[3] = {4, 8, 12};
    const int SHs[3] = {25, 12, 8};
    const int KHs[3] = {25, 16, 12};
    const int BPs[3] = {32, 128, 288};

    for (int cidx = 0; cidx < 3; ++cidx) {
        int nw = NWs[cidx], sh = SHs[cidx], kh = KHs[cidx], Bp = BPs[cidx];
        int L = kh * kh;
        int Lp = (L + 7) & ~7;
        int totalU = Bp * CB_ * L;
        int npix = Bp * L;
        int nq = (npix + 63) / 64;
        gather_u_k<<<(totalU + 255) / 256, 256, 0, stream>>>(x1, U, cidx, nw, sh, kh, totalU);

        unsigned short* Q16 = (unsigned short*)Qb;
        unsigned short* Kt16 = (unsigned short*)Kb;
        unsigned short* V16 = (unsigned short*)Vb;
        qkv_mfma_k<<<dim3(nq, 3), 256, 0, stream>>>(U, q_w, k_w, v_w, Q16, Kt16, V16, L, Lp, npix);

        int nMt = (L + 63) / 64;
        int nLb = (L + 63) / 64;
        attn_mfma_k<<<dim3(nLb, Bp * 4), 256, 0, stream>>>(Q16, Kt16, V16, Ob, L, Lp, nMt);

        proj_mfma_k<<<nq, 256, 0, stream>>>(Ob, U, proj_w, Ab, L, npix);

        // posconv via MFMA (NHWC patches)
        int pw = kh + 2;
        int padTot = Bp * pw * pw;
        int npix_pad = nq * 64;
        padU_nhwc_k<<<(padTot + 255) / 256, 256, 0, stream>>>(U, Up, kh, pw, L, padTot);
        tables_pos_k<<<(npix_pad + 255) / 256, 256, 0, stream>>>(poffp, kh, pw, L, npix, npix_pad);
        posconv_mfma_k<<<nq, 256, 0, stream>>>(Up, pwb, poffp, bnp_g, bnp_b, Ab, L, npix, pw);

        fold_k<<<(N_ * CB_ * PIX_ + 255) / 256, 256, 0, stream>>>(Ab, cat, cidx, nw, sh, kh);
    }

    // ---- MFMA path for the two 3x3 convs (buffers alias dead U region) ----
    unsigned short* Xb   = (unsigned short*)U;    // 3,995,136 bf16 NHWC padded
    unsigned short* w2b  = (unsigned short*)Qb;   // 331,776 bf16 (tap,ci)
    unsigned short* w3b  = (unsigned short*)Kb;   // 331,776 bf16 (tap,ci)
    int*            poff = (int*)Ob;              // 10048

    tables_k<<<(10048 + 255) / 256, 256, 0, stream>>>(poff);
    wcvt_tap_k<<<(C_ * KTOT_ + 255) / 256, 256, 0, stream>>>(conv2_w, w2b, C_, C_ * KTOT_);
    wcvt_tap_k<<<(C_ * KTOT_ + 255) / 256, 256, 0, stream>>>(conv3_w, w3b, C_, C_ * KTOT_);

    const int PADTOT = N_ * 4 * PADPIX_;
    pad_nhwc_k<<<(PADTOT + 255) / 256, 256, 0, stream>>>(cat, Xb);
    conv3x3_mfma_k<true><<<dim3(157, 3, 2), 256, 0, stream>>>(
        Xb, w2b, poff, bn2_g, bn2_b, x1, h2);
    pad_nhwc_k<<<(PADTOT + 255) / 256, 256, 0, stream>>>(h2, Xb);
    conv3x3_mfma_k<false><<<dim3(157, 3, 2), 256, 0, stream>>>(
        Xb, w3b, poff, bn3_g, bn3_b, nullptr, (float*)d_out);
}